// Round 1
// baseline (296.288 us; speedup 1.0000x reference)
//
#include <hip/hip_runtime.h>

#define NB 8
#define NCIN 3
#define NCH 64
#define NH 256
#define NW 256
#define NM 4
#define NLAYERS 6

// tanh(x) = 1 - 2/(1+e^{2x}); __expf -> v_exp_f32. Accurate to ~1e-6 abs.
__device__ __forceinline__ float fast_tanh(float x) {
    float e = __expf(2.0f * x);
    return 1.0f - 2.0f / (1.0f + e);
}

// ---------------------------------------------------------------------------
// K1: encoder (tanh(enc(x))) + row DFT (ky = 0..3) -> P[b][c][row][q] (complex)
// block = (b,row), 256 threads (one per w)
// ---------------------------------------------------------------------------
__global__ __launch_bounds__(256) void k_enc_rowdft(
    const float* __restrict__ x, const float* __restrict__ enc_w,
    const float* __restrict__ enc_b, float2* __restrict__ P)
{
    __shared__ __align__(16) float h0s[NCH][NW + 4];   // +4 pad: float4 reads, 2-way banks
    __shared__ __align__(16) float cT[NM][NW + 4];
    __shared__ __align__(16) float sT[NM][NW + 4];
    const int b   = blockIdx.x >> 8;
    const int row = blockIdx.x & 255;
    const int t   = threadIdx.x;

    // twiddle tables: e^{-2pi i q w / 256}
    for (int idx = t; idx < NM * NW; idx += 256) {
        int q = idx >> 8, w = idx & 255;
        float a = (float)(q * w) * (1.0f / 128.0f);   // 2*q*w/256
        cT[q][w] = cospif(a);
        sT[q][w] = sinpif(a);
    }

    const float x0 = x[((b * NCIN + 0) * NH + row) * NW + t];
    const float x1 = x[((b * NCIN + 1) * NH + row) * NW + t];
    const float x2 = x[((b * NCIN + 2) * NH + row) * NW + t];
    #pragma unroll
    for (int c = 0; c < NCH; ++c) {
        float v = enc_b[c] + enc_w[c * 3 + 0] * x0 + enc_w[c * 3 + 1] * x1
                           + enc_w[c * 3 + 2] * x2;
        h0s[c][t] = fast_tanh(v);
    }
    __syncthreads();

    // thread -> (c,q); sum over w
    const int c = t >> 2, q = t & 3;
    const float4* hv = (const float4*)(&h0s[c][0]);
    const float4* cv = (const float4*)(&cT[q][0]);
    const float4* sv = (const float4*)(&sT[q][0]);
    float re = 0.f, im = 0.f;
    #pragma unroll 8
    for (int w4 = 0; w4 < NW / 4; ++w4) {
        float4 h = hv[w4], cc = cv[w4], ss = sv[w4];
        re += h.x * cc.x + h.y * cc.y + h.z * cc.z + h.w * cc.w;
        im -= h.x * ss.x + h.y * ss.y + h.z * ss.z + h.w * ss.w;
    }
    P[((b * NCH + c) * NH + row) * NM + q] = make_float2(re, im);
}

// ---------------------------------------------------------------------------
// K2: column DFT over rows -> s0[b][p][q][c], p=0..7 <-> kx={0,1,2,3,-4,-3,-2,-1}
// block = (b,c), 64 threads (1 wave), lane handles 4 rows
// ---------------------------------------------------------------------------
__global__ __launch_bounds__(64) void k_coldft(const float2* __restrict__ P,
                                               float2* __restrict__ s0)
{
    const int b    = blockIdx.x >> 6;
    const int c    = blockIdx.x & 63;
    const int lane = threadIdx.x;
    float ar[8][4], ai[8][4];
    #pragma unroll
    for (int p = 0; p < 8; ++p)
        #pragma unroll
        for (int q = 0; q < 4; ++q) { ar[p][q] = 0.f; ai[p][q] = 0.f; }

    const int kxs[8] = {0, 1, 2, 3, -4, -3, -2, -1};
    #pragma unroll
    for (int rr = 0; rr < 4; ++rr) {
        const int row = lane + rr * 64;
        const float4* pp = (const float4*)(&P[((b * NCH + c) * NH + row) * NM]);
        float4 p01 = pp[0], p23 = pp[1];
        float pr[4] = {p01.x, p01.z, p23.x, p23.z};
        float pi[4] = {p01.y, p01.w, p23.y, p23.w};
        #pragma unroll
        for (int p = 0; p < 8; ++p) {
            float a  = (float)(kxs[p] * row) * (1.0f / 128.0f);
            float tr = cospif(a);
            float ti = -sinpif(a);              // e^{-2pi i kx row/256}
            #pragma unroll
            for (int q = 0; q < 4; ++q) {
                ar[p][q] += pr[q] * tr - pi[q] * ti;
                ai[p][q] += pr[q] * ti + pi[q] * tr;
            }
        }
    }
    #pragma unroll
    for (int p = 0; p < 8; ++p)
        #pragma unroll
        for (int q = 0; q < 4; ++q) {
            float vr = ar[p][q], vi = ai[p][q];
            #pragma unroll
            for (int m = 1; m < 64; m <<= 1) {
                vr += __shfl_xor(vr, m);
                vi += __shfl_xor(vi, m);
            }
            ar[p][q] = vr; ai[p][q] = vi;
        }
    if (lane == 0) {
        #pragma unroll
        for (int p = 0; p < 8; ++p)
            #pragma unroll
            for (int q = 0; q < 4; ++q)
                s0[((b * 8 + p) * 4 + q) * NCH + c] = make_float2(ar[p][q], ai[p][q]);
    }
}

// ---------------------------------------------------------------------------
// K3a: spectral iteration for ky=q in {1,2,3} (modes fully independent).
// block = (b,q,p), 64 threads (thread = out channel o). 6 layers in-block.
// d += F each layer; s += F. F[o] = sum_i s[i]*W[i][o] (complex).
// ---------------------------------------------------------------------------
__global__ __launch_bounds__(64) void k_spec_q123(
    const float* __restrict__ w1r, const float* __restrict__ w1i,
    const float* __restrict__ w2r, const float* __restrict__ w2i,
    const float2* __restrict__ s0, float2* __restrict__ dacc)
{
    __shared__ float Wr[NCH * NCH];
    __shared__ float Wi[NCH * NCH];
    __shared__ float sr[NCH], si[NCH];
    const int gx = blockIdx.x;
    const int b  = gx / 24;
    const int r  = gx % 24;
    const int q  = (r >> 3) + 1;
    const int p  = r & 7;
    const int o  = threadIdx.x;
    const float* wr = (p < 4) ? w1r : w2r;
    const float* wi = (p < 4) ? w1i : w2i;
    const int pm = p & 3;
    for (int i = 0; i < NCH; ++i) {
        int gi_ = ((i * NCH + o) * NM + pm) * NM + q;
        Wr[i * NCH + o] = wr[gi_];
        Wi[i * NCH + o] = wi[gi_];
    }
    float2 sv = s0[((b * 8 + p) * 4 + q) * NCH + o];
    sr[o] = sv.x; si[o] = sv.y;
    float dr = 0.f, di = 0.f;
    __syncthreads();
    for (int l = 0; l < NLAYERS; ++l) {
        float Fr = 0.f, Fi = 0.f;
        for (int i = 0; i < NCH; ++i) {
            float a0 = sr[i], a1 = si[i];
            float b0 = Wr[i * NCH + o], b1 = Wi[i * NCH + o];
            Fr += a0 * b0 - a1 * b1;
            Fi += a0 * b1 + a1 * b0;
        }
        __syncthreads();
        sr[o] += Fr; si[o] += Fi;
        dr += Fr; di += Fi;
        __syncthreads();
    }
    dacc[((b * 9 + p) * 4 + q) * NCH + o] = make_float2(dr, di);
}

// ---------------------------------------------------------------------------
// K3b: spectral iteration for ky=0 with irfft Hermitian semantics.
// Groups per b: {p0}, {p1,p7}, {p2,p6}, {p3,p5}, {p4(+leak to kx=+4)}.
// add(p=0)   = (Re F, 0)
// add(pairs) = (F[p] + conj(F[partner]))/2
// add(p=4)   = F/2 ; write-only bin (kx=+4,ky=0) += conj(F)/2  (slot pp=8)
// block = (b,group), 128 threads = (which, o).
// ---------------------------------------------------------------------------
__global__ __launch_bounds__(128) void k_spec_q0(
    const float* __restrict__ w1r, const float* __restrict__ w1i,
    const float* __restrict__ w2r, const float* __restrict__ w2i,
    const float2* __restrict__ s0, float2* __restrict__ dacc)
{
    __shared__ float Wr[2][NCH * NCH];
    __shared__ float Wi[2][NCH * NCH];
    __shared__ float sr[2][NCH], si[2][NCH];
    __shared__ float2 FL[2][NCH];
    const int gx    = blockIdx.x;
    const int b     = gx / 5;
    const int g     = gx % 5;
    const int which = threadIdx.x >> 6;
    const int o     = threadIdx.x & 63;
    int p;
    if (which == 0) p = g;
    else            p = (g == 1) ? 7 : (g == 2) ? 6 : (g == 3) ? 5 : -1;
    const bool active = (p >= 0);
    if (active) {
        const float* wr = (p < 4) ? w1r : w2r;
        const float* wi = (p < 4) ? w1i : w2i;
        const int pm = p & 3;
        for (int i = 0; i < NCH; ++i) {
            int gi_ = ((i * NCH + o) * NM + pm) * NM + 0;
            Wr[which][i * NCH + o] = wr[gi_];
            Wi[which][i * NCH + o] = wi[gi_];
        }
        float2 sv = s0[((b * 8 + p) * 4 + 0) * NCH + o];
        sr[which][o] = sv.x; si[which][o] = sv.y;
    }
    float dr = 0.f, di = 0.f, d8r = 0.f, d8i = 0.f;
    __syncthreads();
    for (int l = 0; l < NLAYERS; ++l) {
        float Fr = 0.f, Fi = 0.f;
        if (active) {
            for (int i = 0; i < NCH; ++i) {
                float a0 = sr[which][i], a1 = si[which][i];
                float b0 = Wr[which][i * NCH + o], b1 = Wi[which][i * NCH + o];
                Fr += a0 * b0 - a1 * b1;
                Fi += a0 * b1 + a1 * b0;
            }
        }
        FL[which][o] = make_float2(Fr, Fi);
        __syncthreads();
        float addr_ = 0.f, addi_ = 0.f;
        if (active) {
            if (g == 0) { addr_ = Fr; addi_ = 0.f; }
            else if (g == 4) {
                addr_ = 0.5f * Fr; addi_ = 0.5f * Fi;
                d8r += 0.5f * Fr;  d8i -= 0.5f * Fi;
            } else {
                float2 Fo = FL[1 - which][o];
                addr_ = 0.5f * (Fr + Fo.x);
                addi_ = 0.5f * (Fi - Fo.y);
            }
            sr[which][o] += addr_; si[which][o] += addi_;
            dr += addr_; di += addi_;
        }
        __syncthreads();
    }
    if (active) dacc[((b * 9 + p) * 4 + 0) * NCH + o] = make_float2(dr, di);
    if (g == 4 && which == 0)
        dacc[((b * 9 + 8) * 4 + 0) * NCH + o] = make_float2(d8r, d8i);
}

// ---------------------------------------------------------------------------
// K4: G[b][h][c][q] = (1/H) * sum_p d[p][q] * e^{+2pi i kx_p h/256}
// block = (b, h-chunk of 64), 256 threads = (c,q)
// ---------------------------------------------------------------------------
__global__ __launch_bounds__(256) void k_gsynth(const float2* __restrict__ dacc,
                                                float2* __restrict__ G)
{
    __shared__ float twr[64][10];
    __shared__ float twi[64][10];
    const int b  = blockIdx.x >> 2;
    const int hc = blockIdx.x & 3;
    const int t  = threadIdx.x;
    const int c  = t & 63;
    const int q  = t >> 6;
    for (int idx = t; idx < 64 * 9; idx += 256) {
        int hh = idx / 9, p = idx - hh * 9;
        int kx = (p == 8) ? 4 : ((p < 4) ? p : p - 8);
        int h  = hc * 64 + hh;
        float a = (float)(kx * h) * (1.0f / 128.0f);
        twr[hh][p] = cospif(a) * (1.0f / 256.0f);
        twi[hh][p] = sinpif(a) * (1.0f / 256.0f);
    }
    float dr_[9], di_[9];
    #pragma unroll
    for (int p = 0; p < 9; ++p) {
        if (p == 8 && q != 0) { dr_[p] = 0.f; di_[p] = 0.f; }
        else {
            float2 v = dacc[((b * 9 + p) * 4 + q) * NCH + c];
            dr_[p] = v.x; di_[p] = v.y;
        }
    }
    __syncthreads();
    for (int hh = 0; hh < 64; ++hh) {
        float gr = 0.f, gi = 0.f;
        #pragma unroll
        for (int p = 0; p < 9; ++p) {
            float tr = twr[hh][p], ti = twi[hh][p];
            gr += dr_[p] * tr - di_[p] * ti;
            gi += dr_[p] * ti + di_[p] * tr;
        }
        int h = hc * 64 + hh;
        G[((b * NH + h) * NCH + c) * NM + q] = make_float2(gr, gi);
    }
}

// ---------------------------------------------------------------------------
// K5: fused final pass. y[c] = 2*h0[c] + (1/W)*(ReG0 + sum_q 2(ReGq cos - ImGq sin))
// then out = dec2( tanh(dec1(y)) ). block = (b,row), 256 threads (one per w).
// ---------------------------------------------------------------------------
__global__ __launch_bounds__(256) void k_final(
    const float* __restrict__ x, const float* __restrict__ enc_w,
    const float* __restrict__ enc_b, const float* __restrict__ dec1_w,
    const float* __restrict__ dec1_b, const float* __restrict__ dec2_w,
    const float* __restrict__ dec2_b, const float2* __restrict__ G,
    float* __restrict__ out)
{
    __shared__ __align__(16) float aG[NCH][4];
    __shared__ __align__(16) float bG[NCH][4];
    __shared__ __align__(16) float wL[NCH * NCH];
    const int b   = blockIdx.x >> 8;
    const int row = blockIdx.x & 255;
    const int t   = threadIdx.x;
    {
        float2 gv = G[(b * NH + row) * NCH * NM + t];
        int c = t >> 2, q = t & 3;
        float coef = (q == 0) ? (1.0f / 256.0f) : (2.0f / 256.0f);
        aG[c][q] = gv.x * coef;
        bG[c][q] = gv.y * coef;
    }
    for (int idx = t; idx < NCH * NCH; idx += 256) wL[idx] = dec1_w[idx];
    __syncthreads();

    const float wf = (float)t;
    const float c1 = cospif(wf * (1.0f / 128.0f)), s1 = sinpif(wf * (1.0f / 128.0f));
    const float c2 = cospif(wf * (2.0f / 128.0f)), s2 = sinpif(wf * (2.0f / 128.0f));
    const float c3 = cospif(wf * (3.0f / 128.0f)), s3 = sinpif(wf * (3.0f / 128.0f));

    const float x0 = x[((b * NCIN + 0) * NH + row) * NW + t];
    const float x1 = x[((b * NCIN + 1) * NH + row) * NW + t];
    const float x2 = x[((b * NCIN + 2) * NH + row) * NW + t];

    float y[NCH];
    #pragma unroll
    for (int c = 0; c < NCH; ++c) {
        float h0 = fast_tanh(enc_b[c] + enc_w[c * 3 + 0] * x0
                           + enc_w[c * 3 + 1] * x1 + enc_w[c * 3 + 2] * x2);
        const float4 ag = *(const float4*)(&aG[c][0]);
        const float4 bg = *(const float4*)(&bG[c][0]);
        float v = 2.0f * h0 + ag.x;          // q=0: cos=1, sin=0 (Im dropped as irfft does)
        v += ag.y * c1 - bg.y * s1;
        v += ag.z * c2 - bg.z * s2;
        v += ag.w * c3 - bg.w * s3;
        y[c] = v;
    }

    float acc = dec2_b[0];
    for (int o = 0; o < NCH; ++o) {
        const float4* wrow = (const float4*)(&wL[o * NCH]);
        float a0 = 0.f, a1 = 0.f, a2 = 0.f, a3 = 0.f;
        #pragma unroll
        for (int c4 = 0; c4 < NCH / 4; ++c4) {
            float4 w4 = wrow[c4];
            a0 += w4.x * y[c4 * 4 + 0];
            a1 += w4.y * y[c4 * 4 + 1];
            a2 += w4.z * y[c4 * 4 + 2];
            a3 += w4.w * y[c4 * 4 + 3];
        }
        float sv = dec1_b[o] + ((a0 + a1) + (a2 + a3));
        acc += dec2_w[o] * fast_tanh(sv);
    }
    out[(b * NH + row) * NW + t] = acc;
}

extern "C" void kernel_launch(void* const* d_in, const int* in_sizes, int n_in,
                              void* d_out, int out_size, void* d_ws, size_t ws_size,
                              hipStream_t stream) {
    (void)in_sizes; (void)n_in; (void)out_size; (void)ws_size;
    const float* x      = (const float*)d_in[0];
    const float* enc_w  = (const float*)d_in[1];
    const float* enc_b  = (const float*)d_in[2];
    const float* dec1_w = (const float*)d_in[3];
    const float* dec1_b = (const float*)d_in[4];
    const float* dec2_w = (const float*)d_in[5];
    const float* dec2_b = (const float*)d_in[6];
    const float* w1r    = (const float*)d_in[7];
    const float* w1i    = (const float*)d_in[8];
    const float* w2r    = (const float*)d_in[9];
    const float* w2i    = (const float*)d_in[10];
    float* out = (float*)d_out;

    char* ws = (char*)d_ws;
    float2* P   = (float2*)(ws);                                   // 8*64*256*4 c = 4 MB
    float2* s0  = (float2*)(ws + 4194304);                         // 8*8*4*64  c = 128 KB
    float2* dd  = (float2*)(ws + 4194304 + 131072);                // 8*9*4*64  c = 144 KB
    float2* G   = (float2*)(ws + 4194304 + 131072 + 147456);       // 8*256*64*4 c = 4 MB

    k_enc_rowdft<<<NB * NH, 256, 0, stream>>>(x, enc_w, enc_b, P);
    k_coldft    <<<NB * NCH, 64, 0, stream>>>(P, s0);
    k_spec_q123 <<<NB * 24, 64, 0, stream>>>(w1r, w1i, w2r, w2i, s0, dd);
    k_spec_q0   <<<NB * 5, 128, 0, stream>>>(w1r, w1i, w2r, w2i, s0, dd);
    k_gsynth    <<<NB * 4, 256, 0, stream>>>(dd, G);
    k_final     <<<NB * NH, 256, 0, stream>>>(x, enc_w, enc_b, dec1_w, dec1_b,
                                              dec2_w, dec2_b, G, out);
}

// Round 2
// 285.139 us; speedup vs baseline: 1.0391x; 1.0391x over previous
//
#include <hip/hip_runtime.h>

#define NB 8
#define NCIN 3
#define NCH 64
#define NH 256
#define NW 256
#define NM 4
#define NLAYERS 6

// tanh(x) = 1 - 2/(1+e^{2x}); __expf -> v_exp_f32. Accurate to ~1e-6 abs.
__device__ __forceinline__ float fast_tanh(float x) {
    float e = __expf(2.0f * x);
    return 1.0f - 2.0f / (1.0f + e);
}

// ---------------------------------------------------------------------------
// K1: encoder (tanh(enc(x))) + row DFT (ky = 0..3) -> P[b][c][row][q] (complex)
// block = (b,row), 256 threads (one per w)
// ---------------------------------------------------------------------------
__global__ __launch_bounds__(256) void k_enc_rowdft(
    const float* __restrict__ x, const float* __restrict__ enc_w,
    const float* __restrict__ enc_b, float2* __restrict__ P)
{
    __shared__ __align__(16) float h0s[NCH][NW + 4];   // +4 pad: float4 reads, 2-way banks
    __shared__ __align__(16) float cT[NM][NW + 4];
    __shared__ __align__(16) float sT[NM][NW + 4];
    const int b   = blockIdx.x >> 8;
    const int row = blockIdx.x & 255;
    const int t   = threadIdx.x;

    // twiddle tables: e^{-2pi i q w / 256}
    for (int idx = t; idx < NM * NW; idx += 256) {
        int q = idx >> 8, w = idx & 255;
        float a = (float)(q * w) * (1.0f / 128.0f);   // 2*q*w/256
        cT[q][w] = cospif(a);
        sT[q][w] = sinpif(a);
    }

    const float x0 = x[((b * NCIN + 0) * NH + row) * NW + t];
    const float x1 = x[((b * NCIN + 1) * NH + row) * NW + t];
    const float x2 = x[((b * NCIN + 2) * NH + row) * NW + t];
    #pragma unroll
    for (int c = 0; c < NCH; ++c) {
        float v = enc_b[c] + enc_w[c * 3 + 0] * x0 + enc_w[c * 3 + 1] * x1
                           + enc_w[c * 3 + 2] * x2;
        h0s[c][t] = fast_tanh(v);
    }
    __syncthreads();

    // thread -> (c,q); sum over w
    const int c = t >> 2, q = t & 3;
    const float4* hv = (const float4*)(&h0s[c][0]);
    const float4* cv = (const float4*)(&cT[q][0]);
    const float4* sv = (const float4*)(&sT[q][0]);
    float re = 0.f, im = 0.f;
    #pragma unroll 8
    for (int w4 = 0; w4 < NW / 4; ++w4) {
        float4 h = hv[w4], cc = cv[w4], ss = sv[w4];
        re += h.x * cc.x + h.y * cc.y + h.z * cc.z + h.w * cc.w;
        im -= h.x * ss.x + h.y * ss.y + h.z * ss.z + h.w * ss.w;
    }
    P[((b * NCH + c) * NH + row) * NM + q] = make_float2(re, im);
}

// ---------------------------------------------------------------------------
// K2: column DFT over rows -> s0[b][p][q][c], p=0..7 <-> kx={0,1,2,3,-4,-3,-2,-1}
// block = (b,c), 64 threads (1 wave), lane handles 4 rows
// ---------------------------------------------------------------------------
__global__ __launch_bounds__(64) void k_coldft(const float2* __restrict__ P,
                                               float2* __restrict__ s0)
{
    const int b    = blockIdx.x >> 6;
    const int c    = blockIdx.x & 63;
    const int lane = threadIdx.x;
    float ar[8][4], ai[8][4];
    #pragma unroll
    for (int p = 0; p < 8; ++p)
        #pragma unroll
        for (int q = 0; q < 4; ++q) { ar[p][q] = 0.f; ai[p][q] = 0.f; }

    const int kxs[8] = {0, 1, 2, 3, -4, -3, -2, -1};
    #pragma unroll
    for (int rr = 0; rr < 4; ++rr) {
        const int row = lane + rr * 64;
        const float4* pp = (const float4*)(&P[((b * NCH + c) * NH + row) * NM]);
        float4 p01 = pp[0], p23 = pp[1];
        float pr[4] = {p01.x, p01.z, p23.x, p23.z};
        float pi[4] = {p01.y, p01.w, p23.y, p23.w};
        #pragma unroll
        for (int p = 0; p < 8; ++p) {
            float a  = (float)(kxs[p] * row) * (1.0f / 128.0f);
            float tr = cospif(a);
            float ti = -sinpif(a);              // e^{-2pi i kx row/256}
            #pragma unroll
            for (int q = 0; q < 4; ++q) {
                ar[p][q] += pr[q] * tr - pi[q] * ti;
                ai[p][q] += pr[q] * ti + pi[q] * tr;
            }
        }
    }
    #pragma unroll
    for (int p = 0; p < 8; ++p)
        #pragma unroll
        for (int q = 0; q < 4; ++q) {
            float vr = ar[p][q], vi = ai[p][q];
            #pragma unroll
            for (int m = 1; m < 64; m <<= 1) {
                vr += __shfl_xor(vr, m);
                vi += __shfl_xor(vi, m);
            }
            ar[p][q] = vr; ai[p][q] = vi;
        }
    if (lane == 0) {
        #pragma unroll
        for (int p = 0; p < 8; ++p)
            #pragma unroll
            for (int q = 0; q < 4; ++q)
                s0[((b * 8 + p) * 4 + q) * NCH + c] = make_float2(ar[p][q], ai[p][q]);
    }
}

// ---------------------------------------------------------------------------
// K3a: spectral iteration for ky=q in {1,2,3} (modes fully independent).
// block = (b,q,p), 64 threads (thread = out channel o). 6 layers in-block.
// d += F each layer; s += F. F[o] = sum_i s[i]*W[i][o] (complex).
// ---------------------------------------------------------------------------
__global__ __launch_bounds__(64) void k_spec_q123(
    const float* __restrict__ w1r, const float* __restrict__ w1i,
    const float* __restrict__ w2r, const float* __restrict__ w2i,
    const float2* __restrict__ s0, float2* __restrict__ dacc)
{
    __shared__ float Wr[NCH * NCH];
    __shared__ float Wi[NCH * NCH];
    __shared__ float sr[NCH], si[NCH];
    const int gx = blockIdx.x;
    const int b  = gx / 24;
    const int r  = gx % 24;
    const int q  = (r >> 3) + 1;
    const int p  = r & 7;
    const int o  = threadIdx.x;
    const float* wr = (p < 4) ? w1r : w2r;
    const float* wi = (p < 4) ? w1i : w2i;
    const int pm = p & 3;
    for (int i = 0; i < NCH; ++i) {
        int gi_ = ((i * NCH + o) * NM + pm) * NM + q;
        Wr[i * NCH + o] = wr[gi_];
        Wi[i * NCH + o] = wi[gi_];
    }
    float2 sv = s0[((b * 8 + p) * 4 + q) * NCH + o];
    sr[o] = sv.x; si[o] = sv.y;
    float dr = 0.f, di = 0.f;
    __syncthreads();
    for (int l = 0; l < NLAYERS; ++l) {
        float Fr = 0.f, Fi = 0.f;
        for (int i = 0; i < NCH; ++i) {
            float a0 = sr[i], a1 = si[i];
            float b0 = Wr[i * NCH + o], b1 = Wi[i * NCH + o];
            Fr += a0 * b0 - a1 * b1;
            Fi += a0 * b1 + a1 * b0;
        }
        __syncthreads();
        sr[o] += Fr; si[o] += Fi;
        dr += Fr; di += Fi;
        __syncthreads();
    }
    dacc[((b * 9 + p) * 4 + q) * NCH + o] = make_float2(dr, di);
}

// ---------------------------------------------------------------------------
// K3b: spectral iteration for ky=0 with irfft Hermitian semantics.
// Groups per b: {p0}, {p1,p7}, {p2,p6}, {p3,p5}, {p4(+leak to kx=+4)}.
// add(p=0)   = (Re F, 0)
// add(pairs) = (F[p] + conj(F[partner]))/2
// add(p=4)   = F/2 ; write-only bin (kx=+4,ky=0) += conj(F)/2  (slot pp=8)
// block = (b,group), 128 threads = (which, o).
// ---------------------------------------------------------------------------
__global__ __launch_bounds__(128) void k_spec_q0(
    const float* __restrict__ w1r, const float* __restrict__ w1i,
    const float* __restrict__ w2r, const float* __restrict__ w2i,
    const float2* __restrict__ s0, float2* __restrict__ dacc)
{
    __shared__ float Wr[2][NCH * NCH];
    __shared__ float Wi[2][NCH * NCH];
    __shared__ float sr[2][NCH], si[2][NCH];
    __shared__ float2 FL[2][NCH];
    const int gx    = blockIdx.x;
    const int b     = gx / 5;
    const int g     = gx % 5;
    const int which = threadIdx.x >> 6;
    const int o     = threadIdx.x & 63;
    int p;
    if (which == 0) p = g;
    else            p = (g == 1) ? 7 : (g == 2) ? 6 : (g == 3) ? 5 : -1;
    const bool active = (p >= 0);
    if (active) {
        const float* wr = (p < 4) ? w1r : w2r;
        const float* wi = (p < 4) ? w1i : w2i;
        const int pm = p & 3;
        for (int i = 0; i < NCH; ++i) {
            int gi_ = ((i * NCH + o) * NM + pm) * NM + 0;
            Wr[which][i * NCH + o] = wr[gi_];
            Wi[which][i * NCH + o] = wi[gi_];
        }
        float2 sv = s0[((b * 8 + p) * 4 + 0) * NCH + o];
        sr[which][o] = sv.x; si[which][o] = sv.y;
    }
    float dr = 0.f, di = 0.f, d8r = 0.f, d8i = 0.f;
    __syncthreads();
    for (int l = 0; l < NLAYERS; ++l) {
        float Fr = 0.f, Fi = 0.f;
        if (active) {
            for (int i = 0; i < NCH; ++i) {
                float a0 = sr[which][i], a1 = si[which][i];
                float b0 = Wr[which][i * NCH + o], b1 = Wi[which][i * NCH + o];
                Fr += a0 * b0 - a1 * b1;
                Fi += a0 * b1 + a1 * b0;
            }
        }
        FL[which][o] = make_float2(Fr, Fi);
        __syncthreads();
        float addr_ = 0.f, addi_ = 0.f;
        if (active) {
            if (g == 0) { addr_ = Fr; addi_ = 0.f; }
            else if (g == 4) {
                addr_ = 0.5f * Fr; addi_ = 0.5f * Fi;
                d8r += 0.5f * Fr;  d8i -= 0.5f * Fi;
            } else {
                float2 Fo = FL[1 - which][o];
                addr_ = 0.5f * (Fr + Fo.x);
                addi_ = 0.5f * (Fi - Fo.y);
            }
            sr[which][o] += addr_; si[which][o] += addi_;
            dr += addr_; di += addi_;
        }
        __syncthreads();
    }
    if (active) dacc[((b * 9 + p) * 4 + 0) * NCH + o] = make_float2(dr, di);
    if (g == 4 && which == 0)
        dacc[((b * 9 + 8) * 4 + 0) * NCH + o] = make_float2(d8r, d8i);
}

// ---------------------------------------------------------------------------
// K5 (fused): per (b,row):
//   1. inline G-synth from dacc (9 kx bins, conjugate-symmetric twiddles)
//   2. y[c] = 2*h0[c] + (1/W)*(ReG0 + sum_q 2(ReGq cos - ImGq sin))
//   3. out = dec2( tanh(dec1(y)) ), dec1 weights via wave-uniform (scalar) loads
// block = (b,row), 256 threads (one per w).
// ---------------------------------------------------------------------------
__global__ __launch_bounds__(256) void k_final(
    const float* __restrict__ x, const float* __restrict__ enc_w,
    const float* __restrict__ enc_b, const float* __restrict__ dec1_w,
    const float* __restrict__ dec1_b, const float* __restrict__ dec2_w,
    const float* __restrict__ dec2_b, const float2* __restrict__ dacc,
    float* __restrict__ out)
{
    __shared__ __align__(16) float aG[NCH][4];
    __shared__ __align__(16) float bG[NCH][4];
    const int b   = blockIdx.x >> 8;
    const int row = blockIdx.x & 255;
    const int t   = threadIdx.x;

    // ---- inline G synthesis: thread t -> (c,q) = (t>>2, t&3) ----
    {
        const int c = t >> 2, q = t & 3;
        const float frow = (float)row * (1.0f / 128.0f);
        // kx twiddles e^{+2pi i kx row/256}; +/-kx are conjugates -> 5 pairs
        float tc[5], ts[5];
        #pragma unroll
        for (int k = 0; k < 5; ++k) {
            float a = (float)k * frow;
            tc[k] = cospif(a);
            ts[k] = sinpif(a);
        }
        // p order: kx = {0,1,2,3,-4,-3,-2,-1,+4}
        float twr[9] = {tc[0], tc[1], tc[2], tc[3], tc[4], tc[3], tc[2], tc[1], tc[4]};
        float twi[9] = {ts[0], ts[1], ts[2], ts[3], -ts[4], -ts[3], -ts[2], -ts[1], ts[4]};
        float gr = 0.f, gi = 0.f;
        #pragma unroll
        for (int p = 0; p < 9; ++p) {
            if (p == 8 && q != 0) continue;      // leak bin exists only at ky=0
            float2 v = dacc[((b * 9 + p) * 4 + q) * NCH + c];
            gr += v.x * twr[p] - v.y * twi[p];
            gi += v.x * twi[p] + v.y * twr[p];
        }
        const float coef = ((q == 0) ? 1.0f : 2.0f) * (1.0f / 65536.0f); // 1/(H*W), x2 Hermitian ky
        aG[c][q] = gr * coef;
        bG[c][q] = gi * coef;
    }
    __syncthreads();

    const float wf = (float)t;
    const float c1 = cospif(wf * (1.0f / 128.0f)), s1 = sinpif(wf * (1.0f / 128.0f));
    const float c2 = cospif(wf * (2.0f / 128.0f)), s2 = sinpif(wf * (2.0f / 128.0f));
    const float c3 = cospif(wf * (3.0f / 128.0f)), s3 = sinpif(wf * (3.0f / 128.0f));

    const float x0 = x[((b * NCIN + 0) * NH + row) * NW + t];
    const float x1 = x[((b * NCIN + 1) * NH + row) * NW + t];
    const float x2 = x[((b * NCIN + 2) * NH + row) * NW + t];

    float y[NCH];
    #pragma unroll
    for (int c = 0; c < NCH; ++c) {
        float h0 = fast_tanh(enc_b[c] + enc_w[c * 3 + 0] * x0
                           + enc_w[c * 3 + 1] * x1 + enc_w[c * 3 + 2] * x2);
        const float4 ag = *(const float4*)(&aG[c][0]);
        const float4 bg = *(const float4*)(&bG[c][0]);
        float v = 2.0f * h0 + ag.x;          // q=0: cos=1, sin=0 (Im dropped as irfft does)
        v += ag.y * c1 - bg.y * s1;
        v += ag.z * c2 - bg.z * s2;
        v += ag.w * c3 - bg.w * s3;
        y[c] = v;
    }

    // dec1 (+tanh) + dec2: weights are wave-uniform -> scalar loads + SGPR-src FMAs
    float acc = dec2_b[0];
    #pragma unroll 4
    for (int o = 0; o < NCH; ++o) {
        const float* __restrict__ wrow = dec1_w + o * NCH;
        float sv0 = dec1_b[o], sv1 = 0.f, sv2 = 0.f, sv3 = 0.f;
        #pragma unroll
        for (int c4 = 0; c4 < NCH / 4; ++c4) {
            sv0 += wrow[c4 * 4 + 0] * y[c4 * 4 + 0];
            sv1 += wrow[c4 * 4 + 1] * y[c4 * 4 + 1];
            sv2 += wrow[c4 * 4 + 2] * y[c4 * 4 + 2];
            sv3 += wrow[c4 * 4 + 3] * y[c4 * 4 + 3];
        }
        float sv = (sv0 + sv1) + (sv2 + sv3);
        acc += dec2_w[o] * fast_tanh(sv);
    }
    out[(b * NH + row) * NW + t] = acc;
}

extern "C" void kernel_launch(void* const* d_in, const int* in_sizes, int n_in,
                              void* d_out, int out_size, void* d_ws, size_t ws_size,
                              hipStream_t stream) {
    (void)in_sizes; (void)n_in; (void)out_size; (void)ws_size;
    const float* x      = (const float*)d_in[0];
    const float* enc_w  = (const float*)d_in[1];
    const float* enc_b  = (const float*)d_in[2];
    const float* dec1_w = (const float*)d_in[3];
    const float* dec1_b = (const float*)d_in[4];
    const float* dec2_w = (const float*)d_in[5];
    const float* dec2_b = (const float*)d_in[6];
    const float* w1r    = (const float*)d_in[7];
    const float* w1i    = (const float*)d_in[8];
    const float* w2r    = (const float*)d_in[9];
    const float* w2i    = (const float*)d_in[10];
    float* out = (float*)d_out;

    char* ws = (char*)d_ws;
    float2* P   = (float2*)(ws);                                   // 8*64*256*4 c = 4 MB
    float2* s0  = (float2*)(ws + 4194304);                         // 8*8*4*64  c = 128 KB
    float2* dd  = (float2*)(ws + 4194304 + 131072);                // 8*9*4*64  c = 144 KB

    k_enc_rowdft<<<NB * NH, 256, 0, stream>>>(x, enc_w, enc_b, P);
    k_coldft    <<<NB * NCH, 64, 0, stream>>>(P, s0);
    k_spec_q123 <<<NB * 24, 64, 0, stream>>>(w1r, w1i, w2r, w2i, s0, dd);
    k_spec_q0   <<<NB * 5, 128, 0, stream>>>(w1r, w1i, w2r, w2i, s0, dd);
    k_final     <<<NB * NH, 256, 0, stream>>>(x, enc_w, enc_b, dec1_w, dec1_b,
                                              dec2_w, dec2_b, dd, out);
}

// Round 3
// 239.085 us; speedup vs baseline: 1.2393x; 1.1926x over previous
//
#include <hip/hip_runtime.h>

#define NB 8
#define NCIN 3
#define NCH 64
#define NH 256
#define NW 256
#define NM 4
#define NLAYERS 6

typedef short s16x8 __attribute__((ext_vector_type(8)));
typedef float f32x4 __attribute__((ext_vector_type(4)));

// tanh(x) = 1 - 2/(1+e^{2x}); __expf -> v_exp_f32. Accurate to ~1e-6 abs.
__device__ __forceinline__ float fast_tanh(float x) {
    float e = __expf(2.0f * x);
    return 1.0f - 2.0f / (1.0f + e);
}

// round-to-nearest-even fp32 -> bf16 bits
__device__ __forceinline__ unsigned short f2bf(float f) {
    unsigned int u = __float_as_uint(f);
    u = u + 0x7fffu + ((u >> 16) & 1u);
    return (unsigned short)(u >> 16);
}
__device__ __forceinline__ float bf2f(unsigned short h) {
    return __uint_as_float(((unsigned int)h) << 16);
}

// ---------------------------------------------------------------------------
// K1: encoder (tanh(enc(x))) + row DFT (ky = 0..3) -> P[b][c][row][q] (complex)
// block = (b,row), 256 threads (one per w)
// ---------------------------------------------------------------------------
__global__ __launch_bounds__(256) void k_enc_rowdft(
    const float* __restrict__ x, const float* __restrict__ enc_w,
    const float* __restrict__ enc_b, float2* __restrict__ P)
{
    __shared__ __align__(16) float h0s[NCH][NW + 4];
    __shared__ __align__(16) float cT[NM][NW + 4];
    __shared__ __align__(16) float sT[NM][NW + 4];
    const int b   = blockIdx.x >> 8;
    const int row = blockIdx.x & 255;
    const int t   = threadIdx.x;

    for (int idx = t; idx < NM * NW; idx += 256) {
        int q = idx >> 8, w = idx & 255;
        float a = (float)(q * w) * (1.0f / 128.0f);
        cT[q][w] = cospif(a);
        sT[q][w] = sinpif(a);
    }

    const float x0 = x[((b * NCIN + 0) * NH + row) * NW + t];
    const float x1 = x[((b * NCIN + 1) * NH + row) * NW + t];
    const float x2 = x[((b * NCIN + 2) * NH + row) * NW + t];
    #pragma unroll
    for (int c = 0; c < NCH; ++c) {
        float v = enc_b[c] + enc_w[c * 3 + 0] * x0 + enc_w[c * 3 + 1] * x1
                           + enc_w[c * 3 + 2] * x2;
        h0s[c][t] = fast_tanh(v);
    }
    __syncthreads();

    const int c = t >> 2, q = t & 3;
    const float4* hv = (const float4*)(&h0s[c][0]);
    const float4* cv = (const float4*)(&cT[q][0]);
    const float4* sv = (const float4*)(&sT[q][0]);
    float re = 0.f, im = 0.f;
    #pragma unroll 8
    for (int w4 = 0; w4 < NW / 4; ++w4) {
        float4 h = hv[w4], cc = cv[w4], ss = sv[w4];
        re += h.x * cc.x + h.y * cc.y + h.z * cc.z + h.w * cc.w;
        im -= h.x * ss.x + h.y * ss.y + h.z * ss.z + h.w * ss.w;
    }
    P[((b * NCH + c) * NH + row) * NM + q] = make_float2(re, im);
}

// ---------------------------------------------------------------------------
// K2: column DFT over rows -> s0[b][p][q][c], p=0..7 <-> kx={0,1,2,3,-4,-3,-2,-1}
// ---------------------------------------------------------------------------
__global__ __launch_bounds__(64) void k_coldft(const float2* __restrict__ P,
                                               float2* __restrict__ s0)
{
    const int b    = blockIdx.x >> 6;
    const int c    = blockIdx.x & 63;
    const int lane = threadIdx.x;
    float ar[8][4], ai[8][4];
    #pragma unroll
    for (int p = 0; p < 8; ++p)
        #pragma unroll
        for (int q = 0; q < 4; ++q) { ar[p][q] = 0.f; ai[p][q] = 0.f; }

    const int kxs[8] = {0, 1, 2, 3, -4, -3, -2, -1};
    #pragma unroll
    for (int rr = 0; rr < 4; ++rr) {
        const int row = lane + rr * 64;
        const float4* pp = (const float4*)(&P[((b * NCH + c) * NH + row) * NM]);
        float4 p01 = pp[0], p23 = pp[1];
        float pr[4] = {p01.x, p01.z, p23.x, p23.z};
        float pi[4] = {p01.y, p01.w, p23.y, p23.w};
        #pragma unroll
        for (int p = 0; p < 8; ++p) {
            float a  = (float)(kxs[p] * row) * (1.0f / 128.0f);
            float tr = cospif(a);
            float ti = -sinpif(a);
            #pragma unroll
            for (int q = 0; q < 4; ++q) {
                ar[p][q] += pr[q] * tr - pi[q] * ti;
                ai[p][q] += pr[q] * ti + pi[q] * tr;
            }
        }
    }
    #pragma unroll
    for (int p = 0; p < 8; ++p)
        #pragma unroll
        for (int q = 0; q < 4; ++q) {
            float vr = ar[p][q], vi = ai[p][q];
            #pragma unroll
            for (int m = 1; m < 64; m <<= 1) {
                vr += __shfl_xor(vr, m);
                vi += __shfl_xor(vi, m);
            }
            ar[p][q] = vr; ai[p][q] = vi;
        }
    if (lane == 0) {
        #pragma unroll
        for (int p = 0; p < 8; ++p)
            #pragma unroll
            for (int q = 0; q < 4; ++q)
                s0[((b * 8 + p) * 4 + q) * NCH + c] = make_float2(ar[p][q], ai[p][q]);
    }
}

// ---------------------------------------------------------------------------
// K3a: spectral iteration for ky=q in {1,2,3}
// ---------------------------------------------------------------------------
__global__ __launch_bounds__(64) void k_spec_q123(
    const float* __restrict__ w1r, const float* __restrict__ w1i,
    const float* __restrict__ w2r, const float* __restrict__ w2i,
    const float2* __restrict__ s0, float2* __restrict__ dacc)
{
    __shared__ float Wr[NCH * NCH];
    __shared__ float Wi[NCH * NCH];
    __shared__ float sr[NCH], si[NCH];
    const int gx = blockIdx.x;
    const int b  = gx / 24;
    const int r  = gx % 24;
    const int q  = (r >> 3) + 1;
    const int p  = r & 7;
    const int o  = threadIdx.x;
    const float* wr = (p < 4) ? w1r : w2r;
    const float* wi = (p < 4) ? w1i : w2i;
    const int pm = p & 3;
    for (int i = 0; i < NCH; ++i) {
        int gi_ = ((i * NCH + o) * NM + pm) * NM + q;
        Wr[i * NCH + o] = wr[gi_];
        Wi[i * NCH + o] = wi[gi_];
    }
    float2 sv = s0[((b * 8 + p) * 4 + q) * NCH + o];
    sr[o] = sv.x; si[o] = sv.y;
    float dr = 0.f, di = 0.f;
    __syncthreads();
    for (int l = 0; l < NLAYERS; ++l) {
        float Fr = 0.f, Fi = 0.f;
        for (int i = 0; i < NCH; ++i) {
            float a0 = sr[i], a1 = si[i];
            float b0 = Wr[i * NCH + o], b1 = Wi[i * NCH + o];
            Fr += a0 * b0 - a1 * b1;
            Fi += a0 * b1 + a1 * b0;
        }
        __syncthreads();
        sr[o] += Fr; si[o] += Fi;
        dr += Fr; di += Fi;
        __syncthreads();
    }
    dacc[((b * 9 + p) * 4 + q) * NCH + o] = make_float2(dr, di);
}

// ---------------------------------------------------------------------------
// K3b: spectral iteration for ky=0 with irfft Hermitian semantics.
// ---------------------------------------------------------------------------
__global__ __launch_bounds__(128) void k_spec_q0(
    const float* __restrict__ w1r, const float* __restrict__ w1i,
    const float* __restrict__ w2r, const float* __restrict__ w2i,
    const float2* __restrict__ s0, float2* __restrict__ dacc)
{
    __shared__ float Wr[2][NCH * NCH];
    __shared__ float Wi[2][NCH * NCH];
    __shared__ float sr[2][NCH], si[2][NCH];
    __shared__ float2 FL[2][NCH];
    const int gx    = blockIdx.x;
    const int b     = gx / 5;
    const int g     = gx % 5;
    const int which = threadIdx.x >> 6;
    const int o     = threadIdx.x & 63;
    int p;
    if (which == 0) p = g;
    else            p = (g == 1) ? 7 : (g == 2) ? 6 : (g == 3) ? 5 : -1;
    const bool active = (p >= 0);
    if (active) {
        const float* wr = (p < 4) ? w1r : w2r;
        const float* wi = (p < 4) ? w1i : w2i;
        const int pm = p & 3;
        for (int i = 0; i < NCH; ++i) {
            int gi_ = ((i * NCH + o) * NM + pm) * NM + 0;
            Wr[which][i * NCH + o] = wr[gi_];
            Wi[which][i * NCH + o] = wi[gi_];
        }
        float2 sv = s0[((b * 8 + p) * 4 + 0) * NCH + o];
        sr[which][o] = sv.x; si[which][o] = sv.y;
    }
    float dr = 0.f, di = 0.f, d8r = 0.f, d8i = 0.f;
    __syncthreads();
    for (int l = 0; l < NLAYERS; ++l) {
        float Fr = 0.f, Fi = 0.f;
        if (active) {
            for (int i = 0; i < NCH; ++i) {
                float a0 = sr[which][i], a1 = si[which][i];
                float b0 = Wr[which][i * NCH + o], b1 = Wi[which][i * NCH + o];
                Fr += a0 * b0 - a1 * b1;
                Fi += a0 * b1 + a1 * b0;
            }
        }
        FL[which][o] = make_float2(Fr, Fi);
        __syncthreads();
        float addr_ = 0.f, addi_ = 0.f;
        if (active) {
            if (g == 0) { addr_ = Fr; addi_ = 0.f; }
            else if (g == 4) {
                addr_ = 0.5f * Fr; addi_ = 0.5f * Fi;
                d8r += 0.5f * Fr;  d8i -= 0.5f * Fi;
            } else {
                float2 Fo = FL[1 - which][o];
                addr_ = 0.5f * (Fr + Fo.x);
                addi_ = 0.5f * (Fi - Fo.y);
            }
            sr[which][o] += addr_; si[which][o] += addi_;
            dr += addr_; di += addi_;
        }
        __syncthreads();
    }
    if (active) dacc[((b * 9 + p) * 4 + 0) * NCH + o] = make_float2(dr, di);
    if (g == 4 && which == 0)
        dacc[((b * 9 + 8) * 4 + 0) * NCH + o] = make_float2(d8r, d8i);
}

// ---------------------------------------------------------------------------
// K5 (MFMA): block = (b,row,half) covering 128 pixels.
//   phase0: stage dec1_w as bf16 hi/lo (swizzled LDS) + G-coef synth from dacc
//   phase1: y[c] = 2*h0 + spectral corr (fp32), split to bf16 hi/lo -> LDS A
//   phase2: sv = A @ W via 3-term bf16 MFMA (Ahi*Whi + Alo*Whi + Ahi*Wlo)
//   phase3: out = dec2_b + sum_o dec2_w[o]*tanh(sv+dec1_b[o]) (shfl-reduce)
// ---------------------------------------------------------------------------
__global__ __launch_bounds__(256) void k_final(
    const float* __restrict__ x, const float* __restrict__ enc_w,
    const float* __restrict__ enc_b, const float* __restrict__ dec1_w,
    const float* __restrict__ dec1_b, const float* __restrict__ dec2_w,
    const float* __restrict__ dec2_b, const float2* __restrict__ dacc,
    float* __restrict__ out)
{
    __shared__ __align__(16) unsigned short Ahi[128 * NCH];   // 16 KB
    __shared__ __align__(16) unsigned short Alo[128 * NCH];   // 16 KB
    __shared__ __align__(16) unsigned short Whi[NCH * NCH];   // 8 KB
    __shared__ __align__(16) unsigned short Wlo[NCH * NCH];   // 8 KB
    __shared__ __align__(16) float aGs[NCH][4];
    __shared__ __align__(16) float bGs[NCH][4];

    const int bi   = blockIdx.x;
    const int b    = bi >> 9;
    const int rem  = bi & 511;
    const int row  = rem >> 1;
    const int half = rem & 1;
    const int t    = threadIdx.x;

    // ---- stage dec1_w -> bf16 hi/lo, XOR-swizzled rows ----
    {
        const int o  = t >> 2;
        const int cb = (t & 3) * 16;
        const float* wr = dec1_w + o * NCH + cb;
        #pragma unroll
        for (int chunk = 0; chunk < 2; ++chunk) {
            float4 wa = ((const float4*)wr)[chunk * 2 + 0];
            float4 wb = ((const float4*)wr)[chunk * 2 + 1];
            float v[8] = {wa.x, wa.y, wa.z, wa.w, wb.x, wb.y, wb.z, wb.w};
            unsigned int ph[4], pl[4];
            #pragma unroll
            for (int j = 0; j < 4; ++j) {
                unsigned short h0b = f2bf(v[2 * j]);
                unsigned short h1b = f2bf(v[2 * j + 1]);
                unsigned short l0b = f2bf(v[2 * j] - bf2f(h0b));
                unsigned short l1b = f2bf(v[2 * j + 1] - bf2f(h1b));
                ph[j] = (unsigned int)h0b | ((unsigned int)h1b << 16);
                pl[j] = (unsigned int)l0b | ((unsigned int)l1b << 16);
            }
            int byteoff = (o * 128 + (cb + chunk * 8) * 2) ^ ((o & 7) << 4);
            *(uint4*)((char*)Whi + byteoff) = make_uint4(ph[0], ph[1], ph[2], ph[3]);
            *(uint4*)((char*)Wlo + byteoff) = make_uint4(pl[0], pl[1], pl[2], pl[3]);
        }
    }

    // ---- G-coef synthesis: thread t -> (c,q) = (t>>2, t&3) ----
    {
        const int c = t >> 2, q = t & 3;
        const float frow = (float)row * (1.0f / 128.0f);
        float tc[5], ts[5];
        #pragma unroll
        for (int k = 0; k < 5; ++k) {
            float a = (float)k * frow;
            tc[k] = cospif(a);
            ts[k] = sinpif(a);
        }
        float twr[9] = {tc[0], tc[1], tc[2], tc[3], tc[4], tc[3], tc[2], tc[1], tc[4]};
        float twi[9] = {ts[0], ts[1], ts[2], ts[3], -ts[4], -ts[3], -ts[2], -ts[1], ts[4]};
        float gr = 0.f, gi = 0.f;
        #pragma unroll
        for (int p = 0; p < 9; ++p) {
            if (p == 8 && q != 0) continue;
            float2 v = dacc[((b * 9 + p) * 4 + q) * NCH + c];
            gr += v.x * twr[p] - v.y * twi[p];
            gi += v.x * twi[p] + v.y * twr[p];
        }
        const float coef = ((q == 0) ? 1.0f : 2.0f) * (1.0f / 65536.0f);
        aGs[c][q] = gr * coef;
        bGs[c][q] = gi * coef;
    }
    __syncthreads();

    // ---- phase1: y assembly (fp32) -> bf16 hi/lo into A ----
    {
        const int p   = t & 127;          // pixel within block
        const int ch0 = (t >> 7) * 32;    // this thread's channel half
        const int wg  = half * 128 + p;   // global w
        const float wf = (float)wg;
        const float c1 = cospif(wf * (1.0f / 128.0f)), s1 = sinpif(wf * (1.0f / 128.0f));
        const float c2 = cospif(wf * (2.0f / 128.0f)), s2 = sinpif(wf * (2.0f / 128.0f));
        const float c3 = cospif(wf * (3.0f / 128.0f)), s3 = sinpif(wf * (3.0f / 128.0f));
        const float x0 = x[((b * NCIN + 0) * NH + row) * NW + wg];
        const float x1 = x[((b * NCIN + 1) * NH + row) * NW + wg];
        const float x2 = x[((b * NCIN + 2) * NH + row) * NW + wg];

        #pragma unroll
        for (int u = 0; u < 4; ++u) {
            unsigned int ph[4], pl[4];
            #pragma unroll
            for (int j2 = 0; j2 < 4; ++j2) {
                unsigned short hh[2], ll[2];
                #pragma unroll
                for (int e = 0; e < 2; ++e) {
                    int c = ch0 + u * 8 + j2 * 2 + e;
                    float h0 = fast_tanh(enc_b[c] + enc_w[c * 3 + 0] * x0
                                       + enc_w[c * 3 + 1] * x1 + enc_w[c * 3 + 2] * x2);
                    float4 ag = *(const float4*)(&aGs[c][0]);
                    float4 bg = *(const float4*)(&bGs[c][0]);
                    float v = 2.0f * h0 + ag.x;
                    v += ag.y * c1 - bg.y * s1;
                    v += ag.z * c2 - bg.z * s2;
                    v += ag.w * c3 - bg.w * s3;
                    unsigned short hb = f2bf(v);
                    hh[e] = hb;
                    ll[e] = f2bf(v - bf2f(hb));
                }
                ph[j2] = (unsigned int)hh[0] | ((unsigned int)hh[1] << 16);
                pl[j2] = (unsigned int)ll[0] | ((unsigned int)ll[1] << 16);
            }
            int byteoff = (p * 128 + (ch0 + u * 8) * 2) ^ ((p & 7) << 4);
            *(uint4*)((char*)Ahi + byteoff) = make_uint4(ph[0], ph[1], ph[2], ph[3]);
            *(uint4*)((char*)Alo + byteoff) = make_uint4(pl[0], pl[1], pl[2], pl[3]);
        }
    }
    __syncthreads();

    // ---- phase2: MFMA. wave wv handles m-tiles {wv*2, wv*2+1} ----
    const int lane = t & 63;
    const int wv   = t >> 6;
    f32x4 acc[2][4];
    #pragma unroll
    for (int i = 0; i < 2; ++i)
        #pragma unroll
        for (int nt = 0; nt < 4; ++nt)
            #pragma unroll
            for (int e = 0; e < 4; ++e) acc[i][nt][e] = 0.f;

    #pragma unroll
    for (int ks = 0; ks < 2; ++ks) {
        s16x8 ahi[2], alo[2];
        #pragma unroll
        for (int i = 0; i < 2; ++i) {
            int m = (wv * 2 + i) * 16 + (lane & 15);
            int byteoff = (m * 128 + ks * 64 + (lane >> 4) * 16) ^ ((m & 7) << 4);
            ahi[i] = *(const s16x8*)((const char*)Ahi + byteoff);
            alo[i] = *(const s16x8*)((const char*)Alo + byteoff);
        }
        #pragma unroll
        for (int nt = 0; nt < 4; ++nt) {
            int o = nt * 16 + (lane & 15);
            int byteoff = (o * 128 + ks * 64 + (lane >> 4) * 16) ^ ((o & 7) << 4);
            s16x8 whi = *(const s16x8*)((const char*)Whi + byteoff);
            s16x8 wlo = *(const s16x8*)((const char*)Wlo + byteoff);
            #pragma unroll
            for (int i = 0; i < 2; ++i) {
                acc[i][nt] = __builtin_amdgcn_mfma_f32_16x16x32_bf16(ahi[i], whi, acc[i][nt], 0, 0, 0);
                acc[i][nt] = __builtin_amdgcn_mfma_f32_16x16x32_bf16(alo[i], whi, acc[i][nt], 0, 0, 0);
                acc[i][nt] = __builtin_amdgcn_mfma_f32_16x16x32_bf16(ahi[i], wlo, acc[i][nt], 0, 0, 0);
            }
        }
    }

    // ---- phase3: epilogue. D[m][n]: m=(lane>>4)*4+r (pixel), n=lane&15 (o) ----
    float d1b[4], d2w[4];
    #pragma unroll
    for (int nt = 0; nt < 4; ++nt) {
        int o = nt * 16 + (lane & 15);
        d1b[nt] = dec1_b[o];
        d2w[nt] = dec2_w[o];
    }
    const float d2b = dec2_b[0];
    float* orow = out + (b * NH + row) * NW;

    #pragma unroll
    for (int i = 0; i < 2; ++i) {
        float resv[4];
        #pragma unroll
        for (int r = 0; r < 4; ++r) {
            float partial = 0.f;
            #pragma unroll
            for (int nt = 0; nt < 4; ++nt) {
                float svv = acc[i][nt][r] + d1b[nt];
                partial += d2w[nt] * fast_tanh(svv);
            }
            partial += __shfl_xor(partial, 1);
            partial += __shfl_xor(partial, 2);
            partial += __shfl_xor(partial, 4);
            partial += __shfl_xor(partial, 8);
            resv[r] = partial;
        }
        if ((lane & 15) == 0) {
            int pbase = half * 128 + (wv * 2 + i) * 16 + (lane >> 4) * 4;
            #pragma unroll
            for (int r = 0; r < 4; ++r)
                orow[pbase + r] = d2b + resv[r];
        }
    }
}

extern "C" void kernel_launch(void* const* d_in, const int* in_sizes, int n_in,
                              void* d_out, int out_size, void* d_ws, size_t ws_size,
                              hipStream_t stream) {
    (void)in_sizes; (void)n_in; (void)out_size; (void)ws_size;
    const float* x      = (const float*)d_in[0];
    const float* enc_w  = (const float*)d_in[1];
    const float* enc_b  = (const float*)d_in[2];
    const float* dec1_w = (const float*)d_in[3];
    const float* dec1_b = (const float*)d_in[4];
    const float* dec2_w = (const float*)d_in[5];
    const float* dec2_b = (const float*)d_in[6];
    const float* w1r    = (const float*)d_in[7];
    const float* w1i    = (const float*)d_in[8];
    const float* w2r    = (const float*)d_in[9];
    const float* w2i    = (const float*)d_in[10];
    float* out = (float*)d_out;

    char* ws = (char*)d_ws;
    float2* P   = (float2*)(ws);                                   // 4 MB
    float2* s0  = (float2*)(ws + 4194304);                         // 128 KB
    float2* dd  = (float2*)(ws + 4194304 + 131072);                // 144 KB

    k_enc_rowdft<<<NB * NH, 256, 0, stream>>>(x, enc_w, enc_b, P);
    k_coldft    <<<NB * NCH, 64, 0, stream>>>(P, s0);
    k_spec_q123 <<<NB * 24, 64, 0, stream>>>(w1r, w1i, w2r, w2i, s0, dd);
    k_spec_q0   <<<NB * 5, 128, 0, stream>>>(w1r, w1i, w2r, w2i, s0, dd);
    k_final     <<<NB * NH * 2, 256, 0, stream>>>(x, enc_w, enc_b, dec1_w, dec1_b,
                                                  dec2_w, dec2_b, dd, out);
}

// Round 4
// 238.682 us; speedup vs baseline: 1.2413x; 1.0017x over previous
//
#include <hip/hip_runtime.h>

#define NB 8
#define NCIN 3
#define NCH 64
#define NH 256
#define NW 256
#define NM 4
#define NLAYERS 6

typedef short s16x8 __attribute__((ext_vector_type(8)));
typedef float f32x4 __attribute__((ext_vector_type(4)));

// tanh(x) = 1 - 2/(1+e^{2x}); __expf -> v_exp_f32.
__device__ __forceinline__ float fast_tanh(float x) {
    float e = __expf(2.0f * x);
    return 1.0f - 2.0f / (1.0f + e);
}
// sin/cos of (2*pi*x): raw v_sin/v_cos, input in revolutions (|x|<5 here)
__device__ __forceinline__ float sin2pi(float x) { return __builtin_amdgcn_sinf(x); }
__device__ __forceinline__ float cos2pi(float x) { return __builtin_amdgcn_cosf(x); }

// round-to-nearest-even fp32 -> bf16 bits
__device__ __forceinline__ unsigned short f2bf(float f) {
    unsigned int u = __float_as_uint(f);
    u = u + 0x7fffu + ((u >> 16) & 1u);
    return (unsigned short)(u >> 16);
}
__device__ __forceinline__ float bf2f(unsigned short h) {
    return __uint_as_float(((unsigned int)h) << 16);
}
__device__ __forceinline__ unsigned int pack2bf(float a, float b) {
    return (unsigned int)f2bf(a) | ((unsigned int)f2bf(b) << 16);
}

// ---------------------------------------------------------------------------
// K0: one-block prep kernel.
//  Wpk: dec1_w as bf16 hi/lo planes (8KB each), XOR-swizzled ((o&7)<<4) image
//       matching k_final's LDS layout (linear copy there).
//  Tpk: row-DFT twiddle B-matrix fragments: [plane hi/lo][n=16][w=256] bf16,
//       T[w][n<4]=cos(2pi n w/256), T[w][4..7]=-sin(2pi (n-4) w/256), else 0.
//  encwb: [64][4] = {enc_w[c][0..2], enc_b[c]}
// ---------------------------------------------------------------------------
__global__ __launch_bounds__(256) void k_wprep(
    const float* __restrict__ dec1_w, const float* __restrict__ enc_w,
    const float* __restrict__ enc_b, unsigned short* __restrict__ Wpk,
    unsigned short* __restrict__ Tpk, float* __restrict__ encwb)
{
    const int t = threadIdx.x;
    // --- Wpk ---
    {
        const int o  = t & 63;
        const int cb = (t >> 6) * 16;
        #pragma unroll
        for (int ch = 0; ch < 2; ++ch) {
            const float* wr = dec1_w + o * NCH + cb + ch * 8;
            float4 wa = ((const float4*)wr)[0];
            float4 wb = ((const float4*)wr)[1];
            float v[8] = {wa.x, wa.y, wa.z, wa.w, wb.x, wb.y, wb.z, wb.w};
            unsigned int ph[4], pl[4];
            #pragma unroll
            for (int j = 0; j < 4; ++j) {
                unsigned short h0 = f2bf(v[2 * j]), h1 = f2bf(v[2 * j + 1]);
                ph[j] = (unsigned int)h0 | ((unsigned int)h1 << 16);
                pl[j] = pack2bf(v[2 * j] - bf2f(h0), v[2 * j + 1] - bf2f(h1));
            }
            int byteoff = (o * 128 + (cb + ch * 8) * 2) ^ ((o & 7) << 4);
            *(uint4*)((char*)Wpk + byteoff)        = make_uint4(ph[0], ph[1], ph[2], ph[3]);
            *(uint4*)((char*)Wpk + 8192 + byteoff) = make_uint4(pl[0], pl[1], pl[2], pl[3]);
        }
    }
    // --- Tpk ---
    {
        const int n  = t & 15;
        const int w0 = (t >> 4) * 16;
        #pragma unroll
        for (int ch = 0; ch < 2; ++ch) {
            unsigned int ph[4], pl[4];
            #pragma unroll
            for (int j = 0; j < 4; ++j) {
                float vv[2];
                #pragma unroll
                for (int e = 0; e < 2; ++e) {
                    int w = w0 + ch * 8 + j * 2 + e;
                    float val = 0.f;
                    if (n < 4)      val = cos2pi((float)(n * w) * (1.0f / 256.0f));
                    else if (n < 8) val = -sin2pi((float)((n - 4) * w) * (1.0f / 256.0f));
                    vv[e] = val;
                }
                unsigned short h0 = f2bf(vv[0]), h1 = f2bf(vv[1]);
                ph[j] = (unsigned int)h0 | ((unsigned int)h1 << 16);
                pl[j] = pack2bf(vv[0] - bf2f(h0), vv[1] - bf2f(h1));
            }
            int idx = n * 256 + w0 + ch * 8;      // elements
            *(uint4*)(Tpk + idx)            = make_uint4(ph[0], ph[1], ph[2], ph[3]);
            *(uint4*)(Tpk + 16 * 256 + idx) = make_uint4(pl[0], pl[1], pl[2], pl[3]);
        }
    }
    // --- encwb ---
    if (t < NCH) {
        float4 e4;
        e4.x = enc_w[t * 3 + 0]; e4.y = enc_w[t * 3 + 1];
        e4.z = enc_w[t * 3 + 2]; e4.w = enc_b[t];
        ((float4*)encwb)[t] = e4;
    }
}

// ---------------------------------------------------------------------------
// K1: encoder + row DFT on MFMA. block=(b,row,wh) covers 128 w.
//  phase1: h0 (fp32 tanh) -> bf16 hi/lo LDS tile [c=64][wl=128], swz (c&15)<<4
//  phase2: D[c][n] = sum_w h0*T : wave v = c-tile v; 4 k-steps x 3-term MFMA
//  out: P2[wh][b][c][row][q][reim] fp32 partial sums (summed in k_coldft)
// ---------------------------------------------------------------------------
__global__ __launch_bounds__(256) void k_enc_mfma(
    const float* __restrict__ x, const float* __restrict__ encwb,
    const unsigned short* __restrict__ Tpk, float* __restrict__ P2)
{
    __shared__ __align__(16) unsigned short Ah[64 * 128];  // 16 KB
    __shared__ __align__(16) unsigned short Al[64 * 128];  // 16 KB
    const int bi  = blockIdx.x;
    const int b   = bi >> 9;
    const int rem = bi & 511;
    const int row = rem >> 1;
    const int wh  = rem & 1;
    const int t   = threadIdx.x;

    // phase1: thread -> c = t&63, local w chunk (t>>6)*32
    {
        const int c   = t & 63;
        const int wl0 = (t >> 6) * 32;
        float4 ewb = ((const float4*)encwb)[c];
        const float* xr0 = x + ((b * 3 + 0) * NH + row) * NW + wh * 128 + wl0;
        const float* xr1 = x + ((b * 3 + 1) * NH + row) * NW + wh * 128 + wl0;
        const float* xr2 = x + ((b * 3 + 2) * NH + row) * NW + wh * 128 + wl0;
        #pragma unroll
        for (int u = 0; u < 4; ++u) {
            float4 a0 = ((const float4*)xr0)[u * 2], b0 = ((const float4*)xr0)[u * 2 + 1];
            float4 a1 = ((const float4*)xr1)[u * 2], b1 = ((const float4*)xr1)[u * 2 + 1];
            float4 a2 = ((const float4*)xr2)[u * 2], b2 = ((const float4*)xr2)[u * 2 + 1];
            float hv[8];
            hv[0] = fast_tanh(ewb.w + ewb.x * a0.x + ewb.y * a1.x + ewb.z * a2.x);
            hv[1] = fast_tanh(ewb.w + ewb.x * a0.y + ewb.y * a1.y + ewb.z * a2.y);
            hv[2] = fast_tanh(ewb.w + ewb.x * a0.z + ewb.y * a1.z + ewb.z * a2.z);
            hv[3] = fast_tanh(ewb.w + ewb.x * a0.w + ewb.y * a1.w + ewb.z * a2.w);
            hv[4] = fast_tanh(ewb.w + ewb.x * b0.x + ewb.y * b1.x + ewb.z * b2.x);
            hv[5] = fast_tanh(ewb.w + ewb.x * b0.y + ewb.y * b1.y + ewb.z * b2.y);
            hv[6] = fast_tanh(ewb.w + ewb.x * b0.z + ewb.y * b1.z + ewb.z * b2.z);
            hv[7] = fast_tanh(ewb.w + ewb.x * b0.w + ewb.y * b1.w + ewb.z * b2.w);
            unsigned int ph[4], pl[4];
            #pragma unroll
            for (int j = 0; j < 4; ++j) {
                unsigned short h0 = f2bf(hv[2 * j]), h1 = f2bf(hv[2 * j + 1]);
                ph[j] = (unsigned int)h0 | ((unsigned int)h1 << 16);
                pl[j] = pack2bf(hv[2 * j] - bf2f(h0), hv[2 * j + 1] - bf2f(h1));
            }
            int byteoff = (c * 256 + (wl0 + u * 8) * 2) ^ ((c & 15) << 4);
            *(uint4*)((char*)Ah + byteoff) = make_uint4(ph[0], ph[1], ph[2], ph[3]);
            *(uint4*)((char*)Al + byteoff) = make_uint4(pl[0], pl[1], pl[2], pl[3]);
        }
    }
    __syncthreads();

    // phase2: wave v = c-tile; lane: n = li, k-group g
    const int lane = t & 63;
    const int v    = t >> 6;
    const int li   = lane & 15;
    const int g    = lane >> 4;
    f32x4 acc = {0.f, 0.f, 0.f, 0.f};
    #pragma unroll
    for (int kk = 0; kk < 4; ++kk) {
        int cm = v * 16 + li;
        int coff = (cm * 256 + (kk * 32 + g * 8) * 2) ^ ((cm & 15) << 4);
        s16x8 ah = *(const s16x8*)((const char*)Ah + coff);
        s16x8 al = *(const s16x8*)((const char*)Al + coff);
        int wg = wh * 128 + kk * 32 + g * 8;
        s16x8 bh = *(const s16x8*)(Tpk + li * 256 + wg);
        s16x8 bl = *(const s16x8*)(Tpk + (16 + li) * 256 + wg);
        acc = __builtin_amdgcn_mfma_f32_16x16x32_bf16(ah, bh, acc, 0, 0, 0);
        acc = __builtin_amdgcn_mfma_f32_16x16x32_bf16(al, bh, acc, 0, 0, 0);
        acc = __builtin_amdgcn_mfma_f32_16x16x32_bf16(ah, bl, acc, 0, 0, 0);
    }
    // store: n=li (<8 meaningful): q=n&3, reim=n>>2 ; c = v*16 + g*4 + e
    if (li < 8) {
        const int q = li & 3, reim = li >> 2;
        float* pbase = P2 + (size_t)wh * (NB * 64 * 256 * 8);
        #pragma unroll
        for (int e = 0; e < 4; ++e) {
            int c = v * 16 + g * 4 + e;
            pbase[(((b * 64 + c) * 256 + row) * 4 + q) * 2 + reim] = acc[e];
        }
    }
}

// ---------------------------------------------------------------------------
// K2: column DFT over rows (sums the two w-half partials) -> s0[b][p][q][c]
// ---------------------------------------------------------------------------
__global__ __launch_bounds__(64) void k_coldft(const float* __restrict__ P2,
                                               float2* __restrict__ s0)
{
    const int b    = blockIdx.x >> 6;
    const int c    = blockIdx.x & 63;
    const int lane = threadIdx.x;
    float ar[8][4], ai[8][4];
    #pragma unroll
    for (int p = 0; p < 8; ++p)
        #pragma unroll
        for (int q = 0; q < 4; ++q) { ar[p][q] = 0.f; ai[p][q] = 0.f; }

    const int kxs[8] = {0, 1, 2, 3, -4, -3, -2, -1};
    #pragma unroll
    for (int rr = 0; rr < 4; ++rr) {
        const int row = lane + rr * 64;
        const float* pb = P2 + ((b * 64 + c) * 256 + row) * 8;
        float4 v0 = ((const float4*)pb)[0], v1 = ((const float4*)pb)[1];
        float4 w0 = ((const float4*)(pb + NB * 64 * 256 * 8))[0];
        float4 w1 = ((const float4*)(pb + NB * 64 * 256 * 8))[1];
        float pr[4] = {v0.x + w0.x, v0.z + w0.z, v1.x + w1.x, v1.z + w1.z};
        float pi[4] = {v0.y + w0.y, v0.w + w0.w, v1.y + w1.y, v1.w + w1.w};
        float tc[5], ts[5];
        tc[0] = 1.f; ts[0] = 0.f;
        #pragma unroll
        for (int k = 1; k < 5; ++k) {
            float a = (float)(k * row) * (1.0f / 256.0f);
            tc[k] = cos2pi(a); ts[k] = sin2pi(a);
        }
        #pragma unroll
        for (int p = 0; p < 8; ++p) {
            int k = kxs[p] < 0 ? -kxs[p] : kxs[p];
            float tr = tc[k];
            float ti = (kxs[p] < 0) ? ts[k] : -ts[k];   // e^{-2pi i kx row/256}
            #pragma unroll
            for (int q = 0; q < 4; ++q) {
                ar[p][q] += pr[q] * tr - pi[q] * ti;
                ai[p][q] += pr[q] * ti + pi[q] * tr;
            }
        }
    }
    #pragma unroll
    for (int p = 0; p < 8; ++p)
        #pragma unroll
        for (int q = 0; q < 4; ++q) {
            float vr = ar[p][q], vi = ai[p][q];
            #pragma unroll
            for (int m = 1; m < 64; m <<= 1) {
                vr += __shfl_xor(vr, m);
                vi += __shfl_xor(vi, m);
            }
            ar[p][q] = vr; ai[p][q] = vi;
        }
    if (lane == 0) {
        #pragma unroll
        for (int p = 0; p < 8; ++p)
            #pragma unroll
            for (int q = 0; q < 4; ++q)
                s0[((b * 8 + p) * 4 + q) * NCH + c] = make_float2(ar[p][q], ai[p][q]);
    }
}

// ---------------------------------------------------------------------------
// K3a: spectral iteration for ky=q in {1,2,3}
// ---------------------------------------------------------------------------
__global__ __launch_bounds__(64) void k_spec_q123(
    const float* __restrict__ w1r, const float* __restrict__ w1i,
    const float* __restrict__ w2r, const float* __restrict__ w2i,
    const float2* __restrict__ s0, float2* __restrict__ dacc)
{
    __shared__ float Wr[NCH * NCH];
    __shared__ float Wi[NCH * NCH];
    __shared__ float sr[NCH], si[NCH];
    const int gx = blockIdx.x;
    const int b  = gx / 24;
    const int r  = gx % 24;
    const int q  = (r >> 3) + 1;
    const int p  = r & 7;
    const int o  = threadIdx.x;
    const float* wr = (p < 4) ? w1r : w2r;
    const float* wi = (p < 4) ? w1i : w2i;
    const int pm = p & 3;
    for (int i = 0; i < NCH; ++i) {
        int gi_ = ((i * NCH + o) * NM + pm) * NM + q;
        Wr[i * NCH + o] = wr[gi_];
        Wi[i * NCH + o] = wi[gi_];
    }
    float2 sv = s0[((b * 8 + p) * 4 + q) * NCH + o];
    sr[o] = sv.x; si[o] = sv.y;
    float dr = 0.f, di = 0.f;
    __syncthreads();
    for (int l = 0; l < NLAYERS; ++l) {
        float Fr = 0.f, Fi = 0.f;
        for (int i = 0; i < NCH; ++i) {
            float a0 = sr[i], a1 = si[i];
            float b0 = Wr[i * NCH + o], b1 = Wi[i * NCH + o];
            Fr += a0 * b0 - a1 * b1;
            Fi += a0 * b1 + a1 * b0;
        }
        __syncthreads();
        sr[o] += Fr; si[o] += Fi;
        dr += Fr; di += Fi;
        __syncthreads();
    }
    dacc[((b * 9 + p) * 4 + q) * NCH + o] = make_float2(dr, di);
}

// ---------------------------------------------------------------------------
// K3b: spectral iteration for ky=0 with irfft Hermitian semantics.
// ---------------------------------------------------------------------------
__global__ __launch_bounds__(128) void k_spec_q0(
    const float* __restrict__ w1r, const float* __restrict__ w1i,
    const float* __restrict__ w2r, const float* __restrict__ w2i,
    const float2* __restrict__ s0, float2* __restrict__ dacc)
{
    __shared__ float Wr[2][NCH * NCH];
    __shared__ float Wi[2][NCH * NCH];
    __shared__ float sr[2][NCH], si[2][NCH];
    __shared__ float2 FL[2][NCH];
    const int gx    = blockIdx.x;
    const int b     = gx / 5;
    const int g     = gx % 5;
    const int which = threadIdx.x >> 6;
    const int o     = threadIdx.x & 63;
    int p;
    if (which == 0) p = g;
    else            p = (g == 1) ? 7 : (g == 2) ? 6 : (g == 3) ? 5 : -1;
    const bool active = (p >= 0);
    if (active) {
        const float* wr = (p < 4) ? w1r : w2r;
        const float* wi = (p < 4) ? w1i : w2i;
        const int pm = p & 3;
        for (int i = 0; i < NCH; ++i) {
            int gi_ = ((i * NCH + o) * NM + pm) * NM + 0;
            Wr[which][i * NCH + o] = wr[gi_];
            Wi[which][i * NCH + o] = wi[gi_];
        }
        float2 sv = s0[((b * 8 + p) * 4 + 0) * NCH + o];
        sr[which][o] = sv.x; si[which][o] = sv.y;
    }
    float dr = 0.f, di = 0.f, d8r = 0.f, d8i = 0.f;
    __syncthreads();
    for (int l = 0; l < NLAYERS; ++l) {
        float Fr = 0.f, Fi = 0.f;
        if (active) {
            for (int i = 0; i < NCH; ++i) {
                float a0 = sr[which][i], a1 = si[which][i];
                float b0 = Wr[which][i * NCH + o], b1 = Wi[which][i * NCH + o];
                Fr += a0 * b0 - a1 * b1;
                Fi += a0 * b1 + a1 * b0;
            }
        }
        FL[which][o] = make_float2(Fr, Fi);
        __syncthreads();
        float addr_ = 0.f, addi_ = 0.f;
        if (active) {
            if (g == 0) { addr_ = Fr; addi_ = 0.f; }
            else if (g == 4) {
                addr_ = 0.5f * Fr; addi_ = 0.5f * Fi;
                d8r += 0.5f * Fr;  d8i -= 0.5f * Fi;
            } else {
                float2 Fo = FL[1 - which][o];
                addr_ = 0.5f * (Fr + Fo.x);
                addi_ = 0.5f * (Fi - Fo.y);
            }
            sr[which][o] += addr_; si[which][o] += addi_;
            dr += addr_; di += addi_;
        }
        __syncthreads();
    }
    if (active) dacc[((b * 9 + p) * 4 + 0) * NCH + o] = make_float2(dr, di);
    if (g == 4 && which == 0)
        dacc[((b * 9 + 8) * 4 + 0) * NCH + o] = make_float2(d8r, d8i);
}

// ---------------------------------------------------------------------------
// K4: per-(b,row) rank-7 correction coefficients:
//  coef_j[c] from dacc+row twiddles (G-synth), then Bc[j][o] = sum_c coef_j[c]*W1[o][c]
//  basis order: {1, c1, c2, c3, s1, s2, s3}
// ---------------------------------------------------------------------------
__global__ __launch_bounds__(256) void k_rowcorr(
    const float2* __restrict__ dacc, const float* __restrict__ dec1_w,
    float* __restrict__ Bc)
{
    __shared__ __align__(16) float coef[7][NCH];
    const int bi  = blockIdx.x;            // b*256+row
    const int b   = bi >> 8;
    const int row = bi & 255;
    const int t   = threadIdx.x;
    // G-synth: thread -> (c,q)
    {
        const int c = t >> 2, q = t & 3;
        float tc[5], ts[5];
        tc[0] = 1.f; ts[0] = 0.f;
        #pragma unroll
        for (int k = 1; k < 5; ++k) {
            float a = (float)(k * row) * (1.0f / 256.0f);
            tc[k] = cos2pi(a); ts[k] = sin2pi(a);    // e^{+2pi i k row/256}
        }
        float twr[9] = {tc[0], tc[1], tc[2], tc[3], tc[4], tc[3], tc[2], tc[1], tc[4]};
        float twi[9] = {ts[0], ts[1], ts[2], ts[3], -ts[4], -ts[3], -ts[2], -ts[1], ts[4]};
        float gr = 0.f, gi = 0.f;
        #pragma unroll
        for (int p = 0; p < 9; ++p) {
            if (p == 8 && q != 0) continue;
            float2 v = dacc[((b * 9 + p) * 4 + q) * NCH + c];
            gr += v.x * twr[p] - v.y * twi[p];
            gi += v.x * twi[p] + v.y * twr[p];
        }
        const float s = ((q == 0) ? 1.0f : 2.0f) * (1.0f / 65536.0f);
        if (q == 0) {
            coef[0][c] = gr * s;                 // Im dropped (irfft)
        } else {
            coef[q][c]     = gr * s;
            coef[3 + q][c] = -gi * s;
        }
    }
    __syncthreads();
    // Bc: wave v handles j = v and (v<3 ? 4+v : none); lane = o
    const int o = t & 63;
    const int v = t >> 6;
    float4 wrow[16];
    #pragma unroll
    for (int k = 0; k < 16; ++k) wrow[k] = ((const float4*)(dec1_w + o * NCH))[k];
    float* bcrow = Bc + (size_t)bi * 512;
    {
        float s = 0.f;
        #pragma unroll
        for (int k = 0; k < 16; ++k) {
            float4 cf = ((const float4*)&coef[v][0])[k];
            s += wrow[k].x * cf.x + wrow[k].y * cf.y + wrow[k].z * cf.z + wrow[k].w * cf.w;
        }
        bcrow[v * 64 + o] = s;
    }
    if (v < 3) {
        float s = 0.f;
        #pragma unroll
        for (int k = 0; k < 16; ++k) {
            float4 cf = ((const float4*)&coef[4 + v][0])[k];
            s += wrow[k].x * cf.x + wrow[k].y * cf.y + wrow[k].z * cf.z + wrow[k].w * cf.w;
        }
        bcrow[(4 + v) * 64 + o] = s;
    }
}

// ---------------------------------------------------------------------------
// K5: final. block=(b,row,half) covers 128 px; A-frags (2h0 bf16 hi/lo) built
// in registers (producer lane == MFMA lane), W from pre-swizzled Wpk via LDS,
// rank-7 spectral correction applied in epilogue from Bc.
// ---------------------------------------------------------------------------
__global__ __launch_bounds__(256) void k_final(
    const float* __restrict__ x, const float* __restrict__ encwb,
    const unsigned short* __restrict__ Wpk, const float* __restrict__ Bc,
    const float* __restrict__ dec1_b, const float* __restrict__ dec2_w,
    const float* __restrict__ dec2_b, float* __restrict__ out)
{
    __shared__ __align__(16) unsigned short Wl[2][NCH * NCH];  // 16 KB (hi, lo)
    __shared__ __align__(16) float Bcs[7][NCH];                // 1.75 KB
    const int bi   = blockIdx.x;
    const int b    = bi >> 9;
    const int rem  = bi & 511;
    const int row  = rem >> 1;
    const int half = rem & 1;
    const int t    = threadIdx.x;

    // phase0: stage W (linear copy of pre-swizzled image) + Bc
    {
        const uint4* src = (const uint4*)Wpk;
        uint4* dst = (uint4*)&Wl[0][0];
        #pragma unroll
        for (int k = 0; k < 4; ++k) dst[t + 256 * k] = src[t + 256 * k];
        if (t < 112)
            ((float4*)&Bcs[0][0])[t] = ((const float4*)(Bc + (size_t)(b * 256 + row) * 512))[t];
    }
    __syncthreads();

    const int lane = t & 63;
    const int wv   = t >> 6;
    const int li   = lane & 15;
    const int g    = lane >> 4;

    // phase1: A-frags in registers. pixel_i = half*128+(wv*2+i)*16+li;
    // channels c = ks*32 + g*8 + j
    s16x8 ahi[2][2], alo[2][2];
    {
        float xs0[2], xs1[2], xs2[2];
        #pragma unroll
        for (int i = 0; i < 2; ++i) {
            int px = half * 128 + (wv * 2 + i) * 16 + li;
            xs0[i] = x[((b * 3 + 0) * NH + row) * NW + px];
            xs1[i] = x[((b * 3 + 1) * NH + row) * NW + px];
            xs2[i] = x[((b * 3 + 2) * NH + row) * NW + px];
        }
        #pragma unroll
        for (int ks = 0; ks < 2; ++ks) {
            #pragma unroll
            for (int j = 0; j < 8; ++j) {
                float4 ew = ((const float4*)encwb)[ks * 32 + g * 8 + j];
                #pragma unroll
                for (int i = 0; i < 2; ++i) {
                    float h = fast_tanh(ew.w + ew.x * xs0[i] + ew.y * xs1[i] + ew.z * xs2[i]);
                    float v2 = 2.0f * h;
                    unsigned short hb = f2bf(v2);
                    ahi[i][ks][j] = (short)hb;
                    alo[i][ks][j] = (short)f2bf(v2 - bf2f(hb));
                }
            }
        }
    }

    // phase2: MFMA (A regs, W LDS swizzled)
    f32x4 acc[2][4];
    #pragma unroll
    for (int i = 0; i < 2; ++i)
        #pragma unroll
        for (int nt = 0; nt < 4; ++nt)
            acc[i][nt] = (f32x4){0.f, 0.f, 0.f, 0.f};
    #pragma unroll
    for (int ks = 0; ks < 2; ++ks) {
        #pragma unroll
        for (int nt = 0; nt < 4; ++nt) {
            int o = nt * 16 + li;
            int byteoff = (o * 128 + ks * 64 + g * 16) ^ ((o & 7) << 4);
            s16x8 wh = *(const s16x8*)((const char*)&Wl[0][0] + byteoff);
            s16x8 wl = *(const s16x8*)((const char*)&Wl[1][0] + byteoff);
            #pragma unroll
            for (int i = 0; i < 2; ++i) {
                acc[i][nt] = __builtin_amdgcn_mfma_f32_16x16x32_bf16(ahi[i][ks], wh, acc[i][nt], 0, 0, 0);
                acc[i][nt] = __builtin_amdgcn_mfma_f32_16x16x32_bf16(alo[i][ks], wh, acc[i][nt], 0, 0, 0);
                acc[i][nt] = __builtin_amdgcn_mfma_f32_16x16x32_bf16(ahi[i][ks], wl, acc[i][nt], 0, 0, 0);
            }
        }
    }

    // epilogue: sv = acc + d1b + sum_j basis_j(px)*Bc[j][o]; out = d2b + sum d2w*tanh(sv)
    float d1b[4], d2w[4], bcj[4][7];
    #pragma unroll
    for (int nt = 0; nt < 4; ++nt) {
        int o = nt * 16 + li;
        d1b[nt] = dec1_b[o];
        d2w[nt] = dec2_w[o];
        #pragma unroll
        for (int j = 0; j < 7; ++j) bcj[nt][j] = Bcs[j][o];
    }
    const float d2b = dec2_b[0];
    float* orow = out + (b * NH + row) * NW;
    #pragma unroll
    for (int i = 0; i < 2; ++i) {
        #pragma unroll
        for (int r = 0; r < 4; ++r) {
            int px = half * 128 + (wv * 2 + i) * 16 + g * 4 + r;
            float pf = (float)px;
            float c1 = cos2pi(pf * (1.0f / 256.0f)), s1 = sin2pi(pf * (1.0f / 256.0f));
            float c2 = cos2pi(pf * (2.0f / 256.0f)), s2 = sin2pi(pf * (2.0f / 256.0f));
            float c3 = cos2pi(pf * (3.0f / 256.0f)), s3 = sin2pi(pf * (3.0f / 256.0f));
            float partial = 0.f;
            #pragma unroll
            for (int nt = 0; nt < 4; ++nt) {
                float sv = acc[i][nt][r] + d1b[nt] + bcj[nt][0]
                         + bcj[nt][1] * c1 + bcj[nt][2] * c2 + bcj[nt][3] * c3
                         + bcj[nt][4] * s1 + bcj[nt][5] * s2 + bcj[nt][6] * s3;
                partial += d2w[nt] * fast_tanh(sv);
            }
            partial += __shfl_xor(partial, 1);
            partial += __shfl_xor(partial, 2);
            partial += __shfl_xor(partial, 4);
            partial += __shfl_xor(partial, 8);
            if (li == 0) orow[px] = d2b + partial;
        }
    }
}

extern "C" void kernel_launch(void* const* d_in, const int* in_sizes, int n_in,
                              void* d_out, int out_size, void* d_ws, size_t ws_size,
                              hipStream_t stream) {
    (void)in_sizes; (void)n_in; (void)out_size; (void)ws_size;
    const float* x      = (const float*)d_in[0];
    const float* enc_w  = (const float*)d_in[1];
    const float* enc_b  = (const float*)d_in[2];
    const float* dec1_w = (const float*)d_in[3];
    const float* dec1_b = (const float*)d_in[4];
    const float* dec2_w = (const float*)d_in[5];
    const float* dec2_b = (const float*)d_in[6];
    const float* w1r    = (const float*)d_in[7];
    const float* w1i    = (const float*)d_in[8];
    const float* w2r    = (const float*)d_in[9];
    const float* w2i    = (const float*)d_in[10];
    float* out = (float*)d_out;

    char* ws = (char*)d_ws;
    // P2 (8 MB, dead after k_coldft) overlaps Bc (4 MB, written after)
    float*  P2    = (float*)(ws);                         // [2][8][64][256][4][2] f32 = 8 MB
    float*  Bc    = (float*)(ws);                         // [2048][8][64] f32 = 4 MB (aliases P2)
    float2* s0    = (float2*)(ws + (8u << 20));           // 128 KB
    float2* dd    = (float2*)(ws + (8u << 20) + 131072);  // 144 KB
    unsigned short* Wpk = (unsigned short*)(ws + (8u << 20) + 131072 + 147456); // 16 KB
    unsigned short* Tpk = Wpk + 8192;                     // 16 KB
    float*  encwb = (float*)(Tpk + 8192);                 // 1 KB

    k_wprep    <<<1, 256, 0, stream>>>(dec1_w, enc_w, enc_b, Wpk, Tpk, encwb);
    k_enc_mfma <<<NB * NH * 2, 256, 0, stream>>>(x, encwb, Tpk, P2);
    k_coldft   <<<NB * NCH, 64, 0, stream>>>(P2, s0);
    k_spec_q123<<<NB * 24, 64, 0, stream>>>(w1r, w1i, w2r, w2i, s0, dd);
    k_spec_q0  <<<NB * 5, 128, 0, stream>>>(w1r, w1i, w2r, w2i, s0, dd);
    k_rowcorr  <<<NB * NH, 256, 0, stream>>>(dd, dec1_w, Bc);
    k_final    <<<NB * NH * 2, 256, 0, stream>>>(x, encwb, Wpk, Bc, dec1_b,
                                                 dec2_w, dec2_b, out);
}

// Round 6
// 212.031 us; speedup vs baseline: 1.3974x; 1.1257x over previous
//
#include <hip/hip_runtime.h>
#include <hip/hip_bf16.h>

#define NB 8
#define NCIN 3
#define NCH 64
#define NH 256
#define NW 256
#define NM 4
#define NLAYERS 6

typedef short s16x8 __attribute__((ext_vector_type(8)));
typedef float f32x4 __attribute__((ext_vector_type(4)));

__device__ __forceinline__ float fast_tanh(float x) {
    float e = __expf(2.0f * x);
    return 1.0f - 2.0f / (1.0f + e);
}
// sin/cos of (2*pi*x): raw v_sin/v_cos, input in revolutions (|x|<5 here)
__device__ __forceinline__ float sin2pi(float x) { return __builtin_amdgcn_sinf(x); }
__device__ __forceinline__ float cos2pi(float x) { return __builtin_amdgcn_cosf(x); }

// pack 2 fp32 -> 2 bf16 (RNE) in one u32; compiler emits v_cvt_pk_bf16_f32
__device__ __forceinline__ unsigned int pk2(float a, float b) {
    __hip_bfloat162 h = __float22bfloat162_rn(make_float2(a, b));
    unsigned int u; __builtin_memcpy(&u, &h, 4); return u;
}
__device__ __forceinline__ s16x8 u4cast(uint4 u) {
    s16x8 r; __builtin_memcpy(&r, &u, 16); return r;
}
// scalar RNE fp32->bf16 (for scattered stores)
__device__ __forceinline__ unsigned short f2bf(float f) {
    unsigned int u = __float_as_uint(f);
    u = u + 0x7fffu + ((u >> 16) & 1u);
    return (unsigned short)(u >> 16);
}
__device__ __forceinline__ float bf2f(unsigned short h) {
    return __uint_as_float(((unsigned int)h) << 16);
}

// ---------------------------------------------------------------------------
// K0: prep (7 blocks).
//  blocks 0-1: Wpk = dec1_w bf16 hi/lo planes, XOR-swizzled image
//              (512 items: o = tt&63, cb = (tt>>6)*8 -- exactly 64 x 8 chunks)
//  blocks 2-5: Tpk = row-DFT twiddles [n=16][w=256] bf16 (single plane)
//  block  6  : encwb[64] = {enc_w[c][0..2], enc_b[c]}
// ---------------------------------------------------------------------------
__global__ __launch_bounds__(256) void k_wprep(
    const float* __restrict__ dec1_w, const float* __restrict__ enc_w,
    const float* __restrict__ enc_b, unsigned short* __restrict__ Wpk,
    unsigned short* __restrict__ Tpk, float* __restrict__ encwb)
{
    const int bid = blockIdx.x;
    const int t   = threadIdx.x;
    if (bid < 2) {
        const int tt = bid * 256 + t;           // [0,512)
        const int o  = tt & 63;
        const int cb = (tt >> 6) * 8;           // {0,8,...,56}
        const float* wr = dec1_w + o * NCH + cb;
        float4 wa = ((const float4*)wr)[0];
        float4 wb = ((const float4*)wr)[1];
        float v[8] = {wa.x, wa.y, wa.z, wa.w, wb.x, wb.y, wb.z, wb.w};
        unsigned int ph[4], pl[4];
        #pragma unroll
        for (int j = 0; j < 4; ++j) {
            unsigned int h = pk2(v[2 * j], v[2 * j + 1]);
            float ha = __uint_as_float(h << 16);
            float hb = __uint_as_float(h & 0xffff0000u);
            ph[j] = h;
            pl[j] = pk2(v[2 * j] - ha, v[2 * j + 1] - hb);
        }
        int byteoff = (o * 128 + cb * 2) ^ ((o & 7) << 4);
        *(uint4*)((char*)Wpk + byteoff)        = make_uint4(ph[0], ph[1], ph[2], ph[3]);
        *(uint4*)((char*)Wpk + 8192 + byteoff) = make_uint4(pl[0], pl[1], pl[2], pl[3]);
    } else if (bid < 6) {
        const int tt = (bid - 2) * 256 + t;     // [0,1024)
        const int n  = tt >> 6;
        const int w4 = (tt & 63) * 4;
        float vv[4];
        #pragma unroll
        for (int z = 0; z < 4; ++z) {
            int w = w4 + z;
            float val = 0.f;
            if (n < 4)      val = cos2pi((float)(n * w) * (1.0f / 256.0f));
            else if (n < 8) val = -sin2pi((float)((n - 4) * w) * (1.0f / 256.0f));
            vv[z] = val;
        }
        *(uint2*)(Tpk + n * 256 + w4) = make_uint2(pk2(vv[0], vv[1]), pk2(vv[2], vv[3]));
    } else {
        if (t < NCH) {
            float4 e4;
            e4.x = enc_w[t * 3 + 0]; e4.y = enc_w[t * 3 + 1];
            e4.z = enc_w[t * 3 + 2]; e4.w = enc_b[t];
            ((float4*)encwb)[t] = e4;
        }
    }
}

// ---------------------------------------------------------------------------
// K1: encoder + row DFT on MFMA (single-term bf16 — spectral path needs ~1%).
// block=(b,row,wh) covers 128 w. out: P2[wh][b][c][row][q][reim] fp32 partials
// ---------------------------------------------------------------------------
__global__ __launch_bounds__(256) void k_enc_mfma(
    const float* __restrict__ x, const float* __restrict__ encwb,
    const unsigned short* __restrict__ Tpk, float* __restrict__ P2)
{
    __shared__ __align__(16) unsigned short Ah[64 * 128];  // 16 KB
    const int bi  = blockIdx.x;
    const int b   = bi >> 9;
    const int rem = bi & 511;
    const int row = rem >> 1;
    const int wh  = rem & 1;
    const int t   = threadIdx.x;

    // phase1: thread -> c = t&63, local w chunk (t>>6)*32
    {
        const int c   = t & 63;
        const int wl0 = (t >> 6) * 32;
        float4 ewb = ((const float4*)encwb)[c];
        const float* xr0 = x + ((b * 3 + 0) * NH + row) * NW + wh * 128 + wl0;
        const float* xr1 = x + ((b * 3 + 1) * NH + row) * NW + wh * 128 + wl0;
        const float* xr2 = x + ((b * 3 + 2) * NH + row) * NW + wh * 128 + wl0;
        #pragma unroll
        for (int u = 0; u < 4; ++u) {
            float4 a0 = ((const float4*)xr0)[u * 2], b0 = ((const float4*)xr0)[u * 2 + 1];
            float4 a1 = ((const float4*)xr1)[u * 2], b1 = ((const float4*)xr1)[u * 2 + 1];
            float4 a2 = ((const float4*)xr2)[u * 2], b2 = ((const float4*)xr2)[u * 2 + 1];
            float hv[8];
            hv[0] = fast_tanh(ewb.w + ewb.x * a0.x + ewb.y * a1.x + ewb.z * a2.x);
            hv[1] = fast_tanh(ewb.w + ewb.x * a0.y + ewb.y * a1.y + ewb.z * a2.y);
            hv[2] = fast_tanh(ewb.w + ewb.x * a0.z + ewb.y * a1.z + ewb.z * a2.z);
            hv[3] = fast_tanh(ewb.w + ewb.x * a0.w + ewb.y * a1.w + ewb.z * a2.w);
            hv[4] = fast_tanh(ewb.w + ewb.x * b0.x + ewb.y * b1.x + ewb.z * b2.x);
            hv[5] = fast_tanh(ewb.w + ewb.x * b0.y + ewb.y * b1.y + ewb.z * b2.y);
            hv[6] = fast_tanh(ewb.w + ewb.x * b0.z + ewb.y * b1.z + ewb.z * b2.z);
            hv[7] = fast_tanh(ewb.w + ewb.x * b0.w + ewb.y * b1.w + ewb.z * b2.w);
            uint4 pu = make_uint4(pk2(hv[0], hv[1]), pk2(hv[2], hv[3]),
                                  pk2(hv[4], hv[5]), pk2(hv[6], hv[7]));
            int byteoff = (c * 256 + (wl0 + u * 8) * 2) ^ ((c & 15) << 4);
            *(uint4*)((char*)Ah + byteoff) = pu;
        }
    }
    __syncthreads();

    // phase2: wave v = c-tile; lane: n=li, k-group g; 4 k-steps, 1 MFMA each
    const int lane = t & 63;
    const int v    = t >> 6;
    const int li   = lane & 15;
    const int g    = lane >> 4;
    f32x4 acc = {0.f, 0.f, 0.f, 0.f};
    #pragma unroll
    for (int kk = 0; kk < 4; ++kk) {
        int cm = v * 16 + li;
        int coff = (cm * 256 + (kk * 32 + g * 8) * 2) ^ ((cm & 15) << 4);
        s16x8 ah = *(const s16x8*)((const char*)Ah + coff);
        int wg = wh * 128 + kk * 32 + g * 8;
        s16x8 bh = *(const s16x8*)(Tpk + li * 256 + wg);
        acc = __builtin_amdgcn_mfma_f32_16x16x32_bf16(ah, bh, acc, 0, 0, 0);
    }
    if (li < 8) {
        const int q = li & 3, reim = li >> 2;
        float* pbase = P2 + (size_t)wh * (NB * 64 * 256 * 8);
        #pragma unroll
        for (int e = 0; e < 4; ++e) {
            int c = v * 16 + g * 4 + e;
            pbase[(((b * 64 + c) * 256 + row) * 4 + q) * 2 + reim] = acc[e];
        }
    }
}

// ---------------------------------------------------------------------------
// K2: column DFT. block=(b,c), 64 threads = (p,q,reim); each thread owns the
// full 256-row sum (no shfl storm). P halves summed during LDS staging.
// ---------------------------------------------------------------------------
__global__ __launch_bounds__(64) void k_coldft(const float* __restrict__ P2,
                                               float2* __restrict__ s0)
{
    __shared__ __align__(16) float Ps[256][8];   // 8 KB
    __shared__ float twc[5][256];                // 5 KB
    __shared__ float tws[5][256];                // 5 KB
    const int b = blockIdx.x >> 6;
    const int c = blockIdx.x & 63;
    const int t = threadIdx.x;
    {
        const float4* pa = (const float4*)(P2 + (size_t)(b * 64 + c) * 256 * 8);
        const float4* pb = pa + (size_t)NB * 64 * 256 * 2;   // wh=1 plane
        float4* ds = (float4*)&Ps[0][0];
        #pragma unroll
        for (int k = 0; k < 8; ++k) {
            int s = t + 64 * k;
            float4 u = pa[s], v = pb[s];
            ds[s] = make_float4(u.x + v.x, u.y + v.y, u.z + v.z, u.w + v.w);
        }
        for (int idx = t; idx < 5 * 256; idx += 64) {
            int k = idx >> 8, rw = idx & 255;
            float a = (float)(k * rw) * (1.0f / 256.0f);
            twc[k][rw] = cos2pi(a);
            tws[k][rw] = sin2pi(a);
        }
    }
    __syncthreads();
    const int kxs[8] = {0, 1, 2, 3, -4, -3, -2, -1};
    const int p = t >> 3, q = (t >> 1) & 3, reim = t & 1;
    const int kx = kxs[p];
    const int ka = kx < 0 ? -kx : kx;
    const float sgn = (kx < 0) ? 1.f : -1.f;     // ti = sgn * sin(2pi ka row/256)
    float acc = 0.f;
    #pragma unroll 4
    for (int rw = 0; rw < 256; ++rw) {
        float pr = Ps[rw][q * 2], pi = Ps[rw][q * 2 + 1];
        float tr = twc[ka][rw], ti = sgn * tws[ka][rw];
        acc += reim ? (pr * ti + pi * tr) : (pr * tr - pi * ti);
    }
    ((float*)s0)[(((b * 8 + p) * 4 + q) * NCH + c) * 2 + reim] = acc;
}

// ---------------------------------------------------------------------------
// K3 (merged): slots 0-11 = q123 pairs (two independent (q,p) items/block);
//              slots 12-16 = ky=0 Hermitian groups. grid = b*17.
// ---------------------------------------------------------------------------
__global__ __launch_bounds__(128) void k_spec(
    const float* __restrict__ w1r, const float* __restrict__ w1i,
    const float* __restrict__ w2r, const float* __restrict__ w2i,
    const float2* __restrict__ s0, float2* __restrict__ dacc)
{
    __shared__ float Wr[2][NCH * NCH];
    __shared__ float Wi[2][NCH * NCH];
    __shared__ float sr[2][NCH], si[2][NCH];
    __shared__ float2 FL[2][NCH];
    const int gx    = blockIdx.x;
    const int b     = gx / 17;
    const int slot  = gx % 17;
    const int which = threadIdx.x >> 6;
    const int o     = threadIdx.x & 63;

    if (slot < 12) {
        const int r = slot * 2 + which;        // 0..23
        const int q = (r >> 3) + 1;
        const int p = r & 7;
        const float* wr = (p < 4) ? w1r : w2r;
        const float* wi = (p < 4) ? w1i : w2i;
        const int pm = p & 3;
        for (int i = 0; i < NCH; ++i) {
            int gi_ = ((i * NCH + o) * NM + pm) * NM + q;
            Wr[which][i * NCH + o] = wr[gi_];
            Wi[which][i * NCH + o] = wi[gi_];
        }
        float2 sv = s0[((b * 8 + p) * 4 + q) * NCH + o];
        sr[which][o] = sv.x; si[which][o] = sv.y;
        float dr = 0.f, di = 0.f;
        __syncthreads();
        for (int l = 0; l < NLAYERS; ++l) {
            float Fr = 0.f, Fi = 0.f;
            for (int i = 0; i < NCH; ++i) {
                float a0 = sr[which][i], a1 = si[which][i];
                float b0 = Wr[which][i * NCH + o], b1 = Wi[which][i * NCH + o];
                Fr += a0 * b0 - a1 * b1;
                Fi += a0 * b1 + a1 * b0;
            }
            __syncthreads();
            sr[which][o] += Fr; si[which][o] += Fi;
            dr += Fr; di += Fi;
            __syncthreads();
        }
        dacc[((b * 9 + p) * 4 + q) * NCH + o] = make_float2(dr, di);
    } else {
        const int g = slot - 12;
        int p;
        if (which == 0) p = g;
        else            p = (g == 1) ? 7 : (g == 2) ? 6 : (g == 3) ? 5 : -1;
        const bool active = (p >= 0);
        if (active) {
            const float* wr = (p < 4) ? w1r : w2r;
            const float* wi = (p < 4) ? w1i : w2i;
            const int pm = p & 3;
            for (int i = 0; i < NCH; ++i) {
                int gi_ = ((i * NCH + o) * NM + pm) * NM + 0;
                Wr[which][i * NCH + o] = wr[gi_];
                Wi[which][i * NCH + o] = wi[gi_];
            }
            float2 sv = s0[((b * 8 + p) * 4 + 0) * NCH + o];
            sr[which][o] = sv.x; si[which][o] = sv.y;
        }
        float dr = 0.f, di = 0.f, d8r = 0.f, d8i = 0.f;
        __syncthreads();
        for (int l = 0; l < NLAYERS; ++l) {
            float Fr = 0.f, Fi = 0.f;
            if (active) {
                for (int i = 0; i < NCH; ++i) {
                    float a0 = sr[which][i], a1 = si[which][i];
                    float b0 = Wr[which][i * NCH + o], b1 = Wi[which][i * NCH + o];
                    Fr += a0 * b0 - a1 * b1;
                    Fi += a0 * b1 + a1 * b0;
                }
            }
            FL[which][o] = make_float2(Fr, Fi);
            __syncthreads();
            float addr_ = 0.f, addi_ = 0.f;
            if (active) {
                if (g == 0) { addr_ = Fr; addi_ = 0.f; }
                else if (g == 4) {
                    addr_ = 0.5f * Fr; addi_ = 0.5f * Fi;
                    d8r += 0.5f * Fr;  d8i -= 0.5f * Fi;
                } else {
                    float2 Fo = FL[1 - which][o];
                    addr_ = 0.5f * (Fr + Fo.x);
                    addi_ = 0.5f * (Fi - Fo.y);
                }
                sr[which][o] += addr_; si[which][o] += addi_;
                dr += addr_; di += addi_;
            }
            __syncthreads();
        }
        if (active) dacc[((b * 9 + p) * 4 + 0) * NCH + o] = make_float2(dr, di);
        if (g == 4 && which == 0)
            dacc[((b * 9 + 8) * 4 + 0) * NCH + o] = make_float2(d8r, d8i);
    }
}

// ---------------------------------------------------------------------------
// K4: per-(b,row) rank-7 coefficients Bc[j][o] (basis {1,c1,c2,c3,s1,s2,s3})
// ---------------------------------------------------------------------------
__global__ __launch_bounds__(256) void k_rowcorr(
    const float2* __restrict__ dacc, const float* __restrict__ dec1_w,
    float* __restrict__ Bc)
{
    __shared__ __align__(16) float coef[7][NCH];
    const int bi  = blockIdx.x;            // b*256+row
    const int b   = bi >> 8;
    const int row = bi & 255;
    const int t   = threadIdx.x;
    {
        const int c = t >> 2, q = t & 3;
        float tc[5], ts[5];
        tc[0] = 1.f; ts[0] = 0.f;
        #pragma unroll
        for (int k = 1; k < 5; ++k) {
            float a = (float)(k * row) * (1.0f / 256.0f);
            tc[k] = cos2pi(a); ts[k] = sin2pi(a);    // e^{+2pi i k row/256}
        }
        float twr[9] = {tc[0], tc[1], tc[2], tc[3], tc[4], tc[3], tc[2], tc[1], tc[4]};
        float twi[9] = {ts[0], ts[1], ts[2], ts[3], -ts[4], -ts[3], -ts[2], -ts[1], ts[4]};
        float gr = 0.f, gi = 0.f;
        #pragma unroll
        for (int p = 0; p < 9; ++p) {
            if (p == 8 && q != 0) continue;
            float2 v = dacc[((b * 9 + p) * 4 + q) * NCH + c];
            gr += v.x * twr[p] - v.y * twi[p];
            gi += v.x * twi[p] + v.y * twr[p];
        }
        const float s = ((q == 0) ? 1.0f : 2.0f) * (1.0f / 65536.0f);
        if (q == 0) {
            coef[0][c] = gr * s;
        } else {
            coef[q][c]     = gr * s;
            coef[3 + q][c] = -gi * s;
        }
    }
    __syncthreads();
    const int o = t & 63;
    const int v = t >> 6;
    float4 wrow[16];
    #pragma unroll
    for (int k = 0; k < 16; ++k) wrow[k] = ((const float4*)(dec1_w + o * NCH))[k];
    float* bcrow = Bc + (size_t)bi * 512;
    {
        float s = 0.f;
        #pragma unroll
        for (int k = 0; k < 16; ++k) {
            float4 cf = ((const float4*)&coef[v][0])[k];
            s += wrow[k].x * cf.x + wrow[k].y * cf.y + wrow[k].z * cf.z + wrow[k].w * cf.w;
        }
        bcrow[v * 64 + o] = s;
    }
    if (v < 3) {
        float s = 0.f;
        #pragma unroll
        for (int k = 0; k < 16; ++k) {
            float4 cf = ((const float4*)&coef[4 + v][0])[k];
            s += wrow[k].x * cf.x + wrow[k].y * cf.y + wrow[k].z * cf.z + wrow[k].w * cf.w;
        }
        bcrow[(4 + v) * 64 + o] = s;
    }
}

// ---------------------------------------------------------------------------
// K5: final. A-frags (2h0 bf16 hi/lo) in registers; W via pre-swizzled LDS;
// rank-7 correction as an extra MFMA (basis[16x8] @ BcT[8x64] into acc).
// ---------------------------------------------------------------------------
__global__ __launch_bounds__(256) void k_final(
    const float* __restrict__ x, const float* __restrict__ encwb,
    const unsigned short* __restrict__ Wpk, const float* __restrict__ Bc,
    const float* __restrict__ dec1_b, const float* __restrict__ dec2_w,
    const float* __restrict__ dec2_b, float* __restrict__ out)
{
    __shared__ __align__(16) unsigned short Wl[2][NCH * NCH];  // 16 KB (hi, lo)
    __shared__ __align__(16) unsigned short BcsT[NCH][8];      // 1 KB (o-major)
    const int bi   = blockIdx.x;
    const int b    = bi >> 9;
    const int rem  = bi & 511;
    const int row  = rem >> 1;
    const int half = rem & 1;
    const int t    = threadIdx.x;

    // phase0: stage W (linear copy of pre-swizzled image) + BcT (bf16)
    {
        const uint4* src = (const uint4*)Wpk;
        uint4* dst = (uint4*)&Wl[0][0];
        #pragma unroll
        for (int k = 0; k < 4; ++k) dst[t + 256 * k] = src[t + 256 * k];
        if (t < 112) {
            int e0 = t * 4, j = e0 >> 6, o = e0 & 63;
            float4 f = ((const float4*)(Bc + (size_t)(b * 256 + row) * 512))[t];
            BcsT[o + 0][j] = f2bf(f.x);
            BcsT[o + 1][j] = f2bf(f.y);
            BcsT[o + 2][j] = f2bf(f.z);
            BcsT[o + 3][j] = f2bf(f.w);
        } else if (t < 128) {
            int o = (t - 112) * 4;
            #pragma unroll
            for (int z = 0; z < 4; ++z) BcsT[o + z][7] = 0;
        }
    }
    __syncthreads();

    const int lane = t & 63;
    const int wv   = t >> 6;
    const int li   = lane & 15;
    const int g    = lane >> 4;

    // phase1: A-frags in registers (pixel = half*128+(wv*2+i)*16+li)
    s16x8 ahi[2][2], alo[2][2];
    {
        float xs0[2], xs1[2], xs2[2];
        #pragma unroll
        for (int i = 0; i < 2; ++i) {
            int px = half * 128 + (wv * 2 + i) * 16 + li;
            xs0[i] = x[((b * 3 + 0) * NH + row) * NW + px];
            xs1[i] = x[((b * 3 + 1) * NH + row) * NW + px];
            xs2[i] = x[((b * 3 + 2) * NH + row) * NW + px];
        }
        #pragma unroll
        for (int ks = 0; ks < 2; ++ks) {
            unsigned int hu[2][4], lu[2][4];
            #pragma unroll
            for (int j2 = 0; j2 < 4; ++j2) {
                float4 e0 = ((const float4*)encwb)[ks * 32 + g * 8 + j2 * 2 + 0];
                float4 e1 = ((const float4*)encwb)[ks * 32 + g * 8 + j2 * 2 + 1];
                #pragma unroll
                for (int i = 0; i < 2; ++i) {
                    float va = 2.0f * fast_tanh(e0.w + e0.x * xs0[i] + e0.y * xs1[i] + e0.z * xs2[i]);
                    float vb = 2.0f * fast_tanh(e1.w + e1.x * xs0[i] + e1.y * xs1[i] + e1.z * xs2[i]);
                    unsigned int h = pk2(va, vb);
                    float ha = __uint_as_float(h << 16);
                    float hb = __uint_as_float(h & 0xffff0000u);
                    hu[i][j2] = h;
                    lu[i][j2] = pk2(va - ha, vb - hb);
                }
            }
            #pragma unroll
            for (int i = 0; i < 2; ++i) {
                ahi[i][ks] = u4cast(make_uint4(hu[i][0], hu[i][1], hu[i][2], hu[i][3]));
                alo[i][ks] = u4cast(make_uint4(lu[i][0], lu[i][1], lu[i][2], lu[i][3]));
            }
        }
    }

    // phase2: main MFMA (3-term bf16 split)
    f32x4 acc[2][4];
    #pragma unroll
    for (int i = 0; i < 2; ++i)
        #pragma unroll
        for (int nt = 0; nt < 4; ++nt)
            acc[i][nt] = (f32x4){0.f, 0.f, 0.f, 0.f};
    #pragma unroll
    for (int ks = 0; ks < 2; ++ks) {
        #pragma unroll
        for (int nt = 0; nt < 4; ++nt) {
            int o = nt * 16 + li;
            int byteoff = (o * 128 + ks * 64 + g * 16) ^ ((o & 7) << 4);
            s16x8 wh = *(const s16x8*)((const char*)&Wl[0][0] + byteoff);
            s16x8 wl = *(const s16x8*)((const char*)&Wl[1][0] + byteoff);
            #pragma unroll
            for (int i = 0; i < 2; ++i) {
                acc[i][nt] = __builtin_amdgcn_mfma_f32_16x16x32_bf16(ahi[i][ks], wh, acc[i][nt], 0, 0, 0);
                acc[i][nt] = __builtin_amdgcn_mfma_f32_16x16x32_bf16(alo[i][ks], wh, acc[i][nt], 0, 0, 0);
                acc[i][nt] = __builtin_amdgcn_mfma_f32_16x16x32_bf16(ahi[i][ks], wl, acc[i][nt], 0, 0, 0);
            }
        }
    }

    // phase2b: rank-7 correction via MFMA: basis(px)[k=0..7] @ BcT[k][o]
    {
        s16x8 aC[2];
        #pragma unroll
        for (int i = 0; i < 2; ++i) {
            if (g == 0) {
                int px = half * 128 + (wv * 2 + i) * 16 + li;
                float pf = (float)px;
                float c1 = cos2pi(pf * (1.0f / 256.0f)), s1 = sin2pi(pf * (1.0f / 256.0f));
                float c2 = cos2pi(pf * (2.0f / 256.0f)), s2 = sin2pi(pf * (2.0f / 256.0f));
                float c3 = cos2pi(pf * (3.0f / 256.0f)), s3 = sin2pi(pf * (3.0f / 256.0f));
                aC[i] = u4cast(make_uint4(pk2(1.0f, c1), pk2(c2, c3),
                                          pk2(s1, s2), pk2(s3, 0.0f)));
            } else {
                aC[i] = u4cast(make_uint4(0, 0, 0, 0));
            }
        }
        #pragma unroll
        for (int nt = 0; nt < 4; ++nt) {
            s16x8 bC;
            if (g == 0) bC = *(const s16x8*)(&BcsT[nt * 16 + li][0]);
            else        bC = u4cast(make_uint4(0, 0, 0, 0));
            #pragma unroll
            for (int i = 0; i < 2; ++i)
                acc[i][nt] = __builtin_amdgcn_mfma_f32_16x16x32_bf16(aC[i], bC, acc[i][nt], 0, 0, 0);
        }
    }

    // epilogue
    float d1b[4], d2w[4];
    #pragma unroll
    for (int nt = 0; nt < 4; ++nt) {
        int o = nt * 16 + li;
        d1b[nt] = dec1_b[o];
        d2w[nt] = dec2_w[o];
    }
    const float d2b = dec2_b[0];
    float* orow = out + (b * NH + row) * NW;
    #pragma unroll
    for (int i = 0; i < 2; ++i) {
        #pragma unroll
        for (int r = 0; r < 4; ++r) {
            float partial = 0.f;
            #pragma unroll
            for (int nt = 0; nt < 4; ++nt) {
                float sv = acc[i][nt][r] + d1b[nt];
                partial += d2w[nt] * fast_tanh(sv);
            }
            partial += __shfl_xor(partial, 1);
            partial += __shfl_xor(partial, 2);
            partial += __shfl_xor(partial, 4);
            partial += __shfl_xor(partial, 8);
            if (li == 0) {
                int px = half * 128 + (wv * 2 + i) * 16 + g * 4 + r;
                orow[px] = d2b + partial;
            }
        }
    }
}

extern "C" void kernel_launch(void* const* d_in, const int* in_sizes, int n_in,
                              void* d_out, int out_size, void* d_ws, size_t ws_size,
                              hipStream_t stream) {
    (void)in_sizes; (void)n_in; (void)out_size; (void)ws_size;
    const float* x      = (const float*)d_in[0];
    const float* enc_w  = (const float*)d_in[1];
    const float* enc_b  = (const float*)d_in[2];
    const float* dec1_w = (const float*)d_in[3];
    const float* dec1_b = (const float*)d_in[4];
    const float* dec2_w = (const float*)d_in[5];
    const float* dec2_b = (const float*)d_in[6];
    const float* w1r    = (const float*)d_in[7];
    const float* w1i    = (const float*)d_in[8];
    const float* w2r    = (const float*)d_in[9];
    const float* w2i    = (const float*)d_in[10];
    float* out = (float*)d_out;

    char* ws = (char*)d_ws;
    // P2 (8 MB, dead after k_coldft) overlaps Bc (4 MB, written after)
    float*  P2    = (float*)(ws);                         // [2][8][64][256][4][2] f32 = 8 MB
    float*  Bc    = (float*)(ws);                         // [2048][8][64] f32 (aliases P2)
    float2* s0    = (float2*)(ws + (8u << 20));           // 128 KB
    float2* dd    = (float2*)(ws + (8u << 20) + 131072);  // 144 KB
    unsigned short* Wpk = (unsigned short*)(ws + (8u << 20) + 131072 + 147456); // 16 KB
    unsigned short* Tpk = Wpk + 8192;                     // 8 KB
    float*  encwb = (float*)(Tpk + 4096);                 // 1 KB

    k_wprep    <<<7, 256, 0, stream>>>(dec1_w, enc_w, enc_b, Wpk, Tpk, encwb);
    k_enc_mfma <<<NB * NH * 2, 256, 0, stream>>>(x, encwb, Tpk, P2);
    k_coldft   <<<NB * NCH, 64, 0, stream>>>(P2, s0);
    k_spec     <<<NB * 17, 128, 0, stream>>>(w1r, w1i, w2r, w2i, s0, dd);
    k_rowcorr  <<<NB * NH, 256, 0, stream>>>(dd, dec1_w, Bc);
    k_final    <<<NB * NH * 2, 256, 0, stream>>>(x, encwb, Wpk, Bc, dec1_b,
                                                 dec2_w, dec2_b, out);
}

// Round 7
// 197.881 us; speedup vs baseline: 1.4973x; 1.0715x over previous
//
#include <hip/hip_runtime.h>
#include <hip/hip_bf16.h>

#define NB 8
#define NCIN 3
#define NCH 64
#define NH 256
#define NW 256
#define NM 4
#define NLAYERS 6

typedef short s16x8 __attribute__((ext_vector_type(8)));
typedef float f32x4 __attribute__((ext_vector_type(4)));

// tanh(x) = 1 - 2*rcp(1+e^{2x}); v_exp + v_rcp (no precise-div sequence).
// Saturates correctly: x>>0 -> e=inf -> rcp=0 -> 1 ; x<<0 -> rcp(1)=1 -> -1.
__device__ __forceinline__ float fast_tanh(float x) {
    float e = __expf(2.0f * x);
    return 1.0f - 2.0f * __builtin_amdgcn_rcpf(1.0f + e);
}
// sin/cos of (2*pi*x): raw v_sin/v_cos, input in revolutions (|x|<5 here)
__device__ __forceinline__ float sin2pi(float x) { return __builtin_amdgcn_sinf(x); }
__device__ __forceinline__ float cos2pi(float x) { return __builtin_amdgcn_cosf(x); }

// pack 2 fp32 -> 2 bf16 (RNE) in one u32; compiler emits v_cvt_pk_bf16_f32
__device__ __forceinline__ unsigned int pk2(float a, float b) {
    __hip_bfloat162 h = __float22bfloat162_rn(make_float2(a, b));
    unsigned int u; __builtin_memcpy(&u, &h, 4); return u;
}
__device__ __forceinline__ s16x8 u4cast(uint4 u) {
    s16x8 r; __builtin_memcpy(&r, &u, 16); return r;
}
__device__ __forceinline__ unsigned short f2bf(float f) {
    unsigned int u = __float_as_uint(f);
    u = u + 0x7fffu + ((u >> 16) & 1u);
    return (unsigned short)(u >> 16);
}

// ---------------------------------------------------------------------------
// K0: prep (1031 blocks, all independent; runs once before everything).
//  blocks [0,1024):  Wt{r,i}[p][q][i][o] fp32 transpose of w1/w2 (coalesced
//                    consumption in k_spec)
//  blocks 1024-1025: Wpk = dec1_w bf16 hi/lo planes, XOR-swizzled image
//  blocks 1026-1029: Tpk = row-DFT twiddles [n=16][w=256] bf16
//  block  1030:      encwb[64] = {enc_w[c][0..2], enc_b[c]}
// ---------------------------------------------------------------------------
__global__ __launch_bounds__(256) void k_prep(
    const float* __restrict__ dec1_w, const float* __restrict__ enc_w,
    const float* __restrict__ enc_b,
    const float* __restrict__ w1r, const float* __restrict__ w1i,
    const float* __restrict__ w2r, const float* __restrict__ w2i,
    unsigned short* __restrict__ Wpk, unsigned short* __restrict__ Tpk,
    float* __restrict__ encwb, float* __restrict__ Wtr, float* __restrict__ Wti)
{
    const int bid = blockIdx.x;
    const int t   = threadIdx.x;
    if (bid < 1024) {
        int elem = bid * 256 + t;              // [0, 262144)
        int ri = elem >> 17;
        int rem = elem & 0x1FFFF;
        int p  = rem >> 14;
        int q  = (rem >> 12) & 3;
        int i  = (rem >> 6) & 63;
        int o  = rem & 63;
        const float* src;
        if (p < 4) src = ri ? w1i : w1r;
        else       src = ri ? w2i : w2r;
        float v = src[((i * 64 + o) * 4 + (p & 3)) * 4 + q];
        float* dst = ri ? Wti : Wtr;
        dst[(p * 4 + q) * 4096 + i * 64 + o] = v;
    } else if (bid < 1026) {
        const int tt = (bid - 1024) * 256 + t;  // [0,512)
        const int o  = tt & 63;
        const int cb = (tt >> 6) * 8;           // {0,8,...,56}
        const float* wr = dec1_w + o * NCH + cb;
        float4 wa = ((const float4*)wr)[0];
        float4 wb = ((const float4*)wr)[1];
        float v[8] = {wa.x, wa.y, wa.z, wa.w, wb.x, wb.y, wb.z, wb.w};
        unsigned int ph[4], pl[4];
        #pragma unroll
        for (int j = 0; j < 4; ++j) {
            unsigned int h = pk2(v[2 * j], v[2 * j + 1]);
            float ha = __uint_as_float(h << 16);
            float hb = __uint_as_float(h & 0xffff0000u);
            ph[j] = h;
            pl[j] = pk2(v[2 * j] - ha, v[2 * j + 1] - hb);
        }
        int byteoff = (o * 128 + cb * 2) ^ ((o & 7) << 4);
        *(uint4*)((char*)Wpk + byteoff)        = make_uint4(ph[0], ph[1], ph[2], ph[3]);
        *(uint4*)((char*)Wpk + 8192 + byteoff) = make_uint4(pl[0], pl[1], pl[2], pl[3]);
    } else if (bid < 1030) {
        const int tt = (bid - 1026) * 256 + t;  // [0,1024)
        const int n  = tt >> 6;
        const int w4 = (tt & 63) * 4;
        float vv[4];
        #pragma unroll
        for (int z = 0; z < 4; ++z) {
            int w = w4 + z;
            float val = 0.f;
            if (n < 4)      val = cos2pi((float)(n * w) * (1.0f / 256.0f));
            else if (n < 8) val = -sin2pi((float)((n - 4) * w) * (1.0f / 256.0f));
            vv[z] = val;
        }
        *(uint2*)(Tpk + n * 256 + w4) = make_uint2(pk2(vv[0], vv[1]), pk2(vv[2], vv[3]));
    } else {
        if (t < NCH) {
            float4 e4;
            e4.x = enc_w[t * 3 + 0]; e4.y = enc_w[t * 3 + 1];
            e4.z = enc_w[t * 3 + 2]; e4.w = enc_b[t];
            ((float4*)encwb)[t] = e4;
        }
    }
}

// ---------------------------------------------------------------------------
// K1: encoder + row DFT on MFMA (single-term bf16).
// block=(b,row,wh) covers 128 w. out: P2[wh][b][q][row][c][reim] fp32
// ---------------------------------------------------------------------------
__global__ __launch_bounds__(256) void k_enc_mfma(
    const float* __restrict__ x, const float* __restrict__ encwb,
    const unsigned short* __restrict__ Tpk, float* __restrict__ P2)
{
    __shared__ __align__(16) unsigned short Ah[64 * 128];  // 16 KB
    const int bi  = blockIdx.x;
    const int b   = bi >> 9;
    const int rem = bi & 511;
    const int row = rem >> 1;
    const int wh  = rem & 1;
    const int t   = threadIdx.x;

    // phase1: thread -> c = t&63, local w chunk (t>>6)*32
    {
        const int c   = t & 63;
        const int wl0 = (t >> 6) * 32;
        float4 ewb = ((const float4*)encwb)[c];
        const float* xr0 = x + ((b * 3 + 0) * NH + row) * NW + wh * 128 + wl0;
        const float* xr1 = x + ((b * 3 + 1) * NH + row) * NW + wh * 128 + wl0;
        const float* xr2 = x + ((b * 3 + 2) * NH + row) * NW + wh * 128 + wl0;
        #pragma unroll
        for (int u = 0; u < 4; ++u) {
            float4 a0 = ((const float4*)xr0)[u * 2], b0 = ((const float4*)xr0)[u * 2 + 1];
            float4 a1 = ((const float4*)xr1)[u * 2], b1 = ((const float4*)xr1)[u * 2 + 1];
            float4 a2 = ((const float4*)xr2)[u * 2], b2 = ((const float4*)xr2)[u * 2 + 1];
            float hv[8];
            hv[0] = fast_tanh(ewb.w + ewb.x * a0.x + ewb.y * a1.x + ewb.z * a2.x);
            hv[1] = fast_tanh(ewb.w + ewb.x * a0.y + ewb.y * a1.y + ewb.z * a2.y);
            hv[2] = fast_tanh(ewb.w + ewb.x * a0.z + ewb.y * a1.z + ewb.z * a2.z);
            hv[3] = fast_tanh(ewb.w + ewb.x * a0.w + ewb.y * a1.w + ewb.z * a2.w);
            hv[4] = fast_tanh(ewb.w + ewb.x * b0.x + ewb.y * b1.x + ewb.z * b2.x);
            hv[5] = fast_tanh(ewb.w + ewb.x * b0.y + ewb.y * b1.y + ewb.z * b2.y);
            hv[6] = fast_tanh(ewb.w + ewb.x * b0.z + ewb.y * b1.z + ewb.z * b2.z);
            hv[7] = fast_tanh(ewb.w + ewb.x * b0.w + ewb.y * b1.w + ewb.z * b2.w);
            uint4 pu = make_uint4(pk2(hv[0], hv[1]), pk2(hv[2], hv[3]),
                                  pk2(hv[4], hv[5]), pk2(hv[6], hv[7]));
            int byteoff = (c * 256 + (wl0 + u * 8) * 2) ^ ((c & 15) << 4);
            *(uint4*)((char*)Ah + byteoff) = pu;
        }
    }
    __syncthreads();

    // phase2: wave v = c-tile; lane: n=li, k-group g; 4 k-steps, 1 MFMA each
    const int lane = t & 63;
    const int v    = t >> 6;
    const int li   = lane & 15;
    const int g    = lane >> 4;
    f32x4 acc = {0.f, 0.f, 0.f, 0.f};
    #pragma unroll
    for (int kk = 0; kk < 4; ++kk) {
        int cm = v * 16 + li;
        int coff = (cm * 256 + (kk * 32 + g * 8) * 2) ^ ((cm & 15) << 4);
        s16x8 ah = *(const s16x8*)((const char*)Ah + coff);
        int wg = wh * 128 + kk * 32 + g * 8;
        s16x8 bh = *(const s16x8*)(Tpk + li * 256 + wg);
        acc = __builtin_amdgcn_mfma_f32_16x16x32_bf16(ah, bh, acc, 0, 0, 0);
    }
    if (li < 8) {
        const int q = li & 3, reim = li >> 2;
        float* pb2 = P2 + (size_t)((((wh * NB + b) * 4 + q) * 256 + row) * 64
                                   + v * 16 + g * 4) * 2 + reim;
        #pragma unroll
        for (int e = 0; e < 4; ++e) pb2[e * 2] = acc[e];
    }
}

// ---------------------------------------------------------------------------
// K3 (spec, fused column-DFT front end):
//  slots 0-11 = q123 pairs (two independent (q,p) items/block);
//  slots 12-16 = ky=0 Hermitian groups. grid = b*17.
//  Front end: each which-half row-sums P2 over 256 rows (coalesced float2)
//  with staged twiddles -> s0 in LDS; then the 6-layer iteration as before.
// ---------------------------------------------------------------------------
__global__ __launch_bounds__(128) void k_spec(
    const float* __restrict__ Wtr, const float* __restrict__ Wti,
    const float* __restrict__ P2, float2* __restrict__ dacc)
{
    __shared__ float Wr[2][NCH * NCH];
    __shared__ float Wi[2][NCH * NCH];
    __shared__ float sr[2][NCH], si[2][NCH];
    __shared__ float2 FL[2][NCH];
    __shared__ float twc[2][256], tws[2][256];
    const int gx    = blockIdx.x;
    const int b     = gx / 17;
    const int slot  = gx % 17;
    const int which = threadIdx.x >> 6;
    const int o     = threadIdx.x & 63;

    // item selection
    int p = -1, q = 0, g = -1;
    if (slot < 12) {
        int r = slot * 2 + which;          // 0..23
        q = (r >> 3) + 1;
        p = r & 7;
    } else {
        g = slot - 12;
        if (which == 0) p = g;
        else            p = (g == 1) ? 7 : (g == 2) ? 6 : (g == 3) ? 5 : -1;
        q = 0;
    }
    const bool active = (p >= 0);

    // stage W (coalesced from pre-transposed Wt) + twiddles
    if (active) {
        const float4* wr = (const float4*)(Wtr + (p * 4 + q) * 4096);
        const float4* wi = (const float4*)(Wti + (p * 4 + q) * 4096);
        float4* dr = (float4*)&Wr[which][0];
        float4* di = (float4*)&Wi[which][0];
        #pragma unroll
        for (int k = 0; k < 16; ++k) {
            dr[o + 64 * k] = wr[o + 64 * k];
            di[o + 64 * k] = wi[o + 64 * k];
        }
        const int kxs[8] = {0, 1, 2, 3, -4, -3, -2, -1};
        int kx = kxs[p];
        int ka = kx < 0 ? -kx : kx;
        float sgn = kx < 0 ? 1.f : -1.f;
        #pragma unroll
        for (int z = 0; z < 4; ++z) {
            int rw = o + z * 64;
            float a = (float)(ka * rw) * (1.0f / 256.0f);
            twc[which][rw] = cos2pi(a);
            tws[which][rw] = sgn * sin2pi(a);
        }
    }
    __syncthreads();

    // fused coldft: row-sum with twiddles (both wh planes)
    if (active) {
        const float* pA = P2 + (size_t)(((0 * NB + b) * 4 + q) * 256) * 128 + o * 2;
        const float* pB = P2 + (size_t)(((1 * NB + b) * 4 + q) * 256) * 128 + o * 2;
        float s_r = 0.f, s_i = 0.f;
        #pragma unroll 4
        for (int rw = 0; rw < 256; ++rw) {
            float2 u = *(const float2*)(pA + (size_t)rw * 128);
            float2 v = *(const float2*)(pB + (size_t)rw * 128);
            float pr = u.x + v.x, pi = u.y + v.y;
            float tr = twc[which][rw], ti = tws[which][rw];
            s_r += pr * tr - pi * ti;
            s_i += pr * ti + pi * tr;
        }
        sr[which][o] = s_r; si[which][o] = s_i;
    }
    __syncthreads();

    if (slot < 12) {
        float dr = 0.f, di = 0.f;
        for (int l = 0; l < NLAYERS; ++l) {
            float Fr = 0.f, Fi = 0.f;
            for (int i = 0; i < NCH; ++i) {
                float a0 = sr[which][i], a1 = si[which][i];
                float b0 = Wr[which][i * NCH + o], b1 = Wi[which][i * NCH + o];
                Fr += a0 * b0 - a1 * b1;
                Fi += a0 * b1 + a1 * b0;
            }
            __syncthreads();
            sr[which][o] += Fr; si[which][o] += Fi;
            dr += Fr; di += Fi;
            __syncthreads();
        }
        dacc[((b * 9 + p) * 4 + q) * NCH + o] = make_float2(dr, di);
    } else {
        float dr = 0.f, di = 0.f, d8r = 0.f, d8i = 0.f;
        for (int l = 0; l < NLAYERS; ++l) {
            float Fr = 0.f, Fi = 0.f;
            if (active) {
                for (int i = 0; i < NCH; ++i) {
                    float a0 = sr[which][i], a1 = si[which][i];
                    float b0 = Wr[which][i * NCH + o], b1 = Wi[which][i * NCH + o];
                    Fr += a0 * b0 - a1 * b1;
                    Fi += a0 * b1 + a1 * b0;
                }
            }
            FL[which][o] = make_float2(Fr, Fi);
            __syncthreads();
            float addr_ = 0.f, addi_ = 0.f;
            if (active) {
                if (g == 0) { addr_ = Fr; addi_ = 0.f; }
                else if (g == 4) {
                    addr_ = 0.5f * Fr; addi_ = 0.5f * Fi;
                    d8r += 0.5f * Fr;  d8i -= 0.5f * Fi;
                } else {
                    float2 Fo = FL[1 - which][o];
                    addr_ = 0.5f * (Fr + Fo.x);
                    addi_ = 0.5f * (Fi - Fo.y);
                }
                sr[which][o] += addr_; si[which][o] += addi_;
                dr += addr_; di += addi_;
            }
            __syncthreads();
        }
        if (active) dacc[((b * 9 + p) * 4 + 0) * NCH + o] = make_float2(dr, di);
        if (g == 4 && which == 0)
            dacc[((b * 9 + 8) * 4 + 0) * NCH + o] = make_float2(d8r, d8i);
    }
}

// ---------------------------------------------------------------------------
// K4: per-(b,row) rank-7 coefficients Bc[j][o] (basis {1,c1,c2,c3,s1,s2,s3})
// ---------------------------------------------------------------------------
__global__ __launch_bounds__(256) void k_rowcorr(
    const float2* __restrict__ dacc, const float* __restrict__ dec1_w,
    float* __restrict__ Bc)
{
    __shared__ __align__(16) float coef[7][NCH];
    const int bi  = blockIdx.x;            // b*256+row
    const int b   = bi >> 8;
    const int row = bi & 255;
    const int t   = threadIdx.x;
    {
        const int c = t >> 2, q = t & 3;
        float tc[5], ts[5];
        tc[0] = 1.f; ts[0] = 0.f;
        #pragma unroll
        for (int k = 1; k < 5; ++k) {
            float a = (float)(k * row) * (1.0f / 256.0f);
            tc[k] = cos2pi(a); ts[k] = sin2pi(a);    // e^{+2pi i k row/256}
        }
        float twr[9] = {tc[0], tc[1], tc[2], tc[3], tc[4], tc[3], tc[2], tc[1], tc[4]};
        float twi[9] = {ts[0], ts[1], ts[2], ts[3], -ts[4], -ts[3], -ts[2], -ts[1], ts[4]};
        float gr = 0.f, gi = 0.f;
        #pragma unroll
        for (int p = 0; p < 9; ++p) {
            if (p == 8 && q != 0) continue;
            float2 v = dacc[((b * 9 + p) * 4 + q) * NCH + c];
            gr += v.x * twr[p] - v.y * twi[p];
            gi += v.x * twi[p] + v.y * twr[p];
        }
        const float s = ((q == 0) ? 1.0f : 2.0f) * (1.0f / 65536.0f);
        if (q == 0) {
            coef[0][c] = gr * s;
        } else {
            coef[q][c]     = gr * s;
            coef[3 + q][c] = -gi * s;
        }
    }
    __syncthreads();
    const int o = t & 63;
    const int v = t >> 6;
    float4 wrow[16];
    #pragma unroll
    for (int k = 0; k < 16; ++k) wrow[k] = ((const float4*)(dec1_w + o * NCH))[k];
    float* bcrow = Bc + (size_t)bi * 512;
    {
        float s = 0.f;
        #pragma unroll
        for (int k = 0; k < 16; ++k) {
            float4 cf = ((const float4*)&coef[v][0])[k];
            s += wrow[k].x * cf.x + wrow[k].y * cf.y + wrow[k].z * cf.z + wrow[k].w * cf.w;
        }
        bcrow[v * 64 + o] = s;
    }
    if (v < 3) {
        float s = 0.f;
        #pragma unroll
        for (int k = 0; k < 16; ++k) {
            float4 cf = ((const float4*)&coef[4 + v][0])[k];
            s += wrow[k].x * cf.x + wrow[k].y * cf.y + wrow[k].z * cf.z + wrow[k].w * cf.w;
        }
        bcrow[(4 + v) * 64 + o] = s;
    }
}

// ---------------------------------------------------------------------------
// K5: final. A-frags (2h0 bf16 hi/lo) in registers; W via pre-swizzled LDS;
// rank-7 correction as an extra MFMA (basis[16x8] @ BcT[8x64] into acc).
// ---------------------------------------------------------------------------
__global__ __launch_bounds__(256) void k_final(
    const float* __restrict__ x, const float* __restrict__ encwb,
    const unsigned short* __restrict__ Wpk, const float* __restrict__ Bc,
    const float* __restrict__ dec1_b, const float* __restrict__ dec2_w,
    const float* __restrict__ dec2_b, float* __restrict__ out)
{
    __shared__ __align__(16) unsigned short Wl[2][NCH * NCH];  // 16 KB (hi, lo)
    __shared__ __align__(16) unsigned short BcsT[NCH][8];      // 1 KB (o-major)
    const int bi   = blockIdx.x;
    const int b    = bi >> 9;
    const int rem  = bi & 511;
    const int row  = rem >> 1;
    const int half = rem & 1;
    const int t    = threadIdx.x;

    // phase0: stage W (linear copy of pre-swizzled image) + BcT (bf16)
    {
        const uint4* src = (const uint4*)Wpk;
        uint4* dst = (uint4*)&Wl[0][0];
        #pragma unroll
        for (int k = 0; k < 4; ++k) dst[t + 256 * k] = src[t + 256 * k];
        if (t < 112) {
            int e0 = t * 4, j = e0 >> 6, o = e0 & 63;
            float4 f = ((const float4*)(Bc + (size_t)(b * 256 + row) * 512))[t];
            BcsT[o + 0][j] = f2bf(f.x);
            BcsT[o + 1][j] = f2bf(f.y);
            BcsT[o + 2][j] = f2bf(f.z);
            BcsT[o + 3][j] = f2bf(f.w);
        } else if (t < 128) {
            int o = (t - 112) * 4;
            #pragma unroll
            for (int z = 0; z < 4; ++z) BcsT[o + z][7] = 0;
        }
    }
    __syncthreads();

    const int lane = t & 63;
    const int wv   = t >> 6;
    const int li   = lane & 15;
    const int g    = lane >> 4;

    // phase1: A-frags in registers (pixel = half*128+(wv*2+i)*16+li)
    s16x8 ahi[2][2], alo[2][2];
    {
        float xs0[2], xs1[2], xs2[2];
        #pragma unroll
        for (int i = 0; i < 2; ++i) {
            int px = half * 128 + (wv * 2 + i) * 16 + li;
            xs0[i] = x[((b * 3 + 0) * NH + row) * NW + px];
            xs1[i] = x[((b * 3 + 1) * NH + row) * NW + px];
            xs2[i] = x[((b * 3 + 2) * NH + row) * NW + px];
        }
        #pragma unroll
        for (int ks = 0; ks < 2; ++ks) {
            unsigned int hu[2][4], lu[2][4];
            #pragma unroll
            for (int j2 = 0; j2 < 4; ++j2) {
                float4 e0 = ((const float4*)encwb)[ks * 32 + g * 8 + j2 * 2 + 0];
                float4 e1 = ((const float4*)encwb)[ks * 32 + g * 8 + j2 * 2 + 1];
                #pragma unroll
                for (int i = 0; i < 2; ++i) {
                    float va = 2.0f * fast_tanh(e0.w + e0.x * xs0[i] + e0.y * xs1[i] + e0.z * xs2[i]);
                    float vb = 2.0f * fast_tanh(e1.w + e1.x * xs0[i] + e1.y * xs1[i] + e1.z * xs2[i]);
                    unsigned int h = pk2(va, vb);
                    float ha = __uint_as_float(h << 16);
                    float hb = __uint_as_float(h & 0xffff0000u);
                    hu[i][j2] = h;
                    lu[i][j2] = pk2(va - ha, vb - hb);
                }
            }
            #pragma unroll
            for (int i = 0; i < 2; ++i) {
                ahi[i][ks] = u4cast(make_uint4(hu[i][0], hu[i][1], hu[i][2], hu[i][3]));
                alo[i][ks] = u4cast(make_uint4(lu[i][0], lu[i][1], lu[i][2], lu[i][3]));
            }
        }
    }

    // phase2: main MFMA (3-term bf16 split)
    f32x4 acc[2][4];
    #pragma unroll
    for (int i = 0; i < 2; ++i)
        #pragma unroll
        for (int nt = 0; nt < 4; ++nt)
            acc[i][nt] = (f32x4){0.f, 0.f, 0.f, 0.f};
    #pragma unroll
    for (int ks = 0; ks < 2; ++ks) {
        #pragma unroll
        for (int nt = 0; nt < 4; ++nt) {
            int o = nt * 16 + li;
            int byteoff = (o * 128 + ks * 64 + g * 16) ^ ((o & 7) << 4);
            s16x8 wh = *(const s16x8*)((const char*)&Wl[0][0] + byteoff);
            s16x8 wl = *(const s16x8*)((const char*)&Wl[1][0] + byteoff);
            #pragma unroll
            for (int i = 0; i < 2; ++i) {
                acc[i][nt] = __builtin_amdgcn_mfma_f32_16x16x32_bf16(ahi[i][ks], wh, acc[i][nt], 0, 0, 0);
                acc[i][nt] = __builtin_amdgcn_mfma_f32_16x16x32_bf16(alo[i][ks], wh, acc[i][nt], 0, 0, 0);
                acc[i][nt] = __builtin_amdgcn_mfma_f32_16x16x32_bf16(ahi[i][ks], wl, acc[i][nt], 0, 0, 0);
            }
        }
    }

    // phase2b: rank-7 correction via MFMA: basis(px)[k=0..7] @ BcT[k][o]
    {
        s16x8 aC[2];
        #pragma unroll
        for (int i = 0; i < 2; ++i) {
            if (g == 0) {
                int px = half * 128 + (wv * 2 + i) * 16 + li;
                float pf = (float)px;
                float c1 = cos2pi(pf * (1.0f / 256.0f)), s1 = sin2pi(pf * (1.0f / 256.0f));
                float c2 = cos2pi(pf * (2.0f / 256.0f)), s2 = sin2pi(pf * (2.0f / 256.0f));
                float c3 = cos2pi(pf * (3.0f / 256.0f)), s3 = sin2pi(pf * (3.0f / 256.0f));
                aC[i] = u4cast(make_uint4(pk2(1.0f, c1), pk2(c2, c3),
                                          pk2(s1, s2), pk2(s3, 0.0f)));
            } else {
                aC[i] = u4cast(make_uint4(0, 0, 0, 0));
            }
        }
        #pragma unroll
        for (int nt = 0; nt < 4; ++nt) {
            s16x8 bC;
            if (g == 0) bC = *(const s16x8*)(&BcsT[nt * 16 + li][0]);
            else        bC = u4cast(make_uint4(0, 0, 0, 0));
            #pragma unroll
            for (int i = 0; i < 2; ++i)
                acc[i][nt] = __builtin_amdgcn_mfma_f32_16x16x32_bf16(aC[i], bC, acc[i][nt], 0, 0, 0);
        }
    }

    // epilogue
    float d1b[4], d2w[4];
    #pragma unroll
    for (int nt = 0; nt < 4; ++nt) {
        int o = nt * 16 + li;
        d1b[nt] = dec1_b[o];
        d2w[nt] = dec2_w[o];
    }
    const float d2b = dec2_b[0];
    float* orow = out + (b * NH + row) * NW;
    #pragma unroll
    for (int i = 0; i < 2; ++i) {
        #pragma unroll
        for (int r = 0; r < 4; ++r) {
            float partial = 0.f;
            #pragma unroll
            for (int nt = 0; nt < 4; ++nt) {
                float sv = acc[i][nt][r] + d1b[nt];
                partial += d2w[nt] * fast_tanh(sv);
            }
            partial += __shfl_xor(partial, 1);
            partial += __shfl_xor(partial, 2);
            partial += __shfl_xor(partial, 4);
            partial += __shfl_xor(partial, 8);
            if (li == 0) {
                int px = half * 128 + (wv * 2 + i) * 16 + g * 4 + r;
                orow[px] = d2b + partial;
            }
        }
    }
}

extern "C" void kernel_launch(void* const* d_in, const int* in_sizes, int n_in,
                              void* d_out, int out_size, void* d_ws, size_t ws_size,
                              hipStream_t stream) {
    (void)in_sizes; (void)n_in; (void)out_size; (void)ws_size;
    const float* x      = (const float*)d_in[0];
    const float* enc_w  = (const float*)d_in[1];
    const float* enc_b  = (const float*)d_in[2];
    const float* dec1_w = (const float*)d_in[3];
    const float* dec1_b = (const float*)d_in[4];
    const float* dec2_w = (const float*)d_in[5];
    const float* dec2_b = (const float*)d_in[6];
    const float* w1r    = (const float*)d_in[7];
    const float* w1i    = (const float*)d_in[8];
    const float* w2r    = (const float*)d_in[9];
    const float* w2i    = (const float*)d_in[10];
    float* out = (float*)d_out;

    char* ws = (char*)d_ws;
    // P2 (8 MB, dead after k_spec) overlaps Bc (4 MB, written by k_rowcorr after)
    float*  P2    = (float*)(ws);                          // [2][8][4][256][64][2] f32 = 8 MB
    float*  Bc    = (float*)(ws);                          // [2048][8][64] f32 (aliases P2)
    float2* dd    = (float2*)(ws + (8u << 20));            // dacc 144 KB
    char*   p0    = ws + (8u << 20) + 147456;
    unsigned short* Wpk = (unsigned short*)(p0);           // 16 KB
    unsigned short* Tpk = (unsigned short*)(p0 + 16384);   // 8 KB
    float*  encwb = (float*)(p0 + 16384 + 8192);           // 1 KB
    float*  Wtr   = (float*)(p0 + 16384 + 8192 + 1024);            // 512 KB
    float*  Wti   = (float*)(p0 + 16384 + 8192 + 1024 + 524288);   // 512 KB

    k_prep     <<<1031, 256, 0, stream>>>(dec1_w, enc_w, enc_b, w1r, w1i, w2r, w2i,
                                          Wpk, Tpk, encwb, Wtr, Wti);
    k_enc_mfma <<<NB * NH * 2, 256, 0, stream>>>(x, encwb, Tpk, P2);
    k_spec     <<<NB * 17, 128, 0, stream>>>(Wtr, Wti, P2, dd);
    k_rowcorr  <<<NB * NH, 256, 0, stream>>>(dd, dec1_w, Bc);
    k_final    <<<NB * NH * 2, 256, 0, stream>>>(x, encwb, Wpk, Bc, dec1_b,
                                                 dec2_w, dec2_b, out);
}

// Round 8
// 167.435 us; speedup vs baseline: 1.7696x; 1.1818x over previous
//
#include <hip/hip_runtime.h>
#include <hip/hip_bf16.h>

#define NB 8
#define NCIN 3
#define NCH 64
#define NH 256
#define NW 256
#define NM 4
#define NLAYERS 6

typedef short s16x8 __attribute__((ext_vector_type(8)));
typedef float f32x4 __attribute__((ext_vector_type(4)));

// tanh(x) = 1 - 2*rcp(1+e^{2x}); v_exp + v_rcp (no precise-div sequence).
__device__ __forceinline__ float fast_tanh(float x) {
    float e = __expf(2.0f * x);
    return 1.0f - 2.0f * __builtin_amdgcn_rcpf(1.0f + e);
}
// sin/cos of (2*pi*x): raw v_sin/v_cos, input in revolutions (|x|<5 here)
__device__ __forceinline__ float sin2pi(float x) { return __builtin_amdgcn_sinf(x); }
__device__ __forceinline__ float cos2pi(float x) { return __builtin_amdgcn_cosf(x); }

// pack 2 fp32 -> 2 bf16 (RNE) in one u32; compiler emits v_cvt_pk_bf16_f32
__device__ __forceinline__ unsigned int pk2(float a, float b) {
    __hip_bfloat162 h = __float22bfloat162_rn(make_float2(a, b));
    unsigned int u; __builtin_memcpy(&u, &h, 4); return u;
}
__device__ __forceinline__ s16x8 u4cast(uint4 u) {
    s16x8 r; __builtin_memcpy(&r, &u, 16); return r;
}
__device__ __forceinline__ unsigned short f2bf(float f) {
    unsigned int u = __float_as_uint(f);
    u = u + 0x7fffu + ((u >> 16) & 1u);
    return (unsigned short)(u >> 16);
}

// ---------------------------------------------------------------------------
// K0: prep (1032 blocks).
//  [0,1024):  Wt{r,i}[p][q][i][o] fp32 transpose of w1/w2
//  1024-1025: Wpk = dec1_w bf16 hi/lo planes, XOR-swizzled image
//  1026-1029: Tpk = row-DFT twiddles [n=16][w=256] bf16
//  1030:      encwb[64] = {enc_w[c][0..2], enc_b[c]}
//  1031:      d1wT[c][o] = dec1_w[o][c]  (for k_spec's dd2 tail)
// ---------------------------------------------------------------------------
__global__ __launch_bounds__(256) void k_prep(
    const float* __restrict__ dec1_w, const float* __restrict__ enc_w,
    const float* __restrict__ enc_b,
    const float* __restrict__ w1r, const float* __restrict__ w1i,
    const float* __restrict__ w2r, const float* __restrict__ w2i,
    unsigned short* __restrict__ Wpk, unsigned short* __restrict__ Tpk,
    float* __restrict__ encwb, float* __restrict__ Wtr, float* __restrict__ Wti,
    float* __restrict__ d1wT)
{
    const int bid = blockIdx.x;
    const int t   = threadIdx.x;
    if (bid < 1024) {
        int elem = bid * 256 + t;              // [0, 262144)
        int ri = elem >> 17;
        int rem = elem & 0x1FFFF;
        int p  = rem >> 14;
        int q  = (rem >> 12) & 3;
        int i  = (rem >> 6) & 63;
        int o  = rem & 63;
        const float* src;
        if (p < 4) src = ri ? w1i : w1r;
        else       src = ri ? w2i : w2r;
        float v = src[((i * 64 + o) * 4 + (p & 3)) * 4 + q];
        float* dst = ri ? Wti : Wtr;
        dst[(p * 4 + q) * 4096 + i * 64 + o] = v;
    } else if (bid < 1026) {
        const int tt = (bid - 1024) * 256 + t;  // [0,512)
        const int o  = tt & 63;
        const int cb = (tt >> 6) * 8;           // {0,8,...,56}
        const float* wr = dec1_w + o * NCH + cb;
        float4 wa = ((const float4*)wr)[0];
        float4 wb = ((const float4*)wr)[1];
        float v[8] = {wa.x, wa.y, wa.z, wa.w, wb.x, wb.y, wb.z, wb.w};
        unsigned int ph[4], pl[4];
        #pragma unroll
        for (int j = 0; j < 4; ++j) {
            unsigned int h = pk2(v[2 * j], v[2 * j + 1]);
            float ha = __uint_as_float(h << 16);
            float hb = __uint_as_float(h & 0xffff0000u);
            ph[j] = h;
            pl[j] = pk2(v[2 * j] - ha, v[2 * j + 1] - hb);
        }
        int byteoff = (o * 128 + cb * 2) ^ ((o & 7) << 4);
        *(uint4*)((char*)Wpk + byteoff)        = make_uint4(ph[0], ph[1], ph[2], ph[3]);
        *(uint4*)((char*)Wpk + 8192 + byteoff) = make_uint4(pl[0], pl[1], pl[2], pl[3]);
    } else if (bid < 1030) {
        const int tt = (bid - 1026) * 256 + t;  // [0,1024)
        const int n  = tt >> 6;
        const int w4 = (tt & 63) * 4;
        float vv[4];
        #pragma unroll
        for (int z = 0; z < 4; ++z) {
            int w = w4 + z;
            float val = 0.f;
            if (n < 4)      val = cos2pi((float)(n * w) * (1.0f / 256.0f));
            else if (n < 8) val = -sin2pi((float)((n - 4) * w) * (1.0f / 256.0f));
            vv[z] = val;
        }
        *(uint2*)(Tpk + n * 256 + w4) = make_uint2(pk2(vv[0], vv[1]), pk2(vv[2], vv[3]));
    } else if (bid == 1030) {
        if (t < NCH) {
            float4 e4;
            e4.x = enc_w[t * 3 + 0]; e4.y = enc_w[t * 3 + 1];
            e4.z = enc_w[t * 3 + 2]; e4.w = enc_b[t];
            ((float4*)encwb)[t] = e4;
        }
    } else {
        for (int idx = t; idx < 4096; idx += 256) {
            int c = idx >> 6, o = idx & 63;
            d1wT[idx] = dec1_w[o * NCH + c];
        }
    }
}

// ---------------------------------------------------------------------------
// K1: encoder + row DFT on MFMA (single-term bf16).
// block=(b,row,wh) covers 128 w. out: P2[wh][b][c][row][q][reim] fp32
// ---------------------------------------------------------------------------
__global__ __launch_bounds__(256) void k_enc_mfma(
    const float* __restrict__ x, const float* __restrict__ encwb,
    const unsigned short* __restrict__ Tpk, float* __restrict__ P2)
{
    __shared__ __align__(16) unsigned short Ah[64 * 128];  // 16 KB
    const int bi  = blockIdx.x;
    const int b   = bi >> 9;
    const int rem = bi & 511;
    const int row = rem >> 1;
    const int wh  = rem & 1;
    const int t   = threadIdx.x;

    {
        const int c   = t & 63;
        const int wl0 = (t >> 6) * 32;
        float4 ewb = ((const float4*)encwb)[c];
        const float* xr0 = x + ((b * 3 + 0) * NH + row) * NW + wh * 128 + wl0;
        const float* xr1 = x + ((b * 3 + 1) * NH + row) * NW + wh * 128 + wl0;
        const float* xr2 = x + ((b * 3 + 2) * NH + row) * NW + wh * 128 + wl0;
        #pragma unroll
        for (int u = 0; u < 4; ++u) {
            float4 a0 = ((const float4*)xr0)[u * 2], b0 = ((const float4*)xr0)[u * 2 + 1];
            float4 a1 = ((const float4*)xr1)[u * 2], b1 = ((const float4*)xr1)[u * 2 + 1];
            float4 a2 = ((const float4*)xr2)[u * 2], b2 = ((const float4*)xr2)[u * 2 + 1];
            float hv[8];
            hv[0] = fast_tanh(ewb.w + ewb.x * a0.x + ewb.y * a1.x + ewb.z * a2.x);
            hv[1] = fast_tanh(ewb.w + ewb.x * a0.y + ewb.y * a1.y + ewb.z * a2.y);
            hv[2] = fast_tanh(ewb.w + ewb.x * a0.z + ewb.y * a1.z + ewb.z * a2.z);
            hv[3] = fast_tanh(ewb.w + ewb.x * a0.w + ewb.y * a1.w + ewb.z * a2.w);
            hv[4] = fast_tanh(ewb.w + ewb.x * b0.x + ewb.y * b1.x + ewb.z * b2.x);
            hv[5] = fast_tanh(ewb.w + ewb.x * b0.y + ewb.y * b1.y + ewb.z * b2.y);
            hv[6] = fast_tanh(ewb.w + ewb.x * b0.z + ewb.y * b1.z + ewb.z * b2.z);
            hv[7] = fast_tanh(ewb.w + ewb.x * b0.w + ewb.y * b1.w + ewb.z * b2.w);
            uint4 pu = make_uint4(pk2(hv[0], hv[1]), pk2(hv[2], hv[3]),
                                  pk2(hv[4], hv[5]), pk2(hv[6], hv[7]));
            int byteoff = (c * 256 + (wl0 + u * 8) * 2) ^ ((c & 15) << 4);
            *(uint4*)((char*)Ah + byteoff) = pu;
        }
    }
    __syncthreads();

    const int lane = t & 63;
    const int v    = t >> 6;
    const int li   = lane & 15;
    const int g    = lane >> 4;
    f32x4 acc = {0.f, 0.f, 0.f, 0.f};
    #pragma unroll
    for (int kk = 0; kk < 4; ++kk) {
        int cm = v * 16 + li;
        int coff = (cm * 256 + (kk * 32 + g * 8) * 2) ^ ((cm & 15) << 4);
        s16x8 ah = *(const s16x8*)((const char*)Ah + coff);
        int wg = wh * 128 + kk * 32 + g * 8;
        s16x8 bh = *(const s16x8*)(Tpk + li * 256 + wg);
        acc = __builtin_amdgcn_mfma_f32_16x16x32_bf16(ah, bh, acc, 0, 0, 0);
    }
    if (li < 8) {
        const int q = li & 3, reim = li >> 2;
        float* pbase = P2 + (size_t)wh * (NB * 64 * 256 * 8);
        #pragma unroll
        for (int e = 0; e < 4; ++e) {
            int c = v * 16 + g * 4 + e;
            pbase[(((b * 64 + c) * 256 + row) * 4 + q) * 2 + reim] = acc[e];
        }
    }
}

// ---------------------------------------------------------------------------
// K2: column DFT. block=(b,c), 64 threads = (p,q,reim); each thread owns the
// full 256-row sum. P halves summed during LDS staging. Reads P2 exactly once.
// ---------------------------------------------------------------------------
__global__ __launch_bounds__(64) void k_coldft(const float* __restrict__ P2,
                                               float2* __restrict__ s0)
{
    __shared__ __align__(16) float Ps[256][8];   // 8 KB
    __shared__ float twc[5][256];
    __shared__ float tws[5][256];
    const int b = blockIdx.x >> 6;
    const int c = blockIdx.x & 63;
    const int t = threadIdx.x;
    {
        const float4* pa = (const float4*)(P2 + (size_t)(b * 64 + c) * 256 * 8);
        const float4* pb = pa + (size_t)NB * 64 * 256 * 2;   // wh=1 plane
        float4* ds = (float4*)&Ps[0][0];
        #pragma unroll
        for (int k = 0; k < 8; ++k) {
            int s = t + 64 * k;
            float4 u = pa[s], v = pb[s];
            ds[s] = make_float4(u.x + v.x, u.y + v.y, u.z + v.z, u.w + v.w);
        }
        for (int idx = t; idx < 5 * 256; idx += 64) {
            int k = idx >> 8, rw = idx & 255;
            float a = (float)(k * rw) * (1.0f / 256.0f);
            twc[k][rw] = cos2pi(a);
            tws[k][rw] = sin2pi(a);
        }
    }
    __syncthreads();
    const int kxs[8] = {0, 1, 2, 3, -4, -3, -2, -1};
    const int p = t >> 3, q = (t >> 1) & 3, reim = t & 1;
    const int kx = kxs[p];
    const int ka = kx < 0 ? -kx : kx;
    const float sgn = (kx < 0) ? 1.f : -1.f;
    float acc = 0.f;
    #pragma unroll 4
    for (int rw = 0; rw < 256; ++rw) {
        float pr = Ps[rw][q * 2], pi = Ps[rw][q * 2 + 1];
        float tr = twc[ka][rw], ti = sgn * tws[ka][rw];
        acc += reim ? (pr * ti + pi * tr) : (pr * tr - pi * ti);
    }
    ((float*)s0)[(((b * 8 + p) * 4 + q) * NCH + c) * 2 + reim] = acc;
}

// ---------------------------------------------------------------------------
// K3 (spec + dd2 tail): slots 0-11 = q123 pairs; 12-16 = ky=0 Hermitian groups.
// grid = b*17. Reads s0; 6-layer iteration; then dd2[p][q][o] = d @ dec1_w^T
// (the row-synthesis and dec1_w matmul commute) -- k_rowcorr is gone.
// ---------------------------------------------------------------------------
__global__ __launch_bounds__(128) void k_spec(
    const float* __restrict__ Wtr, const float* __restrict__ Wti,
    const float* __restrict__ d1wT, const float2* __restrict__ s0,
    float2* __restrict__ dd2)
{
    __shared__ float Wr[2][NCH * NCH];
    __shared__ float Wi[2][NCH * NCH];
    __shared__ float sr[2][NCH], si[2][NCH];
    __shared__ float2 FL[2][NCH];
    __shared__ float W1T[NCH * NCH];       // d1wT staged, 16 KB
    const int gx    = blockIdx.x;
    const int b     = gx / 17;
    const int slot  = gx % 17;
    const int which = threadIdx.x >> 6;
    const int o     = threadIdx.x & 63;
    const int tid   = threadIdx.x;

    int p = -1, q = 0, g = -1;
    if (slot < 12) {
        int r = slot * 2 + which;
        q = (r >> 3) + 1;
        p = r & 7;
    } else {
        g = slot - 12;
        if (which == 0) p = g;
        else            p = (g == 1) ? 7 : (g == 2) ? 6 : (g == 3) ? 5 : -1;
        q = 0;
    }
    const bool active = (p >= 0);

    // stage W (coalesced from pre-transposed Wt) + d1wT + s0
    if (active) {
        const float4* wr = (const float4*)(Wtr + (p * 4 + q) * 4096);
        const float4* wi = (const float4*)(Wti + (p * 4 + q) * 4096);
        float4* dr = (float4*)&Wr[which][0];
        float4* di = (float4*)&Wi[which][0];
        #pragma unroll
        for (int k = 0; k < 16; ++k) {
            dr[o + 64 * k] = wr[o + 64 * k];
            di[o + 64 * k] = wi[o + 64 * k];
        }
        float2 sv = s0[((b * 8 + p) * 4 + q) * NCH + o];
        sr[which][o] = sv.x; si[which][o] = sv.y;
    }
    {
        float4* w1 = (float4*)W1T;
        const float4* sw = (const float4*)d1wT;
        #pragma unroll
        for (int k = 0; k < 8; ++k) w1[tid + 128 * k] = sw[tid + 128 * k];
    }
    __syncthreads();

    float dr = 0.f, di = 0.f, d8r = 0.f, d8i = 0.f;
    if (slot < 12) {
        for (int l = 0; l < NLAYERS; ++l) {
            float Fr = 0.f, Fi = 0.f;
            for (int i = 0; i < NCH; ++i) {
                float a0 = sr[which][i], a1 = si[which][i];
                float b0 = Wr[which][i * NCH + o], b1 = Wi[which][i * NCH + o];
                Fr += a0 * b0 - a1 * b1;
                Fi += a0 * b1 + a1 * b0;
            }
            __syncthreads();
            sr[which][o] += Fr; si[which][o] += Fi;
            dr += Fr; di += Fi;
            __syncthreads();
        }
    } else {
        for (int l = 0; l < NLAYERS; ++l) {
            float Fr = 0.f, Fi = 0.f;
            if (active) {
                for (int i = 0; i < NCH; ++i) {
                    float a0 = sr[which][i], a1 = si[which][i];
                    float b0 = Wr[which][i * NCH + o], b1 = Wi[which][i * NCH + o];
                    Fr += a0 * b0 - a1 * b1;
                    Fi += a0 * b1 + a1 * b0;
                }
            }
            FL[which][o] = make_float2(Fr, Fi);
            __syncthreads();
            float addr_ = 0.f, addi_ = 0.f;
            if (active) {
                if (g == 0) { addr_ = Fr; addi_ = 0.f; }
                else if (g == 4) {
                    addr_ = 0.5f * Fr; addi_ = 0.5f * Fi;
                    d8r += 0.5f * Fr;  d8i -= 0.5f * Fi;
                } else {
                    float2 Fo = FL[1 - which][o];
                    addr_ = 0.5f * (Fr + Fo.x);
                    addi_ = 0.5f * (Fi - Fo.y);
                }
                sr[which][o] += addr_; si[which][o] += addi_;
                dr += addr_; di += addi_;
            }
            __syncthreads();
        }
    }

    // tail: dd2[p][q][o] = sum_c d[c] * dec1_w[o][c]
    sr[which][o] = dr; si[which][o] = di;
    if (slot == 16 && which == 0) FL[0][o] = make_float2(d8r, d8i);
    __syncthreads();
    float2* db = dd2 + (size_t)b * (9 * 4 * NCH);
    if (active) {
        float ar = 0.f, ai = 0.f;
        for (int c = 0; c < NCH; ++c) {
            float wv = W1T[c * NCH + o];
            ar += sr[which][c] * wv;
            ai += si[which][c] * wv;
        }
        db[(p * 4 + q) * NCH + o] = make_float2(ar, ai);
    }
    if (slot == 16 && which == 0) {
        float ar = 0.f, ai = 0.f;
        for (int c = 0; c < NCH; ++c) {
            float wv = W1T[c * NCH + o];
            ar += FL[0][c].x * wv;
            ai += FL[0][c].y * wv;
        }
        db[(8 * 4 + 0) * NCH + o] = make_float2(ar, ai);
    }
}

// ---------------------------------------------------------------------------
// K5: final. A-frags (2h0 bf16 hi/lo) in registers; W via pre-swizzled LDS;
// rank-7 coef built inline from dd2 (18 KB, L2-hot); correction via MFMA.
// ---------------------------------------------------------------------------
__global__ __launch_bounds__(256) void k_final(
    const float* __restrict__ x, const float* __restrict__ encwb,
    const unsigned short* __restrict__ Wpk, const float2* __restrict__ dd2,
    const float* __restrict__ dec1_b, const float* __restrict__ dec2_w,
    const float* __restrict__ dec2_b, float* __restrict__ out)
{
    __shared__ __align__(16) unsigned short Wl[2][NCH * NCH];  // 16 KB (hi, lo)
    __shared__ __align__(16) unsigned short BcsT[NCH][8];      // 1 KB (o-major)
    const int bi   = blockIdx.x;
    const int b    = bi >> 9;
    const int rem  = bi & 511;
    const int row  = rem >> 1;
    const int half = rem & 1;
    const int t    = threadIdx.x;

    // phase0: stage W (linear copy of pre-swizzled image) + coef from dd2
    {
        const uint4* src = (const uint4*)Wpk;
        uint4* dst = (uint4*)&Wl[0][0];
        #pragma unroll
        for (int k = 0; k < 4; ++k) dst[t + 256 * k] = src[t + 256 * k];
    }
    {
        const int o = t & 63;
        const int v = t >> 6;          // 0..3
        float tc[5], ts[5];
        tc[0] = 1.f; ts[0] = 0.f;
        #pragma unroll
        for (int k = 1; k < 5; ++k) {
            float a = (float)(k * row) * (1.0f / 256.0f);
            tc[k] = cos2pi(a); ts[k] = sin2pi(a);
        }
        const float2* dv = dd2 + (size_t)b * (9 * 4 * NCH);
        float twr[9] = {tc[0], tc[1], tc[2], tc[3], tc[4], tc[3], tc[2], tc[1], tc[4]};
        float twi[9] = {ts[0], ts[1], ts[2], ts[3], -ts[4], -ts[3], -ts[2], -ts[1], ts[4]};
        if (v == 0) {
            float gr = 0.f;
            #pragma unroll
            for (int p = 0; p < 9; ++p) {
                float2 u = dv[(p * 4 + 0) * NCH + o];
                gr += u.x * twr[p] - u.y * twi[p];
            }
            BcsT[o][0] = f2bf(gr * (1.0f / 65536.0f));
            BcsT[o][7] = 0;
        } else {
            const int q = v;
            float gr = 0.f, gi = 0.f;
            #pragma unroll
            for (int p = 0; p < 8; ++p) {
                float2 u = dv[(p * 4 + q) * NCH + o];
                gr += u.x * twr[p] - u.y * twi[p];
                gi += u.x * twi[p] + u.y * twr[p];
            }
            BcsT[o][q]     = f2bf(gr * (2.0f / 65536.0f));
            BcsT[o][3 + q] = f2bf(-gi * (2.0f / 65536.0f));
        }
    }
    __syncthreads();

    const int lane = t & 63;
    const int wv   = t >> 6;
    const int li   = lane & 15;
    const int g    = lane >> 4;

    // phase1: A-frags in registers (pixel = half*128+(wv*2+i)*16+li)
    s16x8 ahi[2][2], alo[2][2];
    {
        float xs0[2], xs1[2], xs2[2];
        #pragma unroll
        for (int i = 0; i < 2; ++i) {
            int px = half * 128 + (wv * 2 + i) * 16 + li;
            xs0[i] = x[((b * 3 + 0) * NH + row) * NW + px];
            xs1[i] = x[((b * 3 + 1) * NH + row) * NW + px];
            xs2[i] = x[((b * 3 + 2) * NH + row) * NW + px];
        }
        #pragma unroll
        for (int ks = 0; ks < 2; ++ks) {
            unsigned int hu[2][4], lu[2][4];
            #pragma unroll
            for (int j2 = 0; j2 < 4; ++j2) {
                float4 e0 = ((const float4*)encwb)[ks * 32 + g * 8 + j2 * 2 + 0];
                float4 e1 = ((const float4*)encwb)[ks * 32 + g * 8 + j2 * 2 + 1];
                #pragma unroll
                for (int i = 0; i < 2; ++i) {
                    float va = 2.0f * fast_tanh(e0.w + e0.x * xs0[i] + e0.y * xs1[i] + e0.z * xs2[i]);
                    float vb = 2.0f * fast_tanh(e1.w + e1.x * xs0[i] + e1.y * xs1[i] + e1.z * xs2[i]);
                    unsigned int h = pk2(va, vb);
                    float ha = __uint_as_float(h << 16);
                    float hb = __uint_as_float(h & 0xffff0000u);
                    hu[i][j2] = h;
                    lu[i][j2] = pk2(va - ha, vb - hb);
                }
            }
            #pragma unroll
            for (int i = 0; i < 2; ++i) {
                ahi[i][ks] = u4cast(make_uint4(hu[i][0], hu[i][1], hu[i][2], hu[i][3]));
                alo[i][ks] = u4cast(make_uint4(lu[i][0], lu[i][1], lu[i][2], lu[i][3]));
            }
        }
    }

    // phase2: main MFMA (3-term bf16 split)
    f32x4 acc[2][4];
    #pragma unroll
    for (int i = 0; i < 2; ++i)
        #pragma unroll
        for (int nt = 0; nt < 4; ++nt)
            acc[i][nt] = (f32x4){0.f, 0.f, 0.f, 0.f};
    #pragma unroll
    for (int ks = 0; ks < 2; ++ks) {
        #pragma unroll
        for (int nt = 0; nt < 4; ++nt) {
            int o = nt * 16 + li;
            int byteoff = (o * 128 + ks * 64 + g * 16) ^ ((o & 7) << 4);
            s16x8 wh = *(const s16x8*)((const char*)&Wl[0][0] + byteoff);
            s16x8 wl = *(const s16x8*)((const char*)&Wl[1][0] + byteoff);
            #pragma unroll
            for (int i = 0; i < 2; ++i) {
                acc[i][nt] = __builtin_amdgcn_mfma_f32_16x16x32_bf16(ahi[i][ks], wh, acc[i][nt], 0, 0, 0);
                acc[i][nt] = __builtin_amdgcn_mfma_f32_16x16x32_bf16(alo[i][ks], wh, acc[i][nt], 0, 0, 0);
                acc[i][nt] = __builtin_amdgcn_mfma_f32_16x16x32_bf16(ahi[i][ks], wl, acc[i][nt], 0, 0, 0);
            }
        }
    }

    // phase2b: rank-7 correction via MFMA: basis(px)[k=0..7] @ BcsT[k][o]
    {
        s16x8 aC[2];
        #pragma unroll
        for (int i = 0; i < 2; ++i) {
            if (g == 0) {
                int px = half * 128 + (wv * 2 + i) * 16 + li;
                float pf = (float)px;
                float c1 = cos2pi(pf * (1.0f / 256.0f)), s1 = sin2pi(pf * (1.0f / 256.0f));
                float c2 = cos2pi(pf * (2.0f / 256.0f)), s2 = sin2pi(pf * (2.0f / 256.0f));
                float c3 = cos2pi(pf * (3.0f / 256.0f)), s3 = sin2pi(pf * (3.0f / 256.0f));
                aC[i] = u4cast(make_uint4(pk2(1.0f, c1), pk2(c2, c3),
                                          pk2(s1, s2), pk2(s3, 0.0f)));
            } else {
                aC[i] = u4cast(make_uint4(0, 0, 0, 0));
            }
        }
        #pragma unroll
        for (int nt = 0; nt < 4; ++nt) {
            s16x8 bC;
            if (g == 0) bC = *(const s16x8*)(&BcsT[nt * 16 + li][0]);
            else        bC = u4cast(make_uint4(0, 0, 0, 0));
            #pragma unroll
            for (int i = 0; i < 2; ++i)
                acc[i][nt] = __builtin_amdgcn_mfma_f32_16x16x32_bf16(aC[i], bC, acc[i][nt], 0, 0, 0);
        }
    }

    // epilogue
    float d1b[4], d2w[4];
    #pragma unroll
    for (int nt = 0; nt < 4; ++nt) {
        int o = nt * 16 + li;
        d1b[nt] = dec1_b[o];
        d2w[nt] = dec2_w[o];
    }
    const float d2b = dec2_b[0];
    float* orow = out + (b * NH + row) * NW;
    #pragma unroll
    for (int i = 0; i < 2; ++i) {
        #pragma unroll
        for (int r = 0; r < 4; ++r) {
            float partial = 0.f;
            #pragma unroll
            for (int nt = 0; nt < 4; ++nt) {
                float sv = acc[i][nt][r] + d1b[nt];
                partial += d2w[nt] * fast_tanh(sv);
            }
            partial += __shfl_xor(partial, 1);
            partial += __shfl_xor(partial, 2);
            partial += __shfl_xor(partial, 4);
            partial += __shfl_xor(partial, 8);
            if (li == 0) {
                int px = half * 128 + (wv * 2 + i) * 16 + g * 4 + r;
                orow[px] = d2b + partial;
            }
        }
    }
}

extern "C" void kernel_launch(void* const* d_in, const int* in_sizes, int n_in,
                              void* d_out, int out_size, void* d_ws, size_t ws_size,
                              hipStream_t stream) {
    (void)in_sizes; (void)n_in; (void)out_size; (void)ws_size;
    const float* x      = (const float*)d_in[0];
    const float* enc_w  = (const float*)d_in[1];
    const float* enc_b  = (const float*)d_in[2];
    const float* dec1_w = (const float*)d_in[3];
    const float* dec1_b = (const float*)d_in[4];
    const float* dec2_w = (const float*)d_in[5];
    const float* dec2_b = (const float*)d_in[6];
    const float* w1r    = (const float*)d_in[7];
    const float* w1i    = (const float*)d_in[8];
    const float* w2r    = (const float*)d_in[9];
    const float* w2i    = (const float*)d_in[10];
    float* out = (float*)d_out;

    char* ws = (char*)d_ws;
    float*  P2    = (float*)(ws);                          // [2][8][64][256][4][2] f32 = 8 MB
    float2* s0    = (float2*)(ws + (8u << 20));            // 128 KB
    float2* dd2   = (float2*)(ws + (8u << 20) + 131072);   // 8*9*4*64 c = 144 KB
    char*   p0    = ws + (8u << 20) + 131072 + 147456;
    unsigned short* Wpk = (unsigned short*)(p0);           // 16 KB
    unsigned short* Tpk = (unsigned short*)(p0 + 16384);   // 8 KB
    float*  encwb = (float*)(p0 + 16384 + 8192);           // 1 KB
    float*  Wtr   = (float*)(p0 + 16384 + 8192 + 1024);            // 512 KB
    float*  Wti   = (float*)(p0 + 16384 + 8192 + 1024 + 524288);   // 512 KB
    float*  d1wT  = (float*)(p0 + 16384 + 8192 + 1024 + 1048576);  // 16 KB

    k_prep     <<<1032, 256, 0, stream>>>(dec1_w, enc_w, enc_b, w1r, w1i, w2r, w2i,
                                          Wpk, Tpk, encwb, Wtr, Wti, d1wT);
    k_enc_mfma <<<NB * NH * 2, 256, 0, stream>>>(x, encwb, Tpk, P2);
    k_coldft   <<<NB * NCH, 64, 0, stream>>>(P2, s0);
    k_spec     <<<NB * 17, 128, 0, stream>>>(Wtr, Wti, d1wT, s0, dd2);
    k_final    <<<NB * NH * 2, 256, 0, stream>>>(x, encwb, Wpk, dd2, dec1_b,
                                                 dec2_w, dec2_b, out);
}

// Round 9
// 162.287 us; speedup vs baseline: 1.8257x; 1.0317x over previous
//
#include <hip/hip_runtime.h>
#include <hip/hip_bf16.h>

#define NB 8
#define NCIN 3
#define NCH 64
#define NH 256
#define NW 256
#define NM 4
#define NLAYERS 6

typedef short s16x8 __attribute__((ext_vector_type(8)));
typedef float f32x4 __attribute__((ext_vector_type(4)));

// tanh(x) = 1 - 2*rcp(1+e^{2x}); v_exp + v_rcp (no precise-div sequence).
__device__ __forceinline__ float fast_tanh(float x) {
    float e = __expf(2.0f * x);
    return 1.0f - 2.0f * __builtin_amdgcn_rcpf(1.0f + e);
}
// sin/cos of (2*pi*x): raw v_sin/v_cos, input in revolutions (|x|<5 here)
__device__ __forceinline__ float sin2pi(float x) { return __builtin_amdgcn_sinf(x); }
__device__ __forceinline__ float cos2pi(float x) { return __builtin_amdgcn_cosf(x); }

// pack 2 fp32 -> 2 bf16 (RNE) in one u32; compiler emits v_cvt_pk_bf16_f32
__device__ __forceinline__ unsigned int pk2(float a, float b) {
    __hip_bfloat162 h = __float22bfloat162_rn(make_float2(a, b));
    unsigned int u; __builtin_memcpy(&u, &h, 4); return u;
}
__device__ __forceinline__ s16x8 u4cast(uint4 u) {
    s16x8 r; __builtin_memcpy(&r, &u, 16); return r;
}
__device__ __forceinline__ unsigned short f2bf(float f) {
    unsigned int u = __float_as_uint(f);
    u = u + 0x7fffu + ((u >> 16) & 1u);
    return (unsigned short)(u >> 16);
}

// ---------------------------------------------------------------------------
// K0: prep (1032 blocks).
//  [0,1024):  Wt{r,i}[p][q][i][o] fp32 transpose of w1/w2
//  1024-1025: Wpk = dec1_w bf16 hi/lo planes, XOR-swizzled image
//  1026-1029: Tpk = row-DFT twiddles [n=16][w=256] bf16
//  1030:      encwb[64] = {enc_w[c][0..2], enc_b[c]}
//  1031:      d1wT[c][o] = dec1_w[o][c]
// ---------------------------------------------------------------------------
__global__ __launch_bounds__(256) void k_prep(
    const float* __restrict__ dec1_w, const float* __restrict__ enc_w,
    const float* __restrict__ enc_b,
    const float* __restrict__ w1r, const float* __restrict__ w1i,
    const float* __restrict__ w2r, const float* __restrict__ w2i,
    unsigned short* __restrict__ Wpk, unsigned short* __restrict__ Tpk,
    float* __restrict__ encwb, float* __restrict__ Wtr, float* __restrict__ Wti,
    float* __restrict__ d1wT)
{
    const int bid = blockIdx.x;
    const int t   = threadIdx.x;
    if (bid < 1024) {
        int elem = bid * 256 + t;
        int ri = elem >> 17;
        int rem = elem & 0x1FFFF;
        int p  = rem >> 14;
        int q  = (rem >> 12) & 3;
        int i  = (rem >> 6) & 63;
        int o  = rem & 63;
        const float* src;
        if (p < 4) src = ri ? w1i : w1r;
        else       src = ri ? w2i : w2r;
        float v = src[((i * 64 + o) * 4 + (p & 3)) * 4 + q];
        float* dst = ri ? Wti : Wtr;
        dst[(p * 4 + q) * 4096 + i * 64 + o] = v;
    } else if (bid < 1026) {
        const int tt = (bid - 1024) * 256 + t;  // [0,512)
        const int o  = tt & 63;
        const int cb = (tt >> 6) * 8;
        const float* wr = dec1_w + o * NCH + cb;
        float4 wa = ((const float4*)wr)[0];
        float4 wb = ((const float4*)wr)[1];
        float v[8] = {wa.x, wa.y, wa.z, wa.w, wb.x, wb.y, wb.z, wb.w};
        unsigned int ph[4], pl[4];
        #pragma unroll
        for (int j = 0; j < 4; ++j) {
            unsigned int h = pk2(v[2 * j], v[2 * j + 1]);
            float ha = __uint_as_float(h << 16);
            float hb = __uint_as_float(h & 0xffff0000u);
            ph[j] = h;
            pl[j] = pk2(v[2 * j] - ha, v[2 * j + 1] - hb);
        }
        int byteoff = (o * 128 + cb * 2) ^ ((o & 7) << 4);
        *(uint4*)((char*)Wpk + byteoff)        = make_uint4(ph[0], ph[1], ph[2], ph[3]);
        *(uint4*)((char*)Wpk + 8192 + byteoff) = make_uint4(pl[0], pl[1], pl[2], pl[3]);
    } else if (bid < 1030) {
        const int tt = (bid - 1026) * 256 + t;  // [0,1024)
        const int n  = tt >> 6;
        const int w4 = (tt & 63) * 4;
        float vv[4];
        #pragma unroll
        for (int z = 0; z < 4; ++z) {
            int w = w4 + z;
            float val = 0.f;
            if (n < 4)      val = cos2pi((float)(n * w) * (1.0f / 256.0f));
            else if (n < 8) val = -sin2pi((float)((n - 4) * w) * (1.0f / 256.0f));
            vv[z] = val;
        }
        *(uint2*)(Tpk + n * 256 + w4) = make_uint2(pk2(vv[0], vv[1]), pk2(vv[2], vv[3]));
    } else if (bid == 1030) {
        if (t < NCH) {
            float4 e4;
            e4.x = enc_w[t * 3 + 0]; e4.y = enc_w[t * 3 + 1];
            e4.z = enc_w[t * 3 + 2]; e4.w = enc_b[t];
            ((float4*)encwb)[t] = e4;
        }
    } else {
        for (int idx = t; idx < 4096; idx += 256) {
            int c = idx >> 6, o = idx & 63;
            d1wT[idx] = dec1_w[o * NCH + c];
        }
    }
}

// ---------------------------------------------------------------------------
// K1: encoder + row DFT on MFMA, FULL ROW per block (K=256, 8 k-steps).
// block=(b,row), 256 threads. out: P2[b][c][row][q][reim] fp32 (single plane)
// ---------------------------------------------------------------------------
__global__ __launch_bounds__(256) void k_enc_mfma(
    const float* __restrict__ x, const float* __restrict__ encwb,
    const unsigned short* __restrict__ Tpk, float* __restrict__ P2)
{
    __shared__ __align__(16) unsigned short Ah[64 * 256];  // 32 KB
    const int bi  = blockIdx.x;
    const int b   = bi >> 8;
    const int row = bi & 255;
    const int t   = threadIdx.x;

    // phase1: thread -> c = t&63, w chunk (t>>6)*64 (64 w per thread)
    {
        const int c   = t & 63;
        const int wl0 = (t >> 6) * 64;
        float4 ewb = ((const float4*)encwb)[c];
        const float* xr0 = x + ((b * 3 + 0) * NH + row) * NW + wl0;
        const float* xr1 = x + ((b * 3 + 1) * NH + row) * NW + wl0;
        const float* xr2 = x + ((b * 3 + 2) * NH + row) * NW + wl0;
        #pragma unroll
        for (int u = 0; u < 8; ++u) {
            float4 a0 = ((const float4*)xr0)[u * 2], b0 = ((const float4*)xr0)[u * 2 + 1];
            float4 a1 = ((const float4*)xr1)[u * 2], b1 = ((const float4*)xr1)[u * 2 + 1];
            float4 a2 = ((const float4*)xr2)[u * 2], b2 = ((const float4*)xr2)[u * 2 + 1];
            float hv[8];
            hv[0] = fast_tanh(ewb.w + ewb.x * a0.x + ewb.y * a1.x + ewb.z * a2.x);
            hv[1] = fast_tanh(ewb.w + ewb.x * a0.y + ewb.y * a1.y + ewb.z * a2.y);
            hv[2] = fast_tanh(ewb.w + ewb.x * a0.z + ewb.y * a1.z + ewb.z * a2.z);
            hv[3] = fast_tanh(ewb.w + ewb.x * a0.w + ewb.y * a1.w + ewb.z * a2.w);
            hv[4] = fast_tanh(ewb.w + ewb.x * b0.x + ewb.y * b1.x + ewb.z * b2.x);
            hv[5] = fast_tanh(ewb.w + ewb.x * b0.y + ewb.y * b1.y + ewb.z * b2.y);
            hv[6] = fast_tanh(ewb.w + ewb.x * b0.z + ewb.y * b1.z + ewb.z * b2.z);
            hv[7] = fast_tanh(ewb.w + ewb.x * b0.w + ewb.y * b1.w + ewb.z * b2.w);
            uint4 pu = make_uint4(pk2(hv[0], hv[1]), pk2(hv[2], hv[3]),
                                  pk2(hv[4], hv[5]), pk2(hv[6], hv[7]));
            int byteoff = (c * 512 + (wl0 + u * 8) * 2) ^ ((c & 15) << 4);
            *(uint4*)((char*)Ah + byteoff) = pu;
        }
    }
    __syncthreads();

    // phase2: wave v = c-tile; lane: n=li, k-group g; 8 k-steps
    const int lane = t & 63;
    const int v    = t >> 6;
    const int li   = lane & 15;
    const int g    = lane >> 4;
    f32x4 acc = {0.f, 0.f, 0.f, 0.f};
    #pragma unroll
    for (int kk = 0; kk < 8; ++kk) {
        int cm = v * 16 + li;
        int coff = (cm * 512 + (kk * 32 + g * 8) * 2) ^ ((cm & 15) << 4);
        s16x8 ah = *(const s16x8*)((const char*)Ah + coff);
        int wg = kk * 32 + g * 8;
        s16x8 bh = *(const s16x8*)(Tpk + li * 256 + wg);
        acc = __builtin_amdgcn_mfma_f32_16x16x32_bf16(ah, bh, acc, 0, 0, 0);
    }
    if (li < 8) {
        const int q = li & 3, reim = li >> 2;
        #pragma unroll
        for (int e = 0; e < 4; ++e) {
            int c = v * 16 + g * 4 + e;
            P2[(((b * 64 + c) * 256 + row) * 4 + q) * 2 + reim] = acc[e];
        }
    }
}

// ---------------------------------------------------------------------------
// K2: column DFT. block=(b,c), 64 threads = (p,q,reim); full 256-row sum.
// ---------------------------------------------------------------------------
__global__ __launch_bounds__(64) void k_coldft(const float* __restrict__ P2,
                                               float2* __restrict__ s0)
{
    __shared__ __align__(16) float Ps[256][8];   // 8 KB
    __shared__ float twc[5][256];
    __shared__ float tws[5][256];
    const int b = blockIdx.x >> 6;
    const int c = blockIdx.x & 63;
    const int t = threadIdx.x;
    {
        const float4* pa = (const float4*)(P2 + (size_t)(b * 64 + c) * 256 * 8);
        float4* ds = (float4*)&Ps[0][0];
        #pragma unroll
        for (int k = 0; k < 8; ++k) {
            int s = t + 64 * k;
            ds[s] = pa[s];
        }
        for (int idx = t; idx < 5 * 256; idx += 64) {
            int k = idx >> 8, rw = idx & 255;
            float a = (float)(k * rw) * (1.0f / 256.0f);
            twc[k][rw] = cos2pi(a);
            tws[k][rw] = sin2pi(a);
        }
    }
    __syncthreads();
    const int kxs[8] = {0, 1, 2, 3, -4, -3, -2, -1};
    const int p = t >> 3, q = (t >> 1) & 3, reim = t & 1;
    const int kx = kxs[p];
    const int ka = kx < 0 ? -kx : kx;
    const float sgn = (kx < 0) ? 1.f : -1.f;
    float acc = 0.f;
    #pragma unroll 4
    for (int rw = 0; rw < 256; ++rw) {
        float pr = Ps[rw][q * 2], pi = Ps[rw][q * 2 + 1];
        float tr = twc[ka][rw], ti = sgn * tws[ka][rw];
        acc += reim ? (pr * ti + pi * tr) : (pr * tr - pi * ti);
    }
    ((float*)s0)[(((b * 8 + p) * 4 + q) * NCH + c) * 2 + reim] = acc;
}

// ---------------------------------------------------------------------------
// K3 (spec + dd2 tail): slots 0-11 = q123 pairs; 12-16 = ky=0 Hermitian groups.
// ---------------------------------------------------------------------------
__global__ __launch_bounds__(128) void k_spec(
    const float* __restrict__ Wtr, const float* __restrict__ Wti,
    const float* __restrict__ d1wT, const float2* __restrict__ s0,
    float2* __restrict__ dd2)
{
    __shared__ float Wr[2][NCH * NCH];
    __shared__ float Wi[2][NCH * NCH];
    __shared__ float sr[2][NCH], si[2][NCH];
    __shared__ float2 FL[2][NCH];
    __shared__ float W1T[NCH * NCH];
    const int gx    = blockIdx.x;
    const int b     = gx / 17;
    const int slot  = gx % 17;
    const int which = threadIdx.x >> 6;
    const int o     = threadIdx.x & 63;
    const int tid   = threadIdx.x;

    int p = -1, q = 0, g = -1;
    if (slot < 12) {
        int r = slot * 2 + which;
        q = (r >> 3) + 1;
        p = r & 7;
    } else {
        g = slot - 12;
        if (which == 0) p = g;
        else            p = (g == 1) ? 7 : (g == 2) ? 6 : (g == 3) ? 5 : -1;
        q = 0;
    }
    const bool active = (p >= 0);

    if (active) {
        const float4* wr = (const float4*)(Wtr + (p * 4 + q) * 4096);
        const float4* wi = (const float4*)(Wti + (p * 4 + q) * 4096);
        float4* dr = (float4*)&Wr[which][0];
        float4* di = (float4*)&Wi[which][0];
        #pragma unroll
        for (int k = 0; k < 16; ++k) {
            dr[o + 64 * k] = wr[o + 64 * k];
            di[o + 64 * k] = wi[o + 64 * k];
        }
        float2 sv = s0[((b * 8 + p) * 4 + q) * NCH + o];
        sr[which][o] = sv.x; si[which][o] = sv.y;
    }
    {
        float4* w1 = (float4*)W1T;
        const float4* sw = (const float4*)d1wT;
        #pragma unroll
        for (int k = 0; k < 8; ++k) w1[tid + 128 * k] = sw[tid + 128 * k];
    }
    __syncthreads();

    float dr = 0.f, di = 0.f, d8r = 0.f, d8i = 0.f;
    if (slot < 12) {
        for (int l = 0; l < NLAYERS; ++l) {
            float Fr = 0.f, Fi = 0.f;
            for (int i = 0; i < NCH; ++i) {
                float a0 = sr[which][i], a1 = si[which][i];
                float b0 = Wr[which][i * NCH + o], b1 = Wi[which][i * NCH + o];
                Fr += a0 * b0 - a1 * b1;
                Fi += a0 * b1 + a1 * b0;
            }
            __syncthreads();
            sr[which][o] += Fr; si[which][o] += Fi;
            dr += Fr; di += Fi;
            __syncthreads();
        }
    } else {
        for (int l = 0; l < NLAYERS; ++l) {
            float Fr = 0.f, Fi = 0.f;
            if (active) {
                for (int i = 0; i < NCH; ++i) {
                    float a0 = sr[which][i], a1 = si[which][i];
                    float b0 = Wr[which][i * NCH + o], b1 = Wi[which][i * NCH + o];
                    Fr += a0 * b0 - a1 * b1;
                    Fi += a0 * b1 + a1 * b0;
                }
            }
            FL[which][o] = make_float2(Fr, Fi);
            __syncthreads();
            float addr_ = 0.f, addi_ = 0.f;
            if (active) {
                if (g == 0) { addr_ = Fr; addi_ = 0.f; }
                else if (g == 4) {
                    addr_ = 0.5f * Fr; addi_ = 0.5f * Fi;
                    d8r += 0.5f * Fr;  d8i -= 0.5f * Fi;
                } else {
                    float2 Fo = FL[1 - which][o];
                    addr_ = 0.5f * (Fr + Fo.x);
                    addi_ = 0.5f * (Fi - Fo.y);
                }
                sr[which][o] += addr_; si[which][o] += addi_;
                dr += addr_; di += addi_;
            }
            __syncthreads();
        }
    }

    // tail: dd2[p][q][o] = sum_c d[c] * dec1_w[o][c]
    sr[which][o] = dr; si[which][o] = di;
    if (slot == 16 && which == 0) FL[0][o] = make_float2(d8r, d8i);
    __syncthreads();
    float2* db = dd2 + (size_t)b * (9 * 4 * NCH);
    if (active) {
        float ar = 0.f, ai = 0.f;
        for (int c = 0; c < NCH; ++c) {
            float wv = W1T[c * NCH + o];
            ar += sr[which][c] * wv;
            ai += si[which][c] * wv;
        }
        db[(p * 4 + q) * NCH + o] = make_float2(ar, ai);
    }
    if (slot == 16 && which == 0) {
        float ar = 0.f, ai = 0.f;
        for (int c = 0; c < NCH; ++c) {
            float wv = W1T[c * NCH + o];
            ar += FL[0][c].x * wv;
            ai += FL[0][c].y * wv;
        }
        db[(8 * 4 + 0) * NCH + o] = make_float2(ar, ai);
    }
}

// ---------------------------------------------------------------------------
// K5: final, FULL ROW per block (512 threads, 8 waves, 256 px).
// A 1-term bf16 (W stays hi/lo 2-term); W-stage + coef once per row.
// ---------------------------------------------------------------------------
__global__ __launch_bounds__(512) void k_final(
    const float* __restrict__ x, const float* __restrict__ encwb,
    const unsigned short* __restrict__ Wpk, const float2* __restrict__ dd2,
    const float* __restrict__ dec1_b, const float* __restrict__ dec2_w,
    const float* __restrict__ dec2_b, float* __restrict__ out)
{
    __shared__ __align__(16) unsigned short Wl[2][NCH * NCH];  // 16 KB (hi, lo)
    __shared__ __align__(16) unsigned short BcsT[NCH][8];      // 1 KB (o-major)
    const int bi   = blockIdx.x;
    const int b    = bi >> 8;
    const int row  = bi & 255;
    const int t    = threadIdx.x;

    // phase0: stage W (pre-swizzled image) + coef from dd2 (threads < 256)
    {
        const uint4* src = (const uint4*)Wpk;
        uint4* dst = (uint4*)&Wl[0][0];
        #pragma unroll
        for (int k = 0; k < 2; ++k) dst[t + 512 * k] = src[t + 512 * k];
    }
    if (t < 256) {
        const int o = t & 63;
        const int v = t >> 6;          // 0..3
        float tc[5], ts[5];
        tc[0] = 1.f; ts[0] = 0.f;
        #pragma unroll
        for (int k = 1; k < 5; ++k) {
            float a = (float)(k * row) * (1.0f / 256.0f);
            tc[k] = cos2pi(a); ts[k] = sin2pi(a);
        }
        const float2* dv = dd2 + (size_t)b * (9 * 4 * NCH);
        float twr[9] = {tc[0], tc[1], tc[2], tc[3], tc[4], tc[3], tc[2], tc[1], tc[4]};
        float twi[9] = {ts[0], ts[1], ts[2], ts[3], -ts[4], -ts[3], -ts[2], -ts[1], ts[4]};
        if (v == 0) {
            float gr = 0.f;
            #pragma unroll
            for (int p = 0; p < 9; ++p) {
                float2 u = dv[(p * 4 + 0) * NCH + o];
                gr += u.x * twr[p] - u.y * twi[p];
            }
            BcsT[o][0] = f2bf(gr * (1.0f / 65536.0f));
            BcsT[o][7] = 0;
        } else {
            const int q = v;
            float gr = 0.f, gi = 0.f;
            #pragma unroll
            for (int p = 0; p < 8; ++p) {
                float2 u = dv[(p * 4 + q) * NCH + o];
                gr += u.x * twr[p] - u.y * twi[p];
                gi += u.x * twi[p] + u.y * twr[p];
            }
            BcsT[o][q]     = f2bf(gr * (2.0f / 65536.0f));
            BcsT[o][3 + q] = f2bf(-gi * (2.0f / 65536.0f));
        }
    }
    __syncthreads();

    const int lane = t & 63;
    const int wv   = t >> 6;           // 0..7
    const int li   = lane & 15;
    const int g    = lane >> 4;

    // phase1: A-frags in registers, 1-term bf16 (pixel = (wv*2+i)*16+li)
    s16x8 ahi[2][2];
    {
        float xs0[2], xs1[2], xs2[2];
        #pragma unroll
        for (int i = 0; i < 2; ++i) {
            int px = (wv * 2 + i) * 16 + li;
            xs0[i] = x[((b * 3 + 0) * NH + row) * NW + px];
            xs1[i] = x[((b * 3 + 1) * NH + row) * NW + px];
            xs2[i] = x[((b * 3 + 2) * NH + row) * NW + px];
        }
        #pragma unroll
        for (int ks = 0; ks < 2; ++ks) {
            unsigned int hu[2][4];
            #pragma unroll
            for (int j2 = 0; j2 < 4; ++j2) {
                float4 e0 = ((const float4*)encwb)[ks * 32 + g * 8 + j2 * 2 + 0];
                float4 e1 = ((const float4*)encwb)[ks * 32 + g * 8 + j2 * 2 + 1];
                #pragma unroll
                for (int i = 0; i < 2; ++i) {
                    float va = 2.0f * fast_tanh(e0.w + e0.x * xs0[i] + e0.y * xs1[i] + e0.z * xs2[i]);
                    float vb = 2.0f * fast_tanh(e1.w + e1.x * xs0[i] + e1.y * xs1[i] + e1.z * xs2[i]);
                    hu[i][j2] = pk2(va, vb);
                }
            }
            #pragma unroll
            for (int i = 0; i < 2; ++i)
                ahi[i][ks] = u4cast(make_uint4(hu[i][0], hu[i][1], hu[i][2], hu[i][3]));
        }
    }

    // phase2: main MFMA (A 1-term x W hi/lo 2-term)
    f32x4 acc[2][4];
    #pragma unroll
    for (int i = 0; i < 2; ++i)
        #pragma unroll
        for (int nt = 0; nt < 4; ++nt)
            acc[i][nt] = (f32x4){0.f, 0.f, 0.f, 0.f};
    #pragma unroll
    for (int ks = 0; ks < 2; ++ks) {
        #pragma unroll
        for (int nt = 0; nt < 4; ++nt) {
            int o = nt * 16 + li;
            int byteoff = (o * 128 + ks * 64 + g * 16) ^ ((o & 7) << 4);
            s16x8 wh = *(const s16x8*)((const char*)&Wl[0][0] + byteoff);
            s16x8 wl = *(const s16x8*)((const char*)&Wl[1][0] + byteoff);
            #pragma unroll
            for (int i = 0; i < 2; ++i) {
                acc[i][nt] = __builtin_amdgcn_mfma_f32_16x16x32_bf16(ahi[i][ks], wh, acc[i][nt], 0, 0, 0);
                acc[i][nt] = __builtin_amdgcn_mfma_f32_16x16x32_bf16(ahi[i][ks], wl, acc[i][nt], 0, 0, 0);
            }
        }
    }

    // phase2b: rank-7 correction via MFMA: basis(px)[k=0..7] @ BcsT[k][o]
    {
        s16x8 aC[2];
        #pragma unroll
        for (int i = 0; i < 2; ++i) {
            if (g == 0) {
                int px = (wv * 2 + i) * 16 + li;
                float pf = (float)px;
                float c1 = cos2pi(pf * (1.0f / 256.0f)), s1 = sin2pi(pf * (1.0f / 256.0f));
                float c2 = cos2pi(pf * (2.0f / 256.0f)), s2 = sin2pi(pf * (2.0f / 256.0f));
                float c3 = cos2pi(pf * (3.0f / 256.0f)), s3 = sin2pi(pf * (3.0f / 256.0f));
                aC[i] = u4cast(make_uint4(pk2(1.0f, c1), pk2(c2, c3),
                                          pk2(s1, s2), pk2(s3, 0.0f)));
            } else {
                aC[i] = u4cast(make_uint4(0, 0, 0, 0));
            }
        }
        #pragma unroll
        for (int nt = 0; nt < 4; ++nt) {
            s16x8 bC;
            if (g == 0) bC = *(const s16x8*)(&BcsT[nt * 16 + li][0]);
            else        bC = u4cast(make_uint4(0, 0, 0, 0));
            #pragma unroll
            for (int i = 0; i < 2; ++i)
                acc[i][nt] = __builtin_amdgcn_mfma_f32_16x16x32_bf16(aC[i], bC, acc[i][nt], 0, 0, 0);
        }
    }

    // epilogue
    float d1b[4], d2w[4];
    #pragma unroll
    for (int nt = 0; nt < 4; ++nt) {
        int o = nt * 16 + li;
        d1b[nt] = dec1_b[o];
        d2w[nt] = dec2_w[o];
    }
    const float d2b = dec2_b[0];
    float* orow = out + (b * NH + row) * NW;
    #pragma unroll
    for (int i = 0; i < 2; ++i) {
        #pragma unroll
        for (int r = 0; r < 4; ++r) {
            float partial = 0.f;
            #pragma unroll
            for (int nt = 0; nt < 4; ++nt) {
                float sv = acc[i][nt][r] + d1b[nt];
                partial += d2w[nt] * fast_tanh(sv);
            }
            partial += __shfl_xor(partial, 1);
            partial += __shfl_xor(partial, 2);
            partial += __shfl_xor(partial, 4);
            partial += __shfl_xor(partial, 8);
            if (li == 0) {
                int px = (wv * 2 + i) * 16 + g * 4 + r;
                orow[px] = d2b + partial;
            }
        }
    }
}

extern "C" void kernel_launch(void* const* d_in, const int* in_sizes, int n_in,
                              void* d_out, int out_size, void* d_ws, size_t ws_size,
                              hipStream_t stream) {
    (void)in_sizes; (void)n_in; (void)out_size; (void)ws_size;
    const float* x      = (const float*)d_in[0];
    const float* enc_w  = (const float*)d_in[1];
    const float* enc_b  = (const float*)d_in[2];
    const float* dec1_w = (const float*)d_in[3];
    const float* dec1_b = (const float*)d_in[4];
    const float* dec2_w = (const float*)d_in[5];
    const float* dec2_b = (const float*)d_in[6];
    const float* w1r    = (const float*)d_in[7];
    const float* w1i    = (const float*)d_in[8];
    const float* w2r    = (const float*)d_in[9];
    const float* w2i    = (const float*)d_in[10];
    float* out = (float*)d_out;

    char* ws = (char*)d_ws;
    float*  P2    = (float*)(ws);                          // [8][64][256][4][2] f32 = 4 MB
    float2* s0    = (float2*)(ws + (4u << 20));            // 128 KB
    float2* dd2   = (float2*)(ws + (4u << 20) + 131072);   // 144 KB
    char*   p0    = ws + (4u << 20) + 131072 + 147456;
    unsigned short* Wpk = (unsigned short*)(p0);           // 16 KB
    unsigned short* Tpk = (unsigned short*)(p0 + 16384);   // 8 KB
    float*  encwb = (float*)(p0 + 16384 + 8192);           // 1 KB
    float*  Wtr   = (float*)(p0 + 16384 + 8192 + 1024);            // 512 KB
    float*  Wti   = (float*)(p0 + 16384 + 8192 + 1024 + 524288);   // 512 KB
    float*  d1wT  = (float*)(p0 + 16384 + 8192 + 1024 + 1048576);  // 16 KB

    k_prep     <<<1032, 256, 0, stream>>>(dec1_w, enc_w, enc_b, w1r, w1i, w2r, w2i,
                                          Wpk, Tpk, encwb, Wtr, Wti, d1wT);
    k_enc_mfma <<<NB * NH, 256, 0, stream>>>(x, encwb, Tpk, P2);
    k_coldft   <<<NB * NCH, 64, 0, stream>>>(P2, s0);
    k_spec     <<<NB * 17, 128, 0, stream>>>(Wtr, Wti, d1wT, s0, dd2);
    k_final    <<<NB * NH, 512, 0, stream>>>(x, encwb, Wpk, dd2, dec1_b,
                                             dec2_w, dec2_b, out);
}

// Round 10
// 161.927 us; speedup vs baseline: 1.8298x; 1.0022x over previous
//
#include <hip/hip_runtime.h>
#include <hip/hip_bf16.h>

#define NB 8
#define NCIN 3
#define NCH 64
#define NH 256
#define NW 256
#define NM 4
#define NLAYERS 6

typedef short s16x8 __attribute__((ext_vector_type(8)));
typedef float f32x4 __attribute__((ext_vector_type(4)));

// tanh(x) = 1 - 2*rcp(1+e^{2x}); v_exp + v_rcp (no precise-div sequence).
__device__ __forceinline__ float fast_tanh(float x) {
    float e = __expf(2.0f * x);
    return 1.0f - 2.0f * __builtin_amdgcn_rcpf(1.0f + e);
}
// sin/cos of (2*pi*x): raw v_sin/v_cos, input in revolutions (|x|<5 here)
__device__ __forceinline__ float sin2pi(float x) { return __builtin_amdgcn_sinf(x); }
__device__ __forceinline__ float cos2pi(float x) { return __builtin_amdgcn_cosf(x); }

// pack 2 fp32 -> 2 bf16 (RNE) in one u32; compiler emits v_cvt_pk_bf16_f32
__device__ __forceinline__ unsigned int pk2(float a, float b) {
    __hip_bfloat162 h = __float22bfloat162_rn(make_float2(a, b));
    unsigned int u; __builtin_memcpy(&u, &h, 4); return u;
}
__device__ __forceinline__ s16x8 u4cast(uint4 u) {
    s16x8 r; __builtin_memcpy(&r, &u, 16); return r;
}
__device__ __forceinline__ unsigned short f2bf(float f) {
    unsigned int u = __float_as_uint(f);
    u = u + 0x7fffu + ((u >> 16) & 1u);
    return (unsigned short)(u >> 16);
}

// ---------------------------------------------------------------------------
// K0: prep (1033 blocks).
//  [0,1024):  Wt{r,i}[p][q][i][o] fp32 transpose of w1/w2
//  1024-1025: Wpk = dec1_w bf16 hi/lo planes, XOR-swizzled image
//  1026-1029: Tpk = row-DFT twiddles [n=16][w=256] bf16
//  1030:      encwb[64] = {enc_w[c][0..2], enc_b[c]}
//  1031:      d1wT[c][o] = dec1_w[o][c]
//  1032:      aCtab[px] = bf16x8 {1,c1,c2,c3,s1,s2,s3,0} basis fragment
// ---------------------------------------------------------------------------
__global__ __launch_bounds__(256) void k_prep(
    const float* __restrict__ dec1_w, const float* __restrict__ enc_w,
    const float* __restrict__ enc_b,
    const float* __restrict__ w1r, const float* __restrict__ w1i,
    const float* __restrict__ w2r, const float* __restrict__ w2i,
    unsigned short* __restrict__ Wpk, unsigned short* __restrict__ Tpk,
    float* __restrict__ encwb, float* __restrict__ Wtr, float* __restrict__ Wti,
    float* __restrict__ d1wT, unsigned short* __restrict__ aCtab)
{
    const int bid = blockIdx.x;
    const int t   = threadIdx.x;
    if (bid < 1024) {
        int elem = bid * 256 + t;
        int ri = elem >> 17;
        int rem = elem & 0x1FFFF;
        int p  = rem >> 14;
        int q  = (rem >> 12) & 3;
        int i  = (rem >> 6) & 63;
        int o  = rem & 63;
        const float* src;
        if (p < 4) src = ri ? w1i : w1r;
        else       src = ri ? w2i : w2r;
        float v = src[((i * 64 + o) * 4 + (p & 3)) * 4 + q];
        float* dst = ri ? Wti : Wtr;
        dst[(p * 4 + q) * 4096 + i * 64 + o] = v;
    } else if (bid < 1026) {
        const int tt = (bid - 1024) * 256 + t;  // [0,512)
        const int o  = tt & 63;
        const int cb = (tt >> 6) * 8;
        const float* wr = dec1_w + o * NCH + cb;
        float4 wa = ((const float4*)wr)[0];
        float4 wb = ((const float4*)wr)[1];
        float v[8] = {wa.x, wa.y, wa.z, wa.w, wb.x, wb.y, wb.z, wb.w};
        unsigned int ph[4], pl[4];
        #pragma unroll
        for (int j = 0; j < 4; ++j) {
            unsigned int h = pk2(v[2 * j], v[2 * j + 1]);
            float ha = __uint_as_float(h << 16);
            float hb = __uint_as_float(h & 0xffff0000u);
            ph[j] = h;
            pl[j] = pk2(v[2 * j] - ha, v[2 * j + 1] - hb);
        }
        int byteoff = (o * 128 + cb * 2) ^ ((o & 7) << 4);
        *(uint4*)((char*)Wpk + byteoff)        = make_uint4(ph[0], ph[1], ph[2], ph[3]);
        *(uint4*)((char*)Wpk + 8192 + byteoff) = make_uint4(pl[0], pl[1], pl[2], pl[3]);
    } else if (bid < 1030) {
        const int tt = (bid - 1026) * 256 + t;  // [0,1024)
        const int n  = tt >> 6;
        const int w4 = (tt & 63) * 4;
        float vv[4];
        #pragma unroll
        for (int z = 0; z < 4; ++z) {
            int w = w4 + z;
            float val = 0.f;
            if (n < 4)      val = cos2pi((float)(n * w) * (1.0f / 256.0f));
            else if (n < 8) val = -sin2pi((float)((n - 4) * w) * (1.0f / 256.0f));
            vv[z] = val;
        }
        *(uint2*)(Tpk + n * 256 + w4) = make_uint2(pk2(vv[0], vv[1]), pk2(vv[2], vv[3]));
    } else if (bid == 1030) {
        if (t < NCH) {
            float4 e4;
            e4.x = enc_w[t * 3 + 0]; e4.y = enc_w[t * 3 + 1];
            e4.z = enc_w[t * 3 + 2]; e4.w = enc_b[t];
            ((float4*)encwb)[t] = e4;
        }
    } else if (bid == 1031) {
        for (int idx = t; idx < 4096; idx += 256) {
            int c = idx >> 6, o = idx & 63;
            d1wT[idx] = dec1_w[o * NCH + c];
        }
    } else {
        // aCtab: per-pixel correction basis fragment (k = 0..7)
        float pf = (float)t;
        float c1 = cos2pi(pf * (1.0f / 256.0f)), s1 = sin2pi(pf * (1.0f / 256.0f));
        float c2 = cos2pi(pf * (2.0f / 256.0f)), s2 = sin2pi(pf * (2.0f / 256.0f));
        float c3 = cos2pi(pf * (3.0f / 256.0f)), s3 = sin2pi(pf * (3.0f / 256.0f));
        *(uint4*)(aCtab + t * 8) = make_uint4(pk2(1.0f, c1), pk2(c2, c3),
                                              pk2(s1, s2), pk2(s3, 0.0f));
    }
}

// ---------------------------------------------------------------------------
// K1: encoder + row DFT on MFMA — A-frags built IN REGISTERS (producer lane ==
// consumer lane): lane (v,li,g) computes h0[c=v*16+li][w=kk*32+g*8+j] inline.
// No LDS, no barriers. block=(b,row), 256 threads (4 independent waves).
// out: P2[b][c][row][q][reim] fp32
// ---------------------------------------------------------------------------
__global__ __launch_bounds__(256) void k_enc_mfma(
    const float* __restrict__ x, const float* __restrict__ encwb,
    const unsigned short* __restrict__ Tpk, float* __restrict__ P2)
{
    const int bi  = blockIdx.x;
    const int b   = bi >> 8;
    const int row = bi & 255;
    const int t   = threadIdx.x;
    const int lane = t & 63;
    const int v    = t >> 6;
    const int li   = lane & 15;
    const int g    = lane >> 4;
    const int c    = v * 16 + li;            // this lane's channel (A row)

    const float4 ewb = ((const float4*)encwb)[c];
    const float* xr0 = x + ((b * 3 + 0) * NH + row) * NW;
    const float* xr1 = x + ((b * 3 + 1) * NH + row) * NW;
    const float* xr2 = x + ((b * 3 + 2) * NH + row) * NW;

    f32x4 acc = {0.f, 0.f, 0.f, 0.f};
    #pragma unroll
    for (int kk = 0; kk < 8; ++kk) {
        const int wg = kk * 32 + g * 8;
        float4 a0 = *(const float4*)(xr0 + wg), b0 = *(const float4*)(xr0 + wg + 4);
        float4 a1 = *(const float4*)(xr1 + wg), b1 = *(const float4*)(xr1 + wg + 4);
        float4 a2 = *(const float4*)(xr2 + wg), b2 = *(const float4*)(xr2 + wg + 4);
        float hv[8];
        hv[0] = fast_tanh(ewb.w + ewb.x * a0.x + ewb.y * a1.x + ewb.z * a2.x);
        hv[1] = fast_tanh(ewb.w + ewb.x * a0.y + ewb.y * a1.y + ewb.z * a2.y);
        hv[2] = fast_tanh(ewb.w + ewb.x * a0.z + ewb.y * a1.z + ewb.z * a2.z);
        hv[3] = fast_tanh(ewb.w + ewb.x * a0.w + ewb.y * a1.w + ewb.z * a2.w);
        hv[4] = fast_tanh(ewb.w + ewb.x * b0.x + ewb.y * b1.x + ewb.z * b2.x);
        hv[5] = fast_tanh(ewb.w + ewb.x * b0.y + ewb.y * b1.y + ewb.z * b2.y);
        hv[6] = fast_tanh(ewb.w + ewb.x * b0.z + ewb.y * b1.z + ewb.z * b2.z);
        hv[7] = fast_tanh(ewb.w + ewb.x * b0.w + ewb.y * b1.w + ewb.z * b2.w);
        s16x8 ah = u4cast(make_uint4(pk2(hv[0], hv[1]), pk2(hv[2], hv[3]),
                                     pk2(hv[4], hv[5]), pk2(hv[6], hv[7])));
        s16x8 bh = *(const s16x8*)(Tpk + li * 256 + wg);
        acc = __builtin_amdgcn_mfma_f32_16x16x32_bf16(ah, bh, acc, 0, 0, 0);
    }
    if (li < 8) {
        const int q = li & 3, reim = li >> 2;
        #pragma unroll
        for (int e = 0; e < 4; ++e) {
            int cc = v * 16 + g * 4 + e;
            P2[(((b * 64 + cc) * 256 + row) * 4 + q) * 2 + reim] = acc[e];
        }
    }
}

// ---------------------------------------------------------------------------
// K2: column DFT. block=(b,c), 64 threads = (p,q,reim); full 256-row sum.
// ---------------------------------------------------------------------------
__global__ __launch_bounds__(64) void k_coldft(const float* __restrict__ P2,
                                               float2* __restrict__ s0)
{
    __shared__ __align__(16) float Ps[256][8];   // 8 KB
    __shared__ float twc[5][256];
    __shared__ float tws[5][256];
    const int b = blockIdx.x >> 6;
    const int c = blockIdx.x & 63;
    const int t = threadIdx.x;
    {
        const float4* pa = (const float4*)(P2 + (size_t)(b * 64 + c) * 256 * 8);
        float4* ds = (float4*)&Ps[0][0];
        #pragma unroll
        for (int k = 0; k < 8; ++k) {
            int s = t + 64 * k;
            ds[s] = pa[s];
        }
        for (int idx = t; idx < 5 * 256; idx += 64) {
            int k = idx >> 8, rw = idx & 255;
            float a = (float)(k * rw) * (1.0f / 256.0f);
            twc[k][rw] = cos2pi(a);
            tws[k][rw] = sin2pi(a);
        }
    }
    __syncthreads();
    const int kxs[8] = {0, 1, 2, 3, -4, -3, -2, -1};
    const int p = t >> 3, q = (t >> 1) & 3, reim = t & 1;
    const int kx = kxs[p];
    const int ka = kx < 0 ? -kx : kx;
    const float sgn = (kx < 0) ? 1.f : -1.f;
    float acc = 0.f;
    #pragma unroll 4
    for (int rw = 0; rw < 256; ++rw) {
        float pr = Ps[rw][q * 2], pi = Ps[rw][q * 2 + 1];
        float tr = twc[ka][rw], ti = sgn * tws[ka][rw];
        acc += reim ? (pr * ti + pi * tr) : (pr * tr - pi * ti);
    }
    ((float*)s0)[(((b * 8 + p) * 4 + q) * NCH + c) * 2 + reim] = acc;
}

// ---------------------------------------------------------------------------
// K3 (spec + dd2 tail): slots 0-11 = q123 pairs; 12-16 = ky=0 Hermitian groups.
// ---------------------------------------------------------------------------
__global__ __launch_bounds__(128) void k_spec(
    const float* __restrict__ Wtr, const float* __restrict__ Wti,
    const float* __restrict__ d1wT, const float2* __restrict__ s0,
    float2* __restrict__ dd2)
{
    __shared__ float Wr[2][NCH * NCH];
    __shared__ float Wi[2][NCH * NCH];
    __shared__ float sr[2][NCH], si[2][NCH];
    __shared__ float2 FL[2][NCH];
    __shared__ float W1T[NCH * NCH];
    const int gx    = blockIdx.x;
    const int b     = gx / 17;
    const int slot  = gx % 17;
    const int which = threadIdx.x >> 6;
    const int o     = threadIdx.x & 63;
    const int tid   = threadIdx.x;

    int p = -1, q = 0, g = -1;
    if (slot < 12) {
        int r = slot * 2 + which;
        q = (r >> 3) + 1;
        p = r & 7;
    } else {
        g = slot - 12;
        if (which == 0) p = g;
        else            p = (g == 1) ? 7 : (g == 2) ? 6 : (g == 3) ? 5 : -1;
        q = 0;
    }
    const bool active = (p >= 0);

    if (active) {
        const float4* wr = (const float4*)(Wtr + (p * 4 + q) * 4096);
        const float4* wi = (const float4*)(Wti + (p * 4 + q) * 4096);
        float4* dr = (float4*)&Wr[which][0];
        float4* di = (float4*)&Wi[which][0];
        #pragma unroll
        for (int k = 0; k < 16; ++k) {
            dr[o + 64 * k] = wr[o + 64 * k];
            di[o + 64 * k] = wi[o + 64 * k];
        }
        float2 sv = s0[((b * 8 + p) * 4 + q) * NCH + o];
        sr[which][o] = sv.x; si[which][o] = sv.y;
    }
    {
        float4* w1 = (float4*)W1T;
        const float4* sw = (const float4*)d1wT;
        #pragma unroll
        for (int k = 0; k < 8; ++k) w1[tid + 128 * k] = sw[tid + 128 * k];
    }
    __syncthreads();

    float dr = 0.f, di = 0.f, d8r = 0.f, d8i = 0.f;
    if (slot < 12) {
        for (int l = 0; l < NLAYERS; ++l) {
            float Fr = 0.f, Fi = 0.f;
            for (int i = 0; i < NCH; ++i) {
                float a0 = sr[which][i], a1 = si[which][i];
                float b0 = Wr[which][i * NCH + o], b1 = Wi[which][i * NCH + o];
                Fr += a0 * b0 - a1 * b1;
                Fi += a0 * b1 + a1 * b0;
            }
            __syncthreads();
            sr[which][o] += Fr; si[which][o] += Fi;
            dr += Fr; di += Fi;
            __syncthreads();
        }
    } else {
        for (int l = 0; l < NLAYERS; ++l) {
            float Fr = 0.f, Fi = 0.f;
            if (active) {
                for (int i = 0; i < NCH; ++i) {
                    float a0 = sr[which][i], a1 = si[which][i];
                    float b0 = Wr[which][i * NCH + o], b1 = Wi[which][i * NCH + o];
                    Fr += a0 * b0 - a1 * b1;
                    Fi += a0 * b1 + a1 * b0;
                }
            }
            FL[which][o] = make_float2(Fr, Fi);
            __syncthreads();
            float addr_ = 0.f, addi_ = 0.f;
            if (active) {
                if (g == 0) { addr_ = Fr; addi_ = 0.f; }
                else if (g == 4) {
                    addr_ = 0.5f * Fr; addi_ = 0.5f * Fi;
                    d8r += 0.5f * Fr;  d8i -= 0.5f * Fi;
                } else {
                    float2 Fo = FL[1 - which][o];
                    addr_ = 0.5f * (Fr + Fo.x);
                    addi_ = 0.5f * (Fi - Fo.y);
                }
                sr[which][o] += addr_; si[which][o] += addi_;
                dr += addr_; di += addi_;
            }
            __syncthreads();
        }
    }

    // tail: dd2[p][q][o] = sum_c d[c] * dec1_w[o][c]
    sr[which][o] = dr; si[which][o] = di;
    if (slot == 16 && which == 0) FL[0][o] = make_float2(d8r, d8i);
    __syncthreads();
    float2* db = dd2 + (size_t)b * (9 * 4 * NCH);
    if (active) {
        float ar = 0.f, ai = 0.f;
        for (int c = 0; c < NCH; ++c) {
            float wv = W1T[c * NCH + o];
            ar += sr[which][c] * wv;
            ai += si[which][c] * wv;
        }
        db[(p * 4 + q) * NCH + o] = make_float2(ar, ai);
    }
    if (slot == 16 && which == 0) {
        float ar = 0.f, ai = 0.f;
        for (int c = 0; c < NCH; ++c) {
            float wv = W1T[c * NCH + o];
            ar += FL[0][c].x * wv;
            ai += FL[0][c].y * wv;
        }
        db[(8 * 4 + 0) * NCH + o] = make_float2(ar, ai);
    }
}

// ---------------------------------------------------------------------------
// K5: final, FULL ROW per block (512 threads, 8 waves, 256 px).
// A 1-term bf16 (W hi/lo 2-term); correction basis from aCtab (no trig).
// ---------------------------------------------------------------------------
__global__ __launch_bounds__(512) void k_final(
    const float* __restrict__ x, const float* __restrict__ encwb,
    const unsigned short* __restrict__ Wpk, const float2* __restrict__ dd2,
    const unsigned short* __restrict__ aCtab,
    const float* __restrict__ dec1_b, const float* __restrict__ dec2_w,
    const float* __restrict__ dec2_b, float* __restrict__ out)
{
    __shared__ __align__(16) unsigned short Wl[2][NCH * NCH];  // 16 KB (hi, lo)
    __shared__ __align__(16) unsigned short BcsT[NCH][8];      // 1 KB (o-major)
    const int bi   = blockIdx.x;
    const int b    = bi >> 8;
    const int row  = bi & 255;
    const int t    = threadIdx.x;

    // phase0: stage W (pre-swizzled image) + coef from dd2 (threads < 256)
    {
        const uint4* src = (const uint4*)Wpk;
        uint4* dst = (uint4*)&Wl[0][0];
        #pragma unroll
        for (int k = 0; k < 2; ++k) dst[t + 512 * k] = src[t + 512 * k];
    }
    if (t < 256) {
        const int o = t & 63;
        const int v = t >> 6;          // 0..3
        float tc[5], ts[5];
        tc[0] = 1.f; ts[0] = 0.f;
        #pragma unroll
        for (int k = 1; k < 5; ++k) {
            float a = (float)(k * row) * (1.0f / 256.0f);
            tc[k] = cos2pi(a); ts[k] = sin2pi(a);
        }
        const float2* dv = dd2 + (size_t)b * (9 * 4 * NCH);
        float twr[9] = {tc[0], tc[1], tc[2], tc[3], tc[4], tc[3], tc[2], tc[1], tc[4]};
        float twi[9] = {ts[0], ts[1], ts[2], ts[3], -ts[4], -ts[3], -ts[2], -ts[1], ts[4]};
        if (v == 0) {
            float gr = 0.f;
            #pragma unroll
            for (int p = 0; p < 9; ++p) {
                float2 u = dv[(p * 4 + 0) * NCH + o];
                gr += u.x * twr[p] - u.y * twi[p];
            }
            BcsT[o][0] = f2bf(gr * (1.0f / 65536.0f));
            BcsT[o][7] = 0;
        } else {
            const int q = v;
            float gr = 0.f, gi = 0.f;
            #pragma unroll
            for (int p = 0; p < 8; ++p) {
                float2 u = dv[(p * 4 + q) * NCH + o];
                gr += u.x * twr[p] - u.y * twi[p];
                gi += u.x * twi[p] + u.y * twr[p];
            }
            BcsT[o][q]     = f2bf(gr * (2.0f / 65536.0f));
            BcsT[o][3 + q] = f2bf(-gi * (2.0f / 65536.0f));
        }
    }
    __syncthreads();

    const int lane = t & 63;
    const int wv   = t >> 6;           // 0..7
    const int li   = lane & 15;
    const int g    = lane >> 4;

    // phase1: A-frags in registers, 1-term bf16 (pixel = (wv*2+i)*16+li)
    s16x8 ahi[2][2];
    {
        float xs0[2], xs1[2], xs2[2];
        #pragma unroll
        for (int i = 0; i < 2; ++i) {
            int px = (wv * 2 + i) * 16 + li;
            xs0[i] = x[((b * 3 + 0) * NH + row) * NW + px];
            xs1[i] = x[((b * 3 + 1) * NH + row) * NW + px];
            xs2[i] = x[((b * 3 + 2) * NH + row) * NW + px];
        }
        #pragma unroll
        for (int ks = 0; ks < 2; ++ks) {
            unsigned int hu[2][4];
            #pragma unroll
            for (int j2 = 0; j2 < 4; ++j2) {
                float4 e0 = ((const float4*)encwb)[ks * 32 + g * 8 + j2 * 2 + 0];
                float4 e1 = ((const float4*)encwb)[ks * 32 + g * 8 + j2 * 2 + 1];
                #pragma unroll
                for (int i = 0; i < 2; ++i) {
                    float va = 2.0f * fast_tanh(e0.w + e0.x * xs0[i] + e0.y * xs1[i] + e0.z * xs2[i]);
                    float vb = 2.0f * fast_tanh(e1.w + e1.x * xs0[i] + e1.y * xs1[i] + e1.z * xs2[i]);
                    hu[i][j2] = pk2(va, vb);
                }
            }
            #pragma unroll
            for (int i = 0; i < 2; ++i)
                ahi[i][ks] = u4cast(make_uint4(hu[i][0], hu[i][1], hu[i][2], hu[i][3]));
        }
    }

    // phase2: main MFMA (A 1-term x W hi/lo 2-term)
    f32x4 acc[2][4];
    #pragma unroll
    for (int i = 0; i < 2; ++i)
        #pragma unroll
        for (int nt = 0; nt < 4; ++nt)
            acc[i][nt] = (f32x4){0.f, 0.f, 0.f, 0.f};
    #pragma unroll
    for (int ks = 0; ks < 2; ++ks) {
        #pragma unroll
        for (int nt = 0; nt < 4; ++nt) {
            int o = nt * 16 + li;
            int byteoff = (o * 128 + ks * 64 + g * 16) ^ ((o & 7) << 4);
            s16x8 wh = *(const s16x8*)((const char*)&Wl[0][0] + byteoff);
            s16x8 wl = *(const s16x8*)((const char*)&Wl[1][0] + byteoff);
            #pragma unroll
            for (int i = 0; i < 2; ++i) {
                acc[i][nt] = __builtin_amdgcn_mfma_f32_16x16x32_bf16(ahi[i][ks], wh, acc[i][nt], 0, 0, 0);
                acc[i][nt] = __builtin_amdgcn_mfma_f32_16x16x32_bf16(ahi[i][ks], wl, acc[i][nt], 0, 0, 0);
            }
        }
    }

    // phase2b: rank-7 correction via MFMA: aCtab basis @ BcsT
    {
        s16x8 aC[2];
        #pragma unroll
        for (int i = 0; i < 2; ++i) {
            if (g == 0) {
                int px = (wv * 2 + i) * 16 + li;
                aC[i] = *(const s16x8*)(aCtab + px * 8);
            } else {
                aC[i] = u4cast(make_uint4(0, 0, 0, 0));
            }
        }
        #pragma unroll
        for (int nt = 0; nt < 4; ++nt) {
            s16x8 bC;
            if (g == 0) bC = *(const s16x8*)(&BcsT[nt * 16 + li][0]);
            else        bC = u4cast(make_uint4(0, 0, 0, 0));
            #pragma unroll
            for (int i = 0; i < 2; ++i)
                acc[i][nt] = __builtin_amdgcn_mfma_f32_16x16x32_bf16(aC[i], bC, acc[i][nt], 0, 0, 0);
        }
    }

    // epilogue
    float d1b[4], d2w[4];
    #pragma unroll
    for (int nt = 0; nt < 4; ++nt) {
        int o = nt * 16 + li;
        d1b[nt] = dec1_b[o];
        d2w[nt] = dec2_w[o];
    }
    const float d2b = dec2_b[0];
    float* orow = out + (b * NH + row) * NW;
    #pragma unroll
    for (int i = 0; i < 2; ++i) {
        #pragma unroll
        for (int r = 0; r < 4; ++r) {
            float partial = 0.f;
            #pragma unroll
            for (int nt = 0; nt < 4; ++nt) {
                float sv = acc[i][nt][r] + d1b[nt];
                partial += d2w[nt] * fast_tanh(sv);
            }
            partial += __shfl_xor(partial, 1);
            partial += __shfl_xor(partial, 2);
            partial += __shfl_xor(partial, 4);
            partial += __shfl_xor(partial, 8);
            if (li == 0) {
                int px = (wv * 2 + i) * 16 + g * 4 + r;
                orow[px] = d2b + partial;
            }
        }
    }
}

extern "C" void kernel_launch(void* const* d_in, const int* in_sizes, int n_in,
                              void* d_out, int out_size, void* d_ws, size_t ws_size,
                              hipStream_t stream) {
    (void)in_sizes; (void)n_in; (void)out_size; (void)ws_size;
    const float* x      = (const float*)d_in[0];
    const float* enc_w  = (const float*)d_in[1];
    const float* enc_b  = (const float*)d_in[2];
    const float* dec1_w = (const float*)d_in[3];
    const float* dec1_b = (const float*)d_in[4];
    const float* dec2_w = (const float*)d_in[5];
    const float* dec2_b = (const float*)d_in[6];
    const float* w1r    = (const float*)d_in[7];
    const float* w1i    = (const float*)d_in[8];
    const float* w2r    = (const float*)d_in[9];
    const float* w2i    = (const float*)d_in[10];
    float* out = (float*)d_out;

    char* ws = (char*)d_ws;
    float*  P2    = (float*)(ws);                          // [8][64][256][4][2] f32 = 4 MB
    float2* s0    = (float2*)(ws + (4u << 20));            // 128 KB
    float2* dd2   = (float2*)(ws + (4u << 20) + 131072);   // 144 KB
    char*   p0    = ws + (4u << 20) + 131072 + 147456;
    unsigned short* Wpk = (unsigned short*)(p0);           // 16 KB
    unsigned short* Tpk = (unsigned short*)(p0 + 16384);   // 8 KB
    float*  encwb = (float*)(p0 + 16384 + 8192);           // 1 KB
    float*  Wtr   = (float*)(p0 + 16384 + 8192 + 1024);            // 512 KB
    float*  Wti   = (float*)(p0 + 16384 + 8192 + 1024 + 524288);   // 512 KB
    float*  d1wT  = (float*)(p0 + 16384 + 8192 + 1024 + 1048576);  // 16 KB
    unsigned short* aCtab = (unsigned short*)(p0 + 16384 + 8192 + 1024 + 1048576 + 16384); // 4 KB

    k_prep     <<<1033, 256, 0, stream>>>(dec1_w, enc_w, enc_b, w1r, w1i, w2r, w2i,
                                          Wpk, Tpk, encwb, Wtr, Wti, d1wT, aCtab);
    k_enc_mfma <<<NB * NH, 256, 0, stream>>>(x, encwb, Tpk, P2);
    k_coldft   <<<NB * NCH, 64, 0, stream>>>(P2, s0);
    k_spec     <<<NB * 17, 128, 0, stream>>>(Wtr, Wti, d1wT, s0, dd2);
    k_final    <<<NB * NH, 512, 0, stream>>>(x, encwb, Wpk, dd2, aCtab, dec1_b,
                                             dec2_w, dec2_b, out);
}